// Round 10
// baseline (2318.869 us; speedup 1.0000x reference)
//
#include <hip/hip_runtime.h>
#include <math.h>

// ---------------------------------------------------------------------------
// HybridBlock: rmsnorm -> LiquidCell scan -> PLIF scan -> sparse synapse +
// sigmoid gate (residual) -> rmsnorm -> SwiGLU-style FFN (residual).
// B=4, T=1024, D=1024, H=8192.
// ---------------------------------------------------------------------------

#define Bsz 4
#define Tsz 1024
#define Dsz 1024
#define Hsz 8192

typedef __attribute__((ext_vector_type(8))) short short8;
typedef __attribute__((ext_vector_type(4))) float floatx4_t;

// ---- helpers --------------------------------------------------------------

__device__ __forceinline__ unsigned short f2bf(float f) {
  union { float f; unsigned u; } c; c.f = f;
  unsigned x = c.u;
  unsigned r = (x + 0x7FFFu + ((x >> 16) & 1u)) >> 16;   // RNE
  return (unsigned short)r;
}

__device__ __forceinline__ void gll16(const void* gsrc, void* ldst) {
  // async global->LDS, 16B per lane; LDS dest = wave-uniform base + lane*16
  __builtin_amdgcn_global_load_lds(
      (const __attribute__((address_space(1))) unsigned int*)gsrc,
      (__attribute__((address_space(3))) unsigned int*)ldst,
      16, 0, 0);
}

// ---- tiny prep kernels ----------------------------------------------------

__global__ void zero_u64_k(unsigned long long* p, int n) {
  int i = blockIdx.x * 256 + threadIdx.x;
  if (i < n) p[i] = 0ull;
}

// ---- rmsnorm (one block per row of 1024) ----------------------------------

template<int BF16OUT>
__global__ __launch_bounds__(256)
void rmsnorm_k(const float* __restrict__ X, const float* __restrict__ w,
               void* __restrict__ out) {
  const long row = blockIdx.x;
  const float* x = X + row * Dsz;
  float4 v = ((const float4*)x)[threadIdx.x];
  float ss = v.x * v.x + v.y * v.y + v.z * v.z + v.w * v.w;
#pragma unroll
  for (int off = 32; off > 0; off >>= 1) ss += __shfl_down(ss, off);
  __shared__ float red[4];
  if ((threadIdx.x & 63) == 0) red[threadIdx.x >> 6] = ss;
  __syncthreads();
  float tot = red[0] + red[1] + red[2] + red[3];
  float scale = 1.0f / sqrtf(tot * (1.0f / Dsz) + 1e-6f);
  float4 wv = ((const float4*)w)[threadIdx.x];
  float o0 = v.x * scale * wv.x, o1 = v.y * scale * wv.y;
  float o2 = v.z * scale * wv.z, o3 = v.w * scale * wv.w;
  if (BF16OUT) {
    ushort4 o; o.x = f2bf(o0); o.y = f2bf(o1); o.z = f2bf(o2); o.w = f2bf(o3);
    ((ushort4*)out)[row * 256 + threadIdx.x] = o;
  } else {
    float4 o; o.x = o0; o.y = o1; o.z = o2; o.w = o3;
    ((float4*)out)[row * 256 + threadIdx.x] = o;
  }
}

// ---- fused persistent kernel ----------------------------------------------
// 256 blocks x 320 threads (r7 structure, proven 2213us total).
// Blocks 0..127  : r3 scan. CHANGE vs r7: the matvec waves' Hex poll is
//                  PIPELINED - two tagged poll rounds in flight (issue B,
//                  check A with vmcnt(4), alternate). Cuts discovery latency
//                  from ~1.5 LLC round trips to ~0.5. Consumer-only change;
//                  protocol/ring/publish identical to r7 (tag-exact match,
//                  depth-2 parity ring). Dead in-flight loads retire
//                  harmlessly into dead registers.
// Blocks 128..255: producer blocks (r7 verbatim): stream u = rmsnorm(x)@Wi^T
//                  + b as tagged u64s into Utag; then convert all weights.

__global__ __launch_bounds__(320)
void liquid_plif_k(const float* __restrict__ x,
                   const float* __restrict__ ln1_w,
                   const float* __restrict__ Wi,
                   const float* __restrict__ liq_b,
                   const float* __restrict__ Wr,
                   const float* __restrict__ liq_tau,
                   const float* __restrict__ plif_tau,
                   unsigned long long* __restrict__ Hex,   // [2][B][D]
                   unsigned long long* __restrict__ Utag,  // [B][T][D]
                   unsigned short* __restrict__ Sout,      // (B,T,D) bf16
                   const float* __restrict__ ffn_wg, unsigned short* wg_bf,
                   const float* __restrict__ ffn_wu, unsigned short* wu_bf,
                   const float* __restrict__ ffn_wd, unsigned short* wd_bf,
                   const float* __restrict__ gate_w, unsigned short* gw_bf,
                   const float* __restrict__ syn_w,  const void* mask,
                   unsigned short* weff_bf) {
  const int tid = threadIdx.x;

  __shared__ float h_lds[1024];
  __shared__ __align__(16) float red[2][4][8][4];
  __shared__ int flags[2][4];
  __shared__ float red4w[4];
  __shared__ int s_mode;

  if (tid < 8) ((int*)flags)[tid] = 0;
  __syncthreads();

  if (blockIdx.x < 128) {
    // ===================== SCAN PATH ======================================
    const int blk = blockIdx.x;
    const int b = blk >> 5;
    const int base = (blk & 31) * 32;

    if (tid < 256) {
      // ---- matvec waves ----
      const int l = tid & 63, w = tid >> 6;
      const int rg = tid & 7;
      const int ck = tid >> 3;
      const int win = 256 * w;

      float4 wr[4][8];
#pragma unroll
      for (int r = 0; r < 4; ++r) {
        const float* wrow = Wr + (long)(base + rg * 4 + r) * Dsz + ck * 32;
#pragma unroll
        for (int qq = 0; qq < 8; ++qq) {
          int q = (qq + ck) & 7;
          wr[r][qq] = *(const float4*)(wrow + q * 4);
        }
      }

#define ALD(p) __hip_atomic_load((p), __ATOMIC_RELAXED, __HIP_MEMORY_SCOPE_AGENT)
#define TOK(v) ((unsigned)((v) >> 32) == want)

      for (int t = 1; t <= Tsz; ++t) {
        const unsigned want = (unsigned)(t - 1);
        const unsigned long long* src =
            Hex + (((long)((t - 1) & 1) * Bsz + b) << 10) + win;
        unsigned long long a0, a1, a2, a3, b0, b1, b2, b3, c0, c1, c2, c3;
        // pipelined double-poll: keep one round in flight while checking
        // the previous one (compiler waits vmcnt(4), not vmcnt(0)).
        a0 = ALD(src + l); a1 = ALD(src + l + 64);
        a2 = ALD(src + l + 128); a3 = ALD(src + l + 192);
        for (;;) {
          b0 = ALD(src + l); b1 = ALD(src + l + 64);
          b2 = ALD(src + l + 128); b3 = ALD(src + l + 192);
          if (__all(TOK(a0) & TOK(a1) & TOK(a2) & TOK(a3))) {
            c0 = a0; c1 = a1; c2 = a2; c3 = a3; break;
          }
          a0 = ALD(src + l); a1 = ALD(src + l + 64);
          a2 = ALD(src + l + 128); a3 = ALD(src + l + 192);
          if (__all(TOK(b0) & TOK(b1) & TOK(b2) & TOK(b3))) {
            c0 = b0; c1 = b1; c2 = b2; c3 = b3; break;
          }
        }
        // wave-local LDS stage (no barrier: same-wave ds ordering)
        h_lds[win + l]       = __uint_as_float((unsigned)c0);
        h_lds[win + l + 64]  = __uint_as_float((unsigned)c1);
        h_lds[win + l + 128] = __uint_as_float((unsigned)c2);
        h_lds[win + l + 192] = __uint_as_float((unsigned)c3);

        float acc0 = 0.f, acc1 = 0.f, acc2 = 0.f, acc3 = 0.f;
        const float* hch = &h_lds[ck * 32];
#pragma unroll
        for (int qq = 0; qq < 8; ++qq) {
          const int q = (qq + ck) & 7;
          float4 hv = *(const float4*)(hch + q * 4);
          acc0 += wr[0][qq].x * hv.x + wr[0][qq].y * hv.y + wr[0][qq].z * hv.z + wr[0][qq].w * hv.w;
          acc1 += wr[1][qq].x * hv.x + wr[1][qq].y * hv.y + wr[1][qq].z * hv.z + wr[1][qq].w * hv.w;
          acc2 += wr[2][qq].x * hv.x + wr[2][qq].y * hv.y + wr[2][qq].z * hv.z + wr[2][qq].w * hv.w;
          acc3 += wr[3][qq].x * hv.x + wr[3][qq].y * hv.y + wr[3][qq].z * hv.z + wr[3][qq].w * hv.w;
        }
        acc0 += __shfl_xor(acc0, 8); acc0 += __shfl_xor(acc0, 16); acc0 += __shfl_xor(acc0, 32);
        acc1 += __shfl_xor(acc1, 8); acc1 += __shfl_xor(acc1, 16); acc1 += __shfl_xor(acc1, 32);
        acc2 += __shfl_xor(acc2, 8); acc2 += __shfl_xor(acc2, 16); acc2 += __shfl_xor(acc2, 32);
        acc3 += __shfl_xor(acc3, 8); acc3 += __shfl_xor(acc3, 16); acc3 += __shfl_xor(acc3, 32);
        if ((l & 56) == 0) {
          float4 rv; rv.x = acc0; rv.y = acc1; rv.z = acc2; rv.w = acc3;
          *(float4*)&red[t & 1][w][rg][0] = rv;
        }
        asm volatile("s_waitcnt lgkmcnt(0)" ::: "memory");
        if (l == 0)
          __hip_atomic_store(&flags[t & 1][w], t, __ATOMIC_RELEASE,
                             __HIP_MEMORY_SCOPE_WORKGROUP);
      }
#undef ALD
#undef TOK
    } else {
      // ---- scalar wave ----
      const int r = tid - 256;  // active lanes r<32
      float hstate = 0.f, vstate = 0.f, dec = 0.f, omdec = 0.f, itau = 0.f;
      if (r < 32) {
        float tau = liq_tau[base + r];
        dec = expf(-1.0f / tau);
        omdec = 1.0f - dec;
        itau = 1.0f / plif_tau[0];
      }
      for (int t = 1; t <= Tsz; ++t) {
        float uval = 0.f;
        if (r < 32) {   // tagged poll on producer output (usually ready)
          const unsigned long long* up =
              Utag + ((long)b * Tsz + (t - 1)) * Dsz + base + r;
          unsigned long long uv;
          do {
            uv = __hip_atomic_load(up, __ATOMIC_RELAXED, __HIP_MEMORY_SCOPE_AGENT);
          } while ((unsigned)(uv >> 32) != (unsigned)t);
          uval = __uint_as_float((unsigned)uv);
        }
        const int p = t & 1;
        for (;;) {
          int f0 = __hip_atomic_load(&flags[p][0], __ATOMIC_ACQUIRE, __HIP_MEMORY_SCOPE_WORKGROUP);
          int f1 = __hip_atomic_load(&flags[p][1], __ATOMIC_ACQUIRE, __HIP_MEMORY_SCOPE_WORKGROUP);
          int f2 = __hip_atomic_load(&flags[p][2], __ATOMIC_ACQUIRE, __HIP_MEMORY_SCOPE_WORKGROUP);
          int f3 = __hip_atomic_load(&flags[p][3], __ATOMIC_ACQUIRE, __HIP_MEMORY_SCOPE_WORKGROUP);
          if ((f0 == t) & (f1 == t) & (f2 == t) & (f3 == t)) break;
        }
        if (r < 32) {
          const int r2 = r >> 2, jj = r & 3;
          float sum = red[p][0][r2][jj] + red[p][1][r2][jj] +
                      red[p][2][r2][jj] + red[p][3][r2][jj];
          float z = sum + uval;
          float ex = __expf(2.0f * z);
          float f = 1.0f - 2.0f * __builtin_amdgcn_rcpf(ex + 1.0f);
          hstate = hstate * dec + omdec * f;
          vstate += (hstate - vstate) * itau;
          float sp = ((vstate - 0.05f) > 0.f) ? 1.f : 0.f;
          vstate -= sp * 0.05f;
          const long pidx = (((long)p * Bsz + b) << 10) + base + r;
          unsigned long long pv =
              (((unsigned long long)(unsigned)t) << 32) |
              (unsigned long long)__float_as_uint(hstate);
          __hip_atomic_store(&Hex[pidx], pv, __ATOMIC_RELAXED,
                             __HIP_MEMORY_SCOPE_AGENT);
          Sout[((long)b * Tsz + (t - 1)) * Dsz + base + r] =
              (sp > 0.f) ? (unsigned short)0x3F80 : (unsigned short)0;
        }
      }
    }
  } else {
    // ===================== PRODUCER PATH ==================================
    const int blk2 = blockIdx.x - 128;   // 0..127
    const int b = blk2 >> 5;
    const int base = (blk2 & 31) * 32;

    // Wi slice -> registers (same rotated layout as scan's Wr)
    const int l = tid & 63, w = tid >> 6;
    const int rg = tid & 7;
    const int ck = tid >> 3;
    float4 wi[4][8];
    if (tid < 256) {
#pragma unroll
      for (int r = 0; r < 4; ++r) {
        const float* wrow = Wi + (long)(base + rg * 4 + r) * Dsz + ck * 32;
#pragma unroll
        for (int qq = 0; qq < 8; ++qq) {
          int q = (qq + ck) & 7;
          wi[r][qq] = *(const float4*)(wrow + q * 4);
        }
      }
    }
    float4 w4 = (tid < 256) ? ((const float4*)ln1_w)[tid] : float4{0, 0, 0, 0};
    float lb = 0.f;
    if (tid >= 256 && (tid - 256) < 32) lb = liq_b[base + (tid - 256)];

    for (int t = 1; t <= Tsz; ++t) {
      // rmsnorm of x[b,t-1] in-block
      float4 xv = {0, 0, 0, 0};
      if (tid < 256) {
        xv = ((const float4*)(x + ((long)b * Tsz + (t - 1)) * Dsz))[tid];
        float ss = xv.x * xv.x + xv.y * xv.y + xv.z * xv.z + xv.w * xv.w;
#pragma unroll
        for (int off = 32; off > 0; off >>= 1) ss += __shfl_down(ss, off);
        if (l == 0) red4w[w] = ss;
      }
      __syncthreads();
      if (tid < 256) {
        float tot = red4w[0] + red4w[1] + red4w[2] + red4w[3];
        float scale = 1.0f / sqrtf(tot * (1.0f / Dsz) + 1e-6f);
        float4 av;
        av.x = xv.x * scale * w4.x; av.y = xv.y * scale * w4.y;
        av.z = xv.z * scale * w4.z; av.w = xv.w * scale * w4.w;
        ((float4*)h_lds)[tid] = av;
      }
      __syncthreads();
      if (tid < 256) {
        float acc0 = 0.f, acc1 = 0.f, acc2 = 0.f, acc3 = 0.f;
        const float* hch = &h_lds[ck * 32];
#pragma unroll
        for (int qq = 0; qq < 8; ++qq) {
          const int q = (qq + ck) & 7;
          float4 hv = *(const float4*)(hch + q * 4);
          acc0 += wi[0][qq].x * hv.x + wi[0][qq].y * hv.y + wi[0][qq].z * hv.z + wi[0][qq].w * hv.w;
          acc1 += wi[1][qq].x * hv.x + wi[1][qq].y * hv.y + wi[1][qq].z * hv.z + wi[1][qq].w * hv.w;
          acc2 += wi[2][qq].x * hv.x + wi[2][qq].y * hv.y + wi[2][qq].z * hv.z + wi[2][qq].w * hv.w;
          acc3 += wi[3][qq].x * hv.x + wi[3][qq].y * hv.y + wi[3][qq].z * hv.z + wi[3][qq].w * hv.w;
        }
        acc0 += __shfl_xor(acc0, 8); acc0 += __shfl_xor(acc0, 16); acc0 += __shfl_xor(acc0, 32);
        acc1 += __shfl_xor(acc1, 8); acc1 += __shfl_xor(acc1, 16); acc1 += __shfl_xor(acc1, 32);
        acc2 += __shfl_xor(acc2, 8); acc2 += __shfl_xor(acc2, 16); acc2 += __shfl_xor(acc2, 32);
        acc3 += __shfl_xor(acc3, 8); acc3 += __shfl_xor(acc3, 16); acc3 += __shfl_xor(acc3, 32);
        if ((l & 56) == 0) {
          float4 rv; rv.x = acc0; rv.y = acc1; rv.z = acc2; rv.w = acc3;
          *(float4*)&red[0][w][rg][0] = rv;
        }
      }
      __syncthreads();
      if (tid >= 256) {
        const int r = tid - 256;
        if (r < 32) {
          const int r2 = r >> 2, jj = r & 3;
          float sum = red[0][0][r2][jj] + red[0][1][r2][jj] +
                      red[0][2][r2][jj] + red[0][3][r2][jj] + lb;
          unsigned long long pv =
              (((unsigned long long)(unsigned)t) << 32) |
              (unsigned long long)__float_as_uint(sum);
          __hip_atomic_store(&Utag[((long)b * Tsz + (t - 1)) * Dsz + base + r],
                             pv, __ATOMIC_RELAXED, __HIP_MEMORY_SCOPE_AGENT);
        }
      }
      __syncthreads();
    }

    // ---- tail: weight conversions (hidden under the scan) ----------------
    if (tid == 0) {
      int md = 0;
      const unsigned* m = (const unsigned*)mask;
      for (int i = 0; i < 256; ++i) {
        unsigned wd = m[i];
        if (wd == 0x3F800000u) { md = 2; break; }
        if (wd > 1u) md = 1;
      }
      s_mode = md;
    }
    __syncthreads();
    const int md = s_mode;
    const long gtid = (long)blk2 * 320 + tid;
    const long gstr = 128 * 320;
    const int n4big = Hsz * Dsz / 4;      // 2,097,152 float4s
    for (long i = gtid; i < n4big; i += gstr) {
      float4 v = ((const float4*)ffn_wg)[i];
      ushort4 o; o.x = f2bf(v.x); o.y = f2bf(v.y); o.z = f2bf(v.z); o.w = f2bf(v.w);
      ((ushort4*)wg_bf)[i] = o;
      v = ((const float4*)ffn_wu)[i];
      o.x = f2bf(v.x); o.y = f2bf(v.y); o.z = f2bf(v.z); o.w = f2bf(v.w);
      ((ushort4*)wu_bf)[i] = o;
      v = ((const float4*)ffn_wd)[i];
      o.x = f2bf(v.x); o.y = f2bf(v.y); o.z = f2bf(v.z); o.w = f2bf(v.w);
      ((ushort4*)wd_bf)[i] = o;
    }
    const int n4g = Dsz * Dsz / 4;
    for (long i = gtid; i < n4g; i += gstr) {
      float4 v = ((const float4*)gate_w)[i];
      ushort4 o; o.x = f2bf(v.x); o.y = f2bf(v.y); o.z = f2bf(v.z); o.w = f2bf(v.w);
      ((ushort4*)gw_bf)[i] = o;
    }
    const int nw = Dsz * Dsz;
    for (long i = gtid; i < nw; i += gstr) {
      bool on;
      if (md == 1)      on = ((const unsigned char*)mask)[i] != 0;
      else if (md == 2) on = ((const float*)mask)[i] != 0.f;
      else              on = ((const int*)mask)[i] != 0;
      weff_bf[i] = on ? f2bf(syn_w[i]) : (unsigned short)0;
    }
  }
}

// ---- bf16 MFMA GEMM, C = A @ B^T, m97-style 128x128x32 tile ---------------
// A:[M,K] bf16 rm, B:[N,K] bf16 rm. NB: 1 or 2 B-matrices. EPI:
//  1: out f32 = aux0 + acc0 * sigmoid(acc1 + aux1[col])   (syn+gate residual)
//  2: out bf16 = silu(acc0) * acc1                        (FFN gate*up)
//  3: out f32 = aux0 + acc0                               (down + residual)

template<int NB, int EPI>
__global__ __launch_bounds__(256)
void gemm_bt(const unsigned short* __restrict__ A,
             const unsigned short* __restrict__ B0,
             const unsigned short* __restrict__ B1,
             const float* __restrict__ aux0, const float* __restrict__ aux1,
             void* __restrict__ outp, int M, int N, int K) {
  __shared__ unsigned short sA[128 * 32];
  __shared__ unsigned short sB[2 * 128 * 32];
  const int tid = threadIdx.x;
  const int w = tid >> 6, l = tid & 63;
  const int wm = w & 1, wn = w >> 1;
  const int bm = blockIdx.x, bn = blockIdx.y;

  floatx4_t acc[NB][4][4];
#pragma unroll
  for (int j = 0; j < NB; ++j)
#pragma unroll
    for (int m = 0; m < 4; ++m)
#pragma unroll
      for (int n = 0; n < 4; ++n) acc[j][m][n] = (floatx4_t)(0.f);

  const int rA = bm * 128 + 16 * w + (l >> 2);
  const int rB = bn * 128 + 16 * w + (l >> 2);
  const int kl = (l & 3) * 8;
  const unsigned short* gA = A + (long)rA * K + kl;
  const unsigned short* gB0 = B0 + (long)rB * K + kl;
  const unsigned short* gB1 = nullptr;
  if constexpr (NB > 1) gB1 = B1 + (long)rB * K + kl;
  unsigned short* lA = &sA[(16 * w) * 32];
  unsigned short* lB = &sB[(16 * w) * 32];

  for (int k0 = 0; k0 < K; k0 += 32) {
    gll16(gA + k0,              lA);
    gll16(gA + k0 + 64 * K,     lA + 64 * 32);
    gll16(gB0 + k0,             lB);
    gll16(gB0 + k0 + 64 * K,    lB + 64 * 32);
    if constexpr (NB > 1) {
      gll16(gB1 + k0,           lB + 128 * 32);
      gll16(gB1 + k0 + 64 * K,  lB + 192 * 32);
    }
    __syncthreads();
    short8 af[4];
#pragma unroll
    for (int m = 0; m < 4; ++m)
      af[m] = *(const short8*)&sA[(wm * 64 + m * 16 + (l & 15)) * 32 + (l >> 4) * 8];
#pragma unroll
    for (int j = 0; j < NB; ++j) {
#pragma unroll
      for (int n = 0; n < 4; ++n) {
        short8 bf = *(const short8*)&sB[j * 128 * 32 +
                        (wn * 64 + n * 16 + (l & 15)) * 32 + (l >> 4) * 8];
#pragma unroll
        for (int m = 0; m < 4; ++m)
          acc[j][m][n] = __builtin_amdgcn_mfma_f32_16x16x32_bf16(
              af[m], bf, acc[j][m][n], 0, 0, 0);
      }
    }
    __syncthreads();
  }

  const int colBase = bn * 128 + wn * 64;
  const int rowBase = bm * 128 + wm * 64;
#pragma unroll
  for (int m = 0; m < 4; ++m) {
#pragma unroll
    for (int n = 0; n < 4; ++n) {
      const int col = colBase + n * 16 + (l & 15);
#pragma unroll
      for (int j = 0; j < 4; ++j) {
        const int row = rowBase + m * 16 + (l >> 4) * 4 + j;
        const long idx = (long)row * N + col;
        float v0 = acc[0][m][n][j];
        if constexpr (EPI == 1) {
          float gsum = acc[NB - 1][m][n][j] + aux1[col];
          float sg = 1.f / (1.f + __expf(-gsum));
          ((float*)outp)[idx] = aux0[idx] + v0 * sg;
        } else if constexpr (EPI == 2) {
          float sil = v0 / (1.f + __expf(-v0));
          ((unsigned short*)outp)[idx] = f2bf(sil * acc[NB - 1][m][n][j]);
        } else {  // EPI == 3
          ((float*)outp)[idx] = aux0[idx] + v0;
        }
      }
    }
  }
}

// ---------------------------------------------------------------------------

extern "C" void kernel_launch(void* const* d_in, const int* in_sizes, int n_in,
                              void* d_out, int out_size, void* d_ws, size_t ws_size,
                              hipStream_t stream) {
  (void)in_sizes; (void)n_in; (void)out_size; (void)ws_size;

  const float* x        = (const float*)d_in[0];
  const float* ln1_w    = (const float*)d_in[1];
  const float* liq_Wi   = (const float*)d_in[2];
  const float* liq_Wr   = (const float*)d_in[3];
  const float* liq_b    = (const float*)d_in[4];
  const float* liq_tau  = (const float*)d_in[5];
  const float* plif_tau = (const float*)d_in[6];
  const float* syn_w    = (const float*)d_in[7];
  const float* gate_w   = (const float*)d_in[8];
  const float* gate_b   = (const float*)d_in[9];
  const float* ln2_w    = (const float*)d_in[10];
  const float* ffn_wg   = (const float*)d_in[11];
  const float* ffn_wu   = (const float*)d_in[12];
  const float* ffn_wd   = (const float*)d_in[13];
  const void*  mask     = d_in[14];

  char* ws = (char*)d_ws;
  const size_t MB = 1024ull * 1024ull;
  unsigned short* wg_bf   = (unsigned short*)(ws + 0 * MB);    // 16 MB
  unsigned short* wu_bf   = (unsigned short*)(ws + 16 * MB);   // 16 MB
  unsigned short* wd_bf   = (unsigned short*)(ws + 32 * MB);   // 16 MB
  unsigned short* weff_bf = (unsigned short*)(ws + 48 * MB);   // 2 MB
  unsigned short* gw_bf   = (unsigned short*)(ws + 50 * MB);   // 2 MB
  float*          x2_f    = (float*)         (ws + 52 * MB);   // 16 MB
  unsigned short* s_bf    = (unsigned short*)(ws + 68 * MB);   // 8 MB
  unsigned short* y_bf    = (unsigned short*)(ws + 76 * MB);   // 8 MB
  unsigned short* ff_bf   = (unsigned short*)(ws + 84 * MB);   // 64 MB (84-148)
  unsigned long long* Utag= (unsigned long long*)(ws + 84 * MB); // 32 MB,
                                    // overlaps ff_bf: Utag dead before FFN
  unsigned long long* hex = (unsigned long long*)(ws + 148 * MB); // 64 KB
  float*          out_f   = (float*)d_out;

  const int M = Bsz * Tsz;  // 4096

  // Hex ring MUST be zeroed before the scan (poisoned tags would deadlock)
  zero_u64_k<<<32, 256, 0, stream>>>(hex, 2 * Bsz * Dsz);

  // fused: scan (blocks 0-127) + u-producers & weight converts (128-255)
  liquid_plif_k<<<256, 320, 0, stream>>>(
      x, ln1_w, liq_Wi, liq_b, liq_Wr, liq_tau, plif_tau, hex, Utag, s_bf,
      ffn_wg, wg_bf, ffn_wu, wu_bf, ffn_wd, wd_bf, gate_w, gw_bf,
      syn_w, mask, weff_bf);

  // x2 = x + (s@weff^T) * sigmoid(s@gate_w^T + gate_b)
  gemm_bt<2, 1><<<dim3(M / 128, Dsz / 128), 256, 0, stream>>>(
      s_bf, weff_bf, gw_bf, x, gate_b, x2_f, M, Dsz, Dsz);

  // y = rmsnorm(x2, ln2_w) (bf16)
  rmsnorm_k<1><<<M, 256, 0, stream>>>(x2_f, ln2_w, y_bf);

  // ff = silu(y@wg^T) * (y@wu^T)  (bf16)
  gemm_bt<2, 2><<<dim3(M / 128, Hsz / 128), 256, 0, stream>>>(
      y_bf, wg_bf, wu_bf, nullptr, nullptr, ff_bf, M, Hsz, Dsz);

  // out = x2 + ff @ wd^T  (f32)
  gemm_bt<1, 3><<<dim3(M / 128, Dsz / 128), 256, 0, stream>>>(
      ff_bf, wd_bf, nullptr, x2_f, nullptr, out_f, M, Dsz, Hsz);
}

// Round 11
// 2264.036 us; speedup vs baseline: 1.0242x; 1.0242x over previous
//
#include <hip/hip_runtime.h>
#include <math.h>

// ---------------------------------------------------------------------------
// HybridBlock: rmsnorm -> LiquidCell scan -> PLIF scan -> sparse synapse +
// sigmoid gate (residual) -> rmsnorm -> SwiGLU-style FFN (residual).
// B=4, T=1024, D=1024, H=8192.
// ---------------------------------------------------------------------------

#define Bsz 4
#define Tsz 1024
#define Dsz 1024
#define Hsz 8192

typedef __attribute__((ext_vector_type(8))) short short8;
typedef __attribute__((ext_vector_type(4))) float floatx4_t;

// ---- helpers --------------------------------------------------------------

__device__ __forceinline__ unsigned short f2bf(float f) {
  union { float f; unsigned u; } c; c.f = f;
  unsigned x = c.u;
  unsigned r = (x + 0x7FFFu + ((x >> 16) & 1u)) >> 16;   // RNE
  return (unsigned short)r;
}

__device__ __forceinline__ void gll16(const void* gsrc, void* ldst) {
  // async global->LDS, 16B per lane; LDS dest = wave-uniform base + lane*16
  __builtin_amdgcn_global_load_lds(
      (const __attribute__((address_space(1))) unsigned int*)gsrc,
      (__attribute__((address_space(3))) unsigned int*)ldst,
      16, 0, 0);
}

// ---- tiny prep kernels ----------------------------------------------------

__global__ void zero_u64_k(unsigned long long* p, int n) {
  int i = blockIdx.x * 256 + threadIdx.x;
  if (i < n) p[i] = 0ull;
}

// ---- rmsnorm (one block per row of 1024) ----------------------------------

template<int BF16OUT>
__global__ __launch_bounds__(256)
void rmsnorm_k(const float* __restrict__ X, const float* __restrict__ w,
               void* __restrict__ out) {
  const long row = blockIdx.x;
  const float* x = X + row * Dsz;
  float4 v = ((const float4*)x)[threadIdx.x];
  float ss = v.x * v.x + v.y * v.y + v.z * v.z + v.w * v.w;
#pragma unroll
  for (int off = 32; off > 0; off >>= 1) ss += __shfl_down(ss, off);
  __shared__ float red[4];
  if ((threadIdx.x & 63) == 0) red[threadIdx.x >> 6] = ss;
  __syncthreads();
  float tot = red[0] + red[1] + red[2] + red[3];
  float scale = 1.0f / sqrtf(tot * (1.0f / Dsz) + 1e-6f);
  float4 wv = ((const float4*)w)[threadIdx.x];
  float o0 = v.x * scale * wv.x, o1 = v.y * scale * wv.y;
  float o2 = v.z * scale * wv.z, o3 = v.w * scale * wv.w;
  if (BF16OUT) {
    ushort4 o; o.x = f2bf(o0); o.y = f2bf(o1); o.z = f2bf(o2); o.w = f2bf(o3);
    ((ushort4*)out)[row * 256 + threadIdx.x] = o;
  } else {
    float4 o; o.x = o0; o.y = o1; o.z = o2; o.w = o3;
    ((float4*)out)[row * 256 + threadIdx.x] = o;
  }
}

// ---- fused persistent kernel (r7, frozen) ---------------------------------
// 256 blocks x 320 threads.
// Blocks 0..127  : the r3 scan (waves 0-3 matvec + LDS flags, wave 4 scalar
//                  combine/tanh/PLIF/publish); scalar wave's U read is a
//                  tagged-u64 poll on Utag. Exchange = tagged u64 agent-scope
//                  (LLC) stores/loads, depth-2 parity ring, single-round
//                  batched polls (r10's double-poll regressed: LLC is
//                  queue-limited; more outstanding polls = slower).
// Blocks 128..255: producer blocks: stream u = rmsnorm(x)@Wi^T + b as tagged
//                  u64s into Utag (~4x faster than the scan consumes), then
//                  convert all FFN/gate/weff weights to bf16 under the scan.

__global__ __launch_bounds__(320)
void liquid_plif_k(const float* __restrict__ x,
                   const float* __restrict__ ln1_w,
                   const float* __restrict__ Wi,
                   const float* __restrict__ liq_b,
                   const float* __restrict__ Wr,
                   const float* __restrict__ liq_tau,
                   const float* __restrict__ plif_tau,
                   unsigned long long* __restrict__ Hex,   // [2][B][D]
                   unsigned long long* __restrict__ Utag,  // [B][T][D]
                   unsigned short* __restrict__ Sout,      // (B,T,D) bf16
                   const float* __restrict__ ffn_wg, unsigned short* wg_bf,
                   const float* __restrict__ ffn_wu, unsigned short* wu_bf,
                   const float* __restrict__ ffn_wd, unsigned short* wd_bf,
                   const float* __restrict__ gate_w, unsigned short* gw_bf,
                   const float* __restrict__ syn_w,  const void* mask,
                   unsigned short* weff_bf) {
  const int tid = threadIdx.x;

  __shared__ float h_lds[1024];
  __shared__ __align__(16) float red[2][4][8][4];
  __shared__ int flags[2][4];
  __shared__ float red4w[4];
  __shared__ int s_mode;

  if (tid < 8) ((int*)flags)[tid] = 0;
  __syncthreads();

  if (blockIdx.x < 128) {
    // ===================== SCAN PATH ======================================
    const int blk = blockIdx.x;
    const int b = blk >> 5;
    const int base = (blk & 31) * 32;

    if (tid < 256) {
      // ---- matvec waves ----
      const int l = tid & 63, w = tid >> 6;
      const int rg = tid & 7;
      const int ck = tid >> 3;
      const int win = 256 * w;

      float4 wr[4][8];
#pragma unroll
      for (int r = 0; r < 4; ++r) {
        const float* wrow = Wr + (long)(base + rg * 4 + r) * Dsz + ck * 32;
#pragma unroll
        for (int qq = 0; qq < 8; ++qq) {
          int q = (qq + ck) & 7;
          wr[r][qq] = *(const float4*)(wrow + q * 4);
        }
      }

      for (int t = 1; t <= Tsz; ++t) {
        const unsigned want = (unsigned)(t - 1);
        const unsigned long long* src =
            Hex + (((long)((t - 1) & 1) * Bsz + b) << 10) + win;
        unsigned long long a0, a1, a2, a3;
        for (;;) {  // 4 batched loads in flight, one wait, wave-wide check
          a0 = __hip_atomic_load(src + l,       __ATOMIC_RELAXED, __HIP_MEMORY_SCOPE_AGENT);
          a1 = __hip_atomic_load(src + l + 64,  __ATOMIC_RELAXED, __HIP_MEMORY_SCOPE_AGENT);
          a2 = __hip_atomic_load(src + l + 128, __ATOMIC_RELAXED, __HIP_MEMORY_SCOPE_AGENT);
          a3 = __hip_atomic_load(src + l + 192, __ATOMIC_RELAXED, __HIP_MEMORY_SCOPE_AGENT);
          int ok = ((unsigned)(a0 >> 32) == want) & ((unsigned)(a1 >> 32) == want) &
                   ((unsigned)(a2 >> 32) == want) & ((unsigned)(a3 >> 32) == want);
          if (__all(ok)) break;
        }
        // wave-local LDS stage (no barrier: same-wave ds ordering)
        h_lds[win + l]       = __uint_as_float((unsigned)a0);
        h_lds[win + l + 64]  = __uint_as_float((unsigned)a1);
        h_lds[win + l + 128] = __uint_as_float((unsigned)a2);
        h_lds[win + l + 192] = __uint_as_float((unsigned)a3);

        float acc0 = 0.f, acc1 = 0.f, acc2 = 0.f, acc3 = 0.f;
        const float* hch = &h_lds[ck * 32];
#pragma unroll
        for (int qq = 0; qq < 8; ++qq) {
          const int q = (qq + ck) & 7;
          float4 hv = *(const float4*)(hch + q * 4);
          acc0 += wr[0][qq].x * hv.x + wr[0][qq].y * hv.y + wr[0][qq].z * hv.z + wr[0][qq].w * hv.w;
          acc1 += wr[1][qq].x * hv.x + wr[1][qq].y * hv.y + wr[1][qq].z * hv.z + wr[1][qq].w * hv.w;
          acc2 += wr[2][qq].x * hv.x + wr[2][qq].y * hv.y + wr[2][qq].z * hv.z + wr[2][qq].w * hv.w;
          acc3 += wr[3][qq].x * hv.x + wr[3][qq].y * hv.y + wr[3][qq].z * hv.z + wr[3][qq].w * hv.w;
        }
        acc0 += __shfl_xor(acc0, 8); acc0 += __shfl_xor(acc0, 16); acc0 += __shfl_xor(acc0, 32);
        acc1 += __shfl_xor(acc1, 8); acc1 += __shfl_xor(acc1, 16); acc1 += __shfl_xor(acc1, 32);
        acc2 += __shfl_xor(acc2, 8); acc2 += __shfl_xor(acc2, 16); acc2 += __shfl_xor(acc2, 32);
        acc3 += __shfl_xor(acc3, 8); acc3 += __shfl_xor(acc3, 16); acc3 += __shfl_xor(acc3, 32);
        if ((l & 56) == 0) {
          float4 rv; rv.x = acc0; rv.y = acc1; rv.z = acc2; rv.w = acc3;
          *(float4*)&red[t & 1][w][rg][0] = rv;
        }
        asm volatile("s_waitcnt lgkmcnt(0)" ::: "memory");
        if (l == 0)
          __hip_atomic_store(&flags[t & 1][w], t, __ATOMIC_RELEASE,
                             __HIP_MEMORY_SCOPE_WORKGROUP);
      }
    } else {
      // ---- scalar wave ----
      const int r = tid - 256;  // active lanes r<32
      float hstate = 0.f, vstate = 0.f, dec = 0.f, omdec = 0.f, itau = 0.f;
      if (r < 32) {
        float tau = liq_tau[base + r];
        dec = expf(-1.0f / tau);
        omdec = 1.0f - dec;
        itau = 1.0f / plif_tau[0];
      }
      for (int t = 1; t <= Tsz; ++t) {
        float uval = 0.f;
        if (r < 32) {   // tagged poll on producer output (usually ready)
          const unsigned long long* up =
              Utag + ((long)b * Tsz + (t - 1)) * Dsz + base + r;
          unsigned long long uv;
          do {
            uv = __hip_atomic_load(up, __ATOMIC_RELAXED, __HIP_MEMORY_SCOPE_AGENT);
          } while ((unsigned)(uv >> 32) != (unsigned)t);
          uval = __uint_as_float((unsigned)uv);
        }
        const int p = t & 1;
        for (;;) {
          int f0 = __hip_atomic_load(&flags[p][0], __ATOMIC_ACQUIRE, __HIP_MEMORY_SCOPE_WORKGROUP);
          int f1 = __hip_atomic_load(&flags[p][1], __ATOMIC_ACQUIRE, __HIP_MEMORY_SCOPE_WORKGROUP);
          int f2 = __hip_atomic_load(&flags[p][2], __ATOMIC_ACQUIRE, __HIP_MEMORY_SCOPE_WORKGROUP);
          int f3 = __hip_atomic_load(&flags[p][3], __ATOMIC_ACQUIRE, __HIP_MEMORY_SCOPE_WORKGROUP);
          if ((f0 == t) & (f1 == t) & (f2 == t) & (f3 == t)) break;
        }
        if (r < 32) {
          const int r2 = r >> 2, jj = r & 3;
          float sum = red[p][0][r2][jj] + red[p][1][r2][jj] +
                      red[p][2][r2][jj] + red[p][3][r2][jj];
          float z = sum + uval;
          float ex = __expf(2.0f * z);
          float f = 1.0f - 2.0f * __builtin_amdgcn_rcpf(ex + 1.0f);
          hstate = hstate * dec + omdec * f;
          vstate += (hstate - vstate) * itau;
          float sp = ((vstate - 0.05f) > 0.f) ? 1.f : 0.f;
          vstate -= sp * 0.05f;
          const long pidx = (((long)p * Bsz + b) << 10) + base + r;
          unsigned long long pv =
              (((unsigned long long)(unsigned)t) << 32) |
              (unsigned long long)__float_as_uint(hstate);
          __hip_atomic_store(&Hex[pidx], pv, __ATOMIC_RELAXED,
                             __HIP_MEMORY_SCOPE_AGENT);
          Sout[((long)b * Tsz + (t - 1)) * Dsz + base + r] =
              (sp > 0.f) ? (unsigned short)0x3F80 : (unsigned short)0;
        }
      }
    }
  } else {
    // ===================== PRODUCER PATH ==================================
    const int blk2 = blockIdx.x - 128;   // 0..127
    const int b = blk2 >> 5;
    const int base = (blk2 & 31) * 32;

    // Wi slice -> registers (same rotated layout as scan's Wr)
    const int l = tid & 63, w = tid >> 6;
    const int rg = tid & 7;
    const int ck = tid >> 3;
    float4 wi[4][8];
    if (tid < 256) {
#pragma unroll
      for (int r = 0; r < 4; ++r) {
        const float* wrow = Wi + (long)(base + rg * 4 + r) * Dsz + ck * 32;
#pragma unroll
        for (int qq = 0; qq < 8; ++qq) {
          int q = (qq + ck) & 7;
          wi[r][qq] = *(const float4*)(wrow + q * 4);
        }
      }
    }
    float4 w4 = (tid < 256) ? ((const float4*)ln1_w)[tid] : float4{0, 0, 0, 0};
    float lb = 0.f;
    if (tid >= 256 && (tid - 256) < 32) lb = liq_b[base + (tid - 256)];

    for (int t = 1; t <= Tsz; ++t) {
      // rmsnorm of x[b,t-1] in-block
      float4 xv = {0, 0, 0, 0};
      if (tid < 256) {
        xv = ((const float4*)(x + ((long)b * Tsz + (t - 1)) * Dsz))[tid];
        float ss = xv.x * xv.x + xv.y * xv.y + xv.z * xv.z + xv.w * xv.w;
#pragma unroll
        for (int off = 32; off > 0; off >>= 1) ss += __shfl_down(ss, off);
        if (l == 0) red4w[w] = ss;
      }
      __syncthreads();
      if (tid < 256) {
        float tot = red4w[0] + red4w[1] + red4w[2] + red4w[3];
        float scale = 1.0f / sqrtf(tot * (1.0f / Dsz) + 1e-6f);
        float4 av;
        av.x = xv.x * scale * w4.x; av.y = xv.y * scale * w4.y;
        av.z = xv.z * scale * w4.z; av.w = xv.w * scale * w4.w;
        ((float4*)h_lds)[tid] = av;
      }
      __syncthreads();
      if (tid < 256) {
        float acc0 = 0.f, acc1 = 0.f, acc2 = 0.f, acc3 = 0.f;
        const float* hch = &h_lds[ck * 32];
#pragma unroll
        for (int qq = 0; qq < 8; ++qq) {
          const int q = (qq + ck) & 7;
          float4 hv = *(const float4*)(hch + q * 4);
          acc0 += wi[0][qq].x * hv.x + wi[0][qq].y * hv.y + wi[0][qq].z * hv.z + wi[0][qq].w * hv.w;
          acc1 += wi[1][qq].x * hv.x + wi[1][qq].y * hv.y + wi[1][qq].z * hv.z + wi[1][qq].w * hv.w;
          acc2 += wi[2][qq].x * hv.x + wi[2][qq].y * hv.y + wi[2][qq].z * hv.z + wi[2][qq].w * hv.w;
          acc3 += wi[3][qq].x * hv.x + wi[3][qq].y * hv.y + wi[3][qq].z * hv.z + wi[3][qq].w * hv.w;
        }
        acc0 += __shfl_xor(acc0, 8); acc0 += __shfl_xor(acc0, 16); acc0 += __shfl_xor(acc0, 32);
        acc1 += __shfl_xor(acc1, 8); acc1 += __shfl_xor(acc1, 16); acc1 += __shfl_xor(acc1, 32);
        acc2 += __shfl_xor(acc2, 8); acc2 += __shfl_xor(acc2, 16); acc2 += __shfl_xor(acc2, 32);
        acc3 += __shfl_xor(acc3, 8); acc3 += __shfl_xor(acc3, 16); acc3 += __shfl_xor(acc3, 32);
        if ((l & 56) == 0) {
          float4 rv; rv.x = acc0; rv.y = acc1; rv.z = acc2; rv.w = acc3;
          *(float4*)&red[0][w][rg][0] = rv;
        }
      }
      __syncthreads();
      if (tid >= 256) {
        const int r = tid - 256;
        if (r < 32) {
          const int r2 = r >> 2, jj = r & 3;
          float sum = red[0][0][r2][jj] + red[0][1][r2][jj] +
                      red[0][2][r2][jj] + red[0][3][r2][jj] + lb;
          unsigned long long pv =
              (((unsigned long long)(unsigned)t) << 32) |
              (unsigned long long)__float_as_uint(sum);
          __hip_atomic_store(&Utag[((long)b * Tsz + (t - 1)) * Dsz + base + r],
                             pv, __ATOMIC_RELAXED, __HIP_MEMORY_SCOPE_AGENT);
        }
      }
      __syncthreads();
    }

    // ---- tail: weight conversions (hidden under the scan) ----------------
    if (tid == 0) {
      int md = 0;
      const unsigned* m = (const unsigned*)mask;
      for (int i = 0; i < 256; ++i) {
        unsigned wd = m[i];
        if (wd == 0x3F800000u) { md = 2; break; }
        if (wd > 1u) md = 1;
      }
      s_mode = md;
    }
    __syncthreads();
    const int md = s_mode;
    const long gtid = (long)blk2 * 320 + tid;
    const long gstr = 128 * 320;
    const int n4big = Hsz * Dsz / 4;      // 2,097,152 float4s
    for (long i = gtid; i < n4big; i += gstr) {
      float4 v = ((const float4*)ffn_wg)[i];
      ushort4 o; o.x = f2bf(v.x); o.y = f2bf(v.y); o.z = f2bf(v.z); o.w = f2bf(v.w);
      ((ushort4*)wg_bf)[i] = o;
      v = ((const float4*)ffn_wu)[i];
      o.x = f2bf(v.x); o.y = f2bf(v.y); o.z = f2bf(v.z); o.w = f2bf(v.w);
      ((ushort4*)wu_bf)[i] = o;
      v = ((const float4*)ffn_wd)[i];
      o.x = f2bf(v.x); o.y = f2bf(v.y); o.z = f2bf(v.z); o.w = f2bf(v.w);
      ((ushort4*)wd_bf)[i] = o;
    }
    const int n4g = Dsz * Dsz / 4;
    for (long i = gtid; i < n4g; i += gstr) {
      float4 v = ((const float4*)gate_w)[i];
      ushort4 o; o.x = f2bf(v.x); o.y = f2bf(v.y); o.z = f2bf(v.z); o.w = f2bf(v.w);
      ((ushort4*)gw_bf)[i] = o;
    }
    const int nw = Dsz * Dsz;
    for (long i = gtid; i < nw; i += gstr) {
      bool on;
      if (md == 1)      on = ((const unsigned char*)mask)[i] != 0;
      else if (md == 2) on = ((const float*)mask)[i] != 0.f;
      else              on = ((const int*)mask)[i] != 0;
      weff_bf[i] = on ? f2bf(syn_w[i]) : (unsigned short)0;
    }
  }
}

// ---- bf16 MFMA GEMM, C = A @ B^T, m97-style 128x128x32 tile ---------------
// A:[M,K] bf16 rm, B:[N,K] bf16 rm. NB: 1 or 2 B-matrices. EPI:
//  1: out f32 = aux0 + acc0 * sigmoid(acc1 + aux1[col])   (syn+gate residual)
//  2: out bf16 = silu(acc0) * acc1                        (FFN gate*up)
//  3: out f32 = aux0 + acc0                               (down + residual)
// T1 XCD swizzle: flat block id remapped (flat%8)*(nwg/8)+flat/8 (bijective,
// nwg%8==0 for all our grids), x-fastest decomposition -> each XCD owns 8
// consecutive bn panels (2MB B, fits 4MB L2) scanned across all bm.

template<int NB, int EPI>
__global__ __launch_bounds__(256)
void gemm_bt(const unsigned short* __restrict__ A,
             const unsigned short* __restrict__ B0,
             const unsigned short* __restrict__ B1,
             const float* __restrict__ aux0, const float* __restrict__ aux1,
             void* __restrict__ outp, int M, int N, int K) {
  __shared__ unsigned short sA[128 * 32];
  __shared__ unsigned short sB[2 * 128 * 32];
  const int tid = threadIdx.x;
  const int w = tid >> 6, l = tid & 63;
  const int wm = w & 1, wn = w >> 1;

  // XCD-aware swizzle of the flattened block index
  const int nwg = gridDim.x * gridDim.y;
  int flat = blockIdx.x + gridDim.x * blockIdx.y;
  if ((nwg & 7) == 0)
    flat = (flat & 7) * (nwg >> 3) + (flat >> 3);
  const int bm = flat % gridDim.x, bn = flat / gridDim.x;

  floatx4_t acc[NB][4][4];
#pragma unroll
  for (int j = 0; j < NB; ++j)
#pragma unroll
    for (int m = 0; m < 4; ++m)
#pragma unroll
      for (int n = 0; n < 4; ++n) acc[j][m][n] = (floatx4_t)(0.f);

  const int rA = bm * 128 + 16 * w + (l >> 2);
  const int rB = bn * 128 + 16 * w + (l >> 2);
  const int kl = (l & 3) * 8;
  const unsigned short* gA = A + (long)rA * K + kl;
  const unsigned short* gB0 = B0 + (long)rB * K + kl;
  const unsigned short* gB1 = nullptr;
  if constexpr (NB > 1) gB1 = B1 + (long)rB * K + kl;
  unsigned short* lA = &sA[(16 * w) * 32];
  unsigned short* lB = &sB[(16 * w) * 32];

  for (int k0 = 0; k0 < K; k0 += 32) {
    gll16(gA + k0,              lA);
    gll16(gA + k0 + 64 * K,     lA + 64 * 32);
    gll16(gB0 + k0,             lB);
    gll16(gB0 + k0 + 64 * K,    lB + 64 * 32);
    if constexpr (NB > 1) {
      gll16(gB1 + k0,           lB + 128 * 32);
      gll16(gB1 + k0 + 64 * K,  lB + 192 * 32);
    }
    __syncthreads();
    short8 af[4];
#pragma unroll
    for (int m = 0; m < 4; ++m)
      af[m] = *(const short8*)&sA[(wm * 64 + m * 16 + (l & 15)) * 32 + (l >> 4) * 8];
#pragma unroll
    for (int j = 0; j < NB; ++j) {
#pragma unroll
      for (int n = 0; n < 4; ++n) {
        short8 bf = *(const short8*)&sB[j * 128 * 32 +
                        (wn * 64 + n * 16 + (l & 15)) * 32 + (l >> 4) * 8];
#pragma unroll
        for (int m = 0; m < 4; ++m)
          acc[j][m][n] = __builtin_amdgcn_mfma_f32_16x16x32_bf16(
              af[m], bf, acc[j][m][n], 0, 0, 0);
      }
    }
    __syncthreads();
  }

  const int colBase = bn * 128 + wn * 64;
  const int rowBase = bm * 128 + wm * 64;
#pragma unroll
  for (int m = 0; m < 4; ++m) {
#pragma unroll
    for (int n = 0; n < 4; ++n) {
      const int col = colBase + n * 16 + (l & 15);
#pragma unroll
      for (int j = 0; j < 4; ++j) {
        const int row = rowBase + m * 16 + (l >> 4) * 4 + j;
        const long idx = (long)row * N + col;
        float v0 = acc[0][m][n][j];
        if constexpr (EPI == 1) {
          float gsum = acc[NB - 1][m][n][j] + aux1[col];
          float sg = 1.f / (1.f + __expf(-gsum));
          ((float*)outp)[idx] = aux0[idx] + v0 * sg;
        } else if constexpr (EPI == 2) {
          float sil = v0 / (1.f + __expf(-v0));
          ((unsigned short*)outp)[idx] = f2bf(sil * acc[NB - 1][m][n][j]);
        } else {  // EPI == 3
          ((float*)outp)[idx] = aux0[idx] + v0;
        }
      }
    }
  }
}

// ---------------------------------------------------------------------------

extern "C" void kernel_launch(void* const* d_in, const int* in_sizes, int n_in,
                              void* d_out, int out_size, void* d_ws, size_t ws_size,
                              hipStream_t stream) {
  (void)in_sizes; (void)n_in; (void)out_size; (void)ws_size;

  const float* x        = (const float*)d_in[0];
  const float* ln1_w    = (const float*)d_in[1];
  const float* liq_Wi   = (const float*)d_in[2];
  const float* liq_Wr   = (const float*)d_in[3];
  const float* liq_b    = (const float*)d_in[4];
  const float* liq_tau  = (const float*)d_in[5];
  const float* plif_tau = (const float*)d_in[6];
  const float* syn_w    = (const float*)d_in[7];
  const float* gate_w   = (const float*)d_in[8];
  const float* gate_b   = (const float*)d_in[9];
  const float* ln2_w    = (const float*)d_in[10];
  const float* ffn_wg   = (const float*)d_in[11];
  const float* ffn_wu   = (const float*)d_in[12];
  const float* ffn_wd   = (const float*)d_in[13];
  const void*  mask     = d_in[14];

  char* ws = (char*)d_ws;
  const size_t MB = 1024ull * 1024ull;
  unsigned short* wg_bf   = (unsigned short*)(ws + 0 * MB);    // 16 MB
  unsigned short* wu_bf   = (unsigned short*)(ws + 16 * MB);   // 16 MB
  unsigned short* wd_bf   = (unsigned short*)(ws + 32 * MB);   // 16 MB
  unsigned short* weff_bf = (unsigned short*)(ws + 48 * MB);   // 2 MB
  unsigned short* gw_bf   = (unsigned short*)(ws + 50 * MB);   // 2 MB
  float*          x2_f    = (float*)         (ws + 52 * MB);   // 16 MB
  unsigned short* s_bf    = (unsigned short*)(ws + 68 * MB);   // 8 MB
  unsigned short* y_bf    = (unsigned short*)(ws + 76 * MB);   // 8 MB
  unsigned short* ff_bf   = (unsigned short*)(ws + 84 * MB);   // 64 MB (84-148)
  unsigned long long* Utag= (unsigned long long*)(ws + 84 * MB); // 32 MB,
                                    // overlaps ff_bf: Utag dead before FFN
  unsigned long long* hex = (unsigned long long*)(ws + 148 * MB); // 64 KB
  float*          out_f   = (float*)d_out;

  const int M = Bsz * Tsz;  // 4096

  // Hex ring MUST be zeroed before the scan (poisoned tags would deadlock)
  zero_u64_k<<<32, 256, 0, stream>>>(hex, 2 * Bsz * Dsz);

  // fused: scan (blocks 0-127) + u-producers & weight converts (128-255)
  liquid_plif_k<<<256, 320, 0, stream>>>(
      x, ln1_w, liq_Wi, liq_b, liq_Wr, liq_tau, plif_tau, hex, Utag, s_bf,
      ffn_wg, wg_bf, ffn_wu, wu_bf, ffn_wd, wd_bf, gate_w, gw_bf,
      syn_w, mask, weff_bf);

  // x2 = x + (s@weff^T) * sigmoid(s@gate_w^T + gate_b)
  gemm_bt<2, 1><<<dim3(M / 128, Dsz / 128), 256, 0, stream>>>(
      s_bf, weff_bf, gw_bf, x, gate_b, x2_f, M, Dsz, Dsz);

  // y = rmsnorm(x2, ln2_w) (bf16)
  rmsnorm_k<1><<<M, 256, 0, stream>>>(x2_f, ln2_w, y_bf);

  // ff = silu(y@wg^T) * (y@wu^T)  (bf16)
  gemm_bt<2, 2><<<dim3(M / 128, Hsz / 128), 256, 0, stream>>>(
      y_bf, wg_bf, wu_bf, nullptr, nullptr, ff_bf, M, Hsz, Dsz);

  // out = x2 + ff @ wd^T  (f32)
  gemm_bt<1, 3><<<dim3(M / 128, Dsz / 128), 256, 0, stream>>>(
      ff_bf, wd_bf, nullptr, x2_f, nullptr, out_f, M, Dsz, Hsz);
}

// Round 12
// 2197.008 us; speedup vs baseline: 1.0555x; 1.0305x over previous
//
#include <hip/hip_runtime.h>
#include <math.h>

// ---------------------------------------------------------------------------
// HybridBlock: rmsnorm -> LiquidCell scan -> PLIF scan -> sparse synapse +
// sigmoid gate (residual) -> rmsnorm -> SwiGLU-style FFN (residual).
// B=4, T=1024, D=1024, H=8192.
// ---------------------------------------------------------------------------

#define Bsz 4
#define Tsz 1024
#define Dsz 1024
#define Hsz 8192

typedef __attribute__((ext_vector_type(8))) short short8;
typedef __attribute__((ext_vector_type(4))) float floatx4_t;

// ---- helpers --------------------------------------------------------------

__device__ __forceinline__ unsigned short f2bf(float f) {
  union { float f; unsigned u; } c; c.f = f;
  unsigned x = c.u;
  unsigned r = (x + 0x7FFFu + ((x >> 16) & 1u)) >> 16;   // RNE
  return (unsigned short)r;
}

__device__ __forceinline__ void gll16(const void* gsrc, void* ldst) {
  // async global->LDS, 16B per lane; LDS dest = wave-uniform base + lane*16
  __builtin_amdgcn_global_load_lds(
      (const __attribute__((address_space(1))) unsigned int*)gsrc,
      (__attribute__((address_space(3))) unsigned int*)ldst,
      16, 0, 0);
}

// ---- tiny prep kernels ----------------------------------------------------

__global__ void zero_u64_k(unsigned long long* p, int n) {
  int i = blockIdx.x * 256 + threadIdx.x;
  if (i < n) p[i] = 0ull;
}

// ---- rmsnorm (one block per row of 1024) ----------------------------------

template<int BF16OUT>
__global__ __launch_bounds__(256)
void rmsnorm_k(const float* __restrict__ X, const float* __restrict__ w,
               void* __restrict__ out) {
  const long row = blockIdx.x;
  const float* x = X + row * Dsz;
  float4 v = ((const float4*)x)[threadIdx.x];
  float ss = v.x * v.x + v.y * v.y + v.z * v.z + v.w * v.w;
#pragma unroll
  for (int off = 32; off > 0; off >>= 1) ss += __shfl_down(ss, off);
  __shared__ float red[4];
  if ((threadIdx.x & 63) == 0) red[threadIdx.x >> 6] = ss;
  __syncthreads();
  float tot = red[0] + red[1] + red[2] + red[3];
  float scale = 1.0f / sqrtf(tot * (1.0f / Dsz) + 1e-6f);
  float4 wv = ((const float4*)w)[threadIdx.x];
  float o0 = v.x * scale * wv.x, o1 = v.y * scale * wv.y;
  float o2 = v.z * scale * wv.z, o3 = v.w * scale * wv.w;
  if (BF16OUT) {
    ushort4 o; o.x = f2bf(o0); o.y = f2bf(o1); o.z = f2bf(o2); o.w = f2bf(o3);
    ((ushort4*)out)[row * 256 + threadIdx.x] = o;
  } else {
    float4 o; o.x = o0; o.y = o1; o.z = o2; o.w = o3;
    ((float4*)out)[row * 256 + threadIdx.x] = o;
  }
}

// ---- fused persistent kernel (r7, frozen) ---------------------------------
// 256 blocks x 320 threads.
// Blocks 0..127  : the r3 scan (waves 0-3 matvec + LDS flags, wave 4 scalar
//                  combine/tanh/PLIF/publish); scalar wave's U read is a
//                  tagged-u64 poll on Utag. Exchange = tagged u64 agent-scope
//                  (LLC) stores/loads, depth-2 parity ring, single-round
//                  batched polls. FROZEN: six redesigns (L2-local, partials,
//                  redundant combine, fences, double-poll) all regressed.
// Blocks 128..255: producer blocks: stream u = rmsnorm(x)@Wi^T + b as tagged
//                  u64s into Utag (~4x faster than the scan consumes), then
//                  convert all FFN/gate/weff weights to bf16 under the scan.

__global__ __launch_bounds__(320)
void liquid_plif_k(const float* __restrict__ x,
                   const float* __restrict__ ln1_w,
                   const float* __restrict__ Wi,
                   const float* __restrict__ liq_b,
                   const float* __restrict__ Wr,
                   const float* __restrict__ liq_tau,
                   const float* __restrict__ plif_tau,
                   unsigned long long* __restrict__ Hex,   // [2][B][D]
                   unsigned long long* __restrict__ Utag,  // [B][T][D]
                   unsigned short* __restrict__ Sout,      // (B,T,D) bf16
                   const float* __restrict__ ffn_wg, unsigned short* wg_bf,
                   const float* __restrict__ ffn_wu, unsigned short* wu_bf,
                   const float* __restrict__ ffn_wd, unsigned short* wd_bf,
                   const float* __restrict__ gate_w, unsigned short* gw_bf,
                   const float* __restrict__ syn_w,  const void* mask,
                   unsigned short* weff_bf) {
  const int tid = threadIdx.x;

  __shared__ float h_lds[1024];
  __shared__ __align__(16) float red[2][4][8][4];
  __shared__ int flags[2][4];
  __shared__ float red4w[4];
  __shared__ int s_mode;

  if (tid < 8) ((int*)flags)[tid] = 0;
  __syncthreads();

  if (blockIdx.x < 128) {
    // ===================== SCAN PATH ======================================
    const int blk = blockIdx.x;
    const int b = blk >> 5;
    const int base = (blk & 31) * 32;

    if (tid < 256) {
      // ---- matvec waves ----
      const int l = tid & 63, w = tid >> 6;
      const int rg = tid & 7;
      const int ck = tid >> 3;
      const int win = 256 * w;

      float4 wr[4][8];
#pragma unroll
      for (int r = 0; r < 4; ++r) {
        const float* wrow = Wr + (long)(base + rg * 4 + r) * Dsz + ck * 32;
#pragma unroll
        for (int qq = 0; qq < 8; ++qq) {
          int q = (qq + ck) & 7;
          wr[r][qq] = *(const float4*)(wrow + q * 4);
        }
      }

      for (int t = 1; t <= Tsz; ++t) {
        const unsigned want = (unsigned)(t - 1);
        const unsigned long long* src =
            Hex + (((long)((t - 1) & 1) * Bsz + b) << 10) + win;
        unsigned long long a0, a1, a2, a3;
        for (;;) {  // 4 batched loads in flight, one wait, wave-wide check
          a0 = __hip_atomic_load(src + l,       __ATOMIC_RELAXED, __HIP_MEMORY_SCOPE_AGENT);
          a1 = __hip_atomic_load(src + l + 64,  __ATOMIC_RELAXED, __HIP_MEMORY_SCOPE_AGENT);
          a2 = __hip_atomic_load(src + l + 128, __ATOMIC_RELAXED, __HIP_MEMORY_SCOPE_AGENT);
          a3 = __hip_atomic_load(src + l + 192, __ATOMIC_RELAXED, __HIP_MEMORY_SCOPE_AGENT);
          int ok = ((unsigned)(a0 >> 32) == want) & ((unsigned)(a1 >> 32) == want) &
                   ((unsigned)(a2 >> 32) == want) & ((unsigned)(a3 >> 32) == want);
          if (__all(ok)) break;
        }
        // wave-local LDS stage (no barrier: same-wave ds ordering)
        h_lds[win + l]       = __uint_as_float((unsigned)a0);
        h_lds[win + l + 64]  = __uint_as_float((unsigned)a1);
        h_lds[win + l + 128] = __uint_as_float((unsigned)a2);
        h_lds[win + l + 192] = __uint_as_float((unsigned)a3);

        float acc0 = 0.f, acc1 = 0.f, acc2 = 0.f, acc3 = 0.f;
        const float* hch = &h_lds[ck * 32];
#pragma unroll
        for (int qq = 0; qq < 8; ++qq) {
          const int q = (qq + ck) & 7;
          float4 hv = *(const float4*)(hch + q * 4);
          acc0 += wr[0][qq].x * hv.x + wr[0][qq].y * hv.y + wr[0][qq].z * hv.z + wr[0][qq].w * hv.w;
          acc1 += wr[1][qq].x * hv.x + wr[1][qq].y * hv.y + wr[1][qq].z * hv.z + wr[1][qq].w * hv.w;
          acc2 += wr[2][qq].x * hv.x + wr[2][qq].y * hv.y + wr[2][qq].z * hv.z + wr[2][qq].w * hv.w;
          acc3 += wr[3][qq].x * hv.x + wr[3][qq].y * hv.y + wr[3][qq].z * hv.z + wr[3][qq].w * hv.w;
        }
        acc0 += __shfl_xor(acc0, 8); acc0 += __shfl_xor(acc0, 16); acc0 += __shfl_xor(acc0, 32);
        acc1 += __shfl_xor(acc1, 8); acc1 += __shfl_xor(acc1, 16); acc1 += __shfl_xor(acc1, 32);
        acc2 += __shfl_xor(acc2, 8); acc2 += __shfl_xor(acc2, 16); acc2 += __shfl_xor(acc2, 32);
        acc3 += __shfl_xor(acc3, 8); acc3 += __shfl_xor(acc3, 16); acc3 += __shfl_xor(acc3, 32);
        if ((l & 56) == 0) {
          float4 rv; rv.x = acc0; rv.y = acc1; rv.z = acc2; rv.w = acc3;
          *(float4*)&red[t & 1][w][rg][0] = rv;
        }
        asm volatile("s_waitcnt lgkmcnt(0)" ::: "memory");
        if (l == 0)
          __hip_atomic_store(&flags[t & 1][w], t, __ATOMIC_RELEASE,
                             __HIP_MEMORY_SCOPE_WORKGROUP);
      }
    } else {
      // ---- scalar wave ----
      const int r = tid - 256;  // active lanes r<32
      float hstate = 0.f, vstate = 0.f, dec = 0.f, omdec = 0.f, itau = 0.f;
      if (r < 32) {
        float tau = liq_tau[base + r];
        dec = expf(-1.0f / tau);
        omdec = 1.0f - dec;
        itau = 1.0f / plif_tau[0];
      }
      for (int t = 1; t <= Tsz; ++t) {
        float uval = 0.f;
        if (r < 32) {   // tagged poll on producer output (usually ready)
          const unsigned long long* up =
              Utag + ((long)b * Tsz + (t - 1)) * Dsz + base + r;
          unsigned long long uv;
          do {
            uv = __hip_atomic_load(up, __ATOMIC_RELAXED, __HIP_MEMORY_SCOPE_AGENT);
          } while ((unsigned)(uv >> 32) != (unsigned)t);
          uval = __uint_as_float((unsigned)uv);
        }
        const int p = t & 1;
        for (;;) {
          int f0 = __hip_atomic_load(&flags[p][0], __ATOMIC_ACQUIRE, __HIP_MEMORY_SCOPE_WORKGROUP);
          int f1 = __hip_atomic_load(&flags[p][1], __ATOMIC_ACQUIRE, __HIP_MEMORY_SCOPE_WORKGROUP);
          int f2 = __hip_atomic_load(&flags[p][2], __ATOMIC_ACQUIRE, __HIP_MEMORY_SCOPE_WORKGROUP);
          int f3 = __hip_atomic_load(&flags[p][3], __ATOMIC_ACQUIRE, __HIP_MEMORY_SCOPE_WORKGROUP);
          if ((f0 == t) & (f1 == t) & (f2 == t) & (f3 == t)) break;
        }
        if (r < 32) {
          const int r2 = r >> 2, jj = r & 3;
          float sum = red[p][0][r2][jj] + red[p][1][r2][jj] +
                      red[p][2][r2][jj] + red[p][3][r2][jj];
          float z = sum + uval;
          float ex = __expf(2.0f * z);
          float f = 1.0f - 2.0f * __builtin_amdgcn_rcpf(ex + 1.0f);
          hstate = hstate * dec + omdec * f;
          vstate += (hstate - vstate) * itau;
          float sp = ((vstate - 0.05f) > 0.f) ? 1.f : 0.f;
          vstate -= sp * 0.05f;
          const long pidx = (((long)p * Bsz + b) << 10) + base + r;
          unsigned long long pv =
              (((unsigned long long)(unsigned)t) << 32) |
              (unsigned long long)__float_as_uint(hstate);
          __hip_atomic_store(&Hex[pidx], pv, __ATOMIC_RELAXED,
                             __HIP_MEMORY_SCOPE_AGENT);
          Sout[((long)b * Tsz + (t - 1)) * Dsz + base + r] =
              (sp > 0.f) ? (unsigned short)0x3F80 : (unsigned short)0;
        }
      }
    }
  } else {
    // ===================== PRODUCER PATH ==================================
    const int blk2 = blockIdx.x - 128;   // 0..127
    const int b = blk2 >> 5;
    const int base = (blk2 & 31) * 32;

    // Wi slice -> registers (same rotated layout as scan's Wr)
    const int l = tid & 63, w = tid >> 6;
    const int rg = tid & 7;
    const int ck = tid >> 3;
    float4 wi[4][8];
    if (tid < 256) {
#pragma unroll
      for (int r = 0; r < 4; ++r) {
        const float* wrow = Wi + (long)(base + rg * 4 + r) * Dsz + ck * 32;
#pragma unroll
        for (int qq = 0; qq < 8; ++qq) {
          int q = (qq + ck) & 7;
          wi[r][qq] = *(const float4*)(wrow + q * 4);
        }
      }
    }
    float4 w4 = (tid < 256) ? ((const float4*)ln1_w)[tid] : float4{0, 0, 0, 0};
    float lb = 0.f;
    if (tid >= 256 && (tid - 256) < 32) lb = liq_b[base + (tid - 256)];

    for (int t = 1; t <= Tsz; ++t) {
      // rmsnorm of x[b,t-1] in-block
      float4 xv = {0, 0, 0, 0};
      if (tid < 256) {
        xv = ((const float4*)(x + ((long)b * Tsz + (t - 1)) * Dsz))[tid];
        float ss = xv.x * xv.x + xv.y * xv.y + xv.z * xv.z + xv.w * xv.w;
#pragma unroll
        for (int off = 32; off > 0; off >>= 1) ss += __shfl_down(ss, off);
        if (l == 0) red4w[w] = ss;
      }
      __syncthreads();
      if (tid < 256) {
        float tot = red4w[0] + red4w[1] + red4w[2] + red4w[3];
        float scale = 1.0f / sqrtf(tot * (1.0f / Dsz) + 1e-6f);
        float4 av;
        av.x = xv.x * scale * w4.x; av.y = xv.y * scale * w4.y;
        av.z = xv.z * scale * w4.z; av.w = xv.w * scale * w4.w;
        ((float4*)h_lds)[tid] = av;
      }
      __syncthreads();
      if (tid < 256) {
        float acc0 = 0.f, acc1 = 0.f, acc2 = 0.f, acc3 = 0.f;
        const float* hch = &h_lds[ck * 32];
#pragma unroll
        for (int qq = 0; qq < 8; ++qq) {
          const int q = (qq + ck) & 7;
          float4 hv = *(const float4*)(hch + q * 4);
          acc0 += wi[0][qq].x * hv.x + wi[0][qq].y * hv.y + wi[0][qq].z * hv.z + wi[0][qq].w * hv.w;
          acc1 += wi[1][qq].x * hv.x + wi[1][qq].y * hv.y + wi[1][qq].z * hv.z + wi[1][qq].w * hv.w;
          acc2 += wi[2][qq].x * hv.x + wi[2][qq].y * hv.y + wi[2][qq].z * hv.z + wi[2][qq].w * hv.w;
          acc3 += wi[3][qq].x * hv.x + wi[3][qq].y * hv.y + wi[3][qq].z * hv.z + wi[3][qq].w * hv.w;
        }
        acc0 += __shfl_xor(acc0, 8); acc0 += __shfl_xor(acc0, 16); acc0 += __shfl_xor(acc0, 32);
        acc1 += __shfl_xor(acc1, 8); acc1 += __shfl_xor(acc1, 16); acc1 += __shfl_xor(acc1, 32);
        acc2 += __shfl_xor(acc2, 8); acc2 += __shfl_xor(acc2, 16); acc2 += __shfl_xor(acc2, 32);
        acc3 += __shfl_xor(acc3, 8); acc3 += __shfl_xor(acc3, 16); acc3 += __shfl_xor(acc3, 32);
        if ((l & 56) == 0) {
          float4 rv; rv.x = acc0; rv.y = acc1; rv.z = acc2; rv.w = acc3;
          *(float4*)&red[0][w][rg][0] = rv;
        }
      }
      __syncthreads();
      if (tid >= 256) {
        const int r = tid - 256;
        if (r < 32) {
          const int r2 = r >> 2, jj = r & 3;
          float sum = red[0][0][r2][jj] + red[0][1][r2][jj] +
                      red[0][2][r2][jj] + red[0][3][r2][jj] + lb;
          unsigned long long pv =
              (((unsigned long long)(unsigned)t) << 32) |
              (unsigned long long)__float_as_uint(sum);
          __hip_atomic_store(&Utag[((long)b * Tsz + (t - 1)) * Dsz + base + r],
                             pv, __ATOMIC_RELAXED, __HIP_MEMORY_SCOPE_AGENT);
        }
      }
      __syncthreads();
    }

    // ---- tail: weight conversions (hidden under the scan) ----------------
    if (tid == 0) {
      int md = 0;
      const unsigned* m = (const unsigned*)mask;
      for (int i = 0; i < 256; ++i) {
        unsigned wd = m[i];
        if (wd == 0x3F800000u) { md = 2; break; }
        if (wd > 1u) md = 1;
      }
      s_mode = md;
    }
    __syncthreads();
    const int md = s_mode;
    const long gtid = (long)blk2 * 320 + tid;
    const long gstr = 128 * 320;
    const int n4big = Hsz * Dsz / 4;      // 2,097,152 float4s
    for (long i = gtid; i < n4big; i += gstr) {
      float4 v = ((const float4*)ffn_wg)[i];
      ushort4 o; o.x = f2bf(v.x); o.y = f2bf(v.y); o.z = f2bf(v.z); o.w = f2bf(v.w);
      ((ushort4*)wg_bf)[i] = o;
      v = ((const float4*)ffn_wu)[i];
      o.x = f2bf(v.x); o.y = f2bf(v.y); o.z = f2bf(v.z); o.w = f2bf(v.w);
      ((ushort4*)wu_bf)[i] = o;
      v = ((const float4*)ffn_wd)[i];
      o.x = f2bf(v.x); o.y = f2bf(v.y); o.z = f2bf(v.z); o.w = f2bf(v.w);
      ((ushort4*)wd_bf)[i] = o;
    }
    const int n4g = Dsz * Dsz / 4;
    for (long i = gtid; i < n4g; i += gstr) {
      float4 v = ((const float4*)gate_w)[i];
      ushort4 o; o.x = f2bf(v.x); o.y = f2bf(v.y); o.z = f2bf(v.z); o.w = f2bf(v.w);
      ((ushort4*)gw_bf)[i] = o;
    }
    const int nw = Dsz * Dsz;
    for (long i = gtid; i < nw; i += gstr) {
      bool on;
      if (md == 1)      on = ((const unsigned char*)mask)[i] != 0;
      else if (md == 2) on = ((const float*)mask)[i] != 0.f;
      else              on = ((const int*)mask)[i] != 0;
      weff_bf[i] = on ? f2bf(syn_w[i]) : (unsigned short)0;
    }
  }
}

// ---- bf16 MFMA GEMM, C = A @ B^T, m97-style 128x128 tile ------------------
// A:[M,K] bf16 rm, B:[N,K] bf16 rm. NB: 1 or 2 B-matrices.
// KU: K-tiles (of 32) staged per barrier pair. KU=2 halves the barrier-drain
// count (the documented ~20% m97-structure stall) at 32KB LDS for NB=1 —
// used for the K=8192 down-proj. Accumulation order (u=0 then u=1) is
// bitwise identical to KU=1's sequential k0, k0+32 steps.
// EPI 1: out f32 = aux0 + acc0 * sigmoid(acc1 + aux1[col])
// EPI 2: out bf16 = silu(acc0) * acc1
// EPI 3: out f32 = aux0 + acc0

template<int NB, int EPI, int KU>
__global__ __launch_bounds__(256)
void gemm_bt(const unsigned short* __restrict__ A,
             const unsigned short* __restrict__ B0,
             const unsigned short* __restrict__ B1,
             const float* __restrict__ aux0, const float* __restrict__ aux1,
             void* __restrict__ outp, int M, int N, int K) {
  __shared__ unsigned short sA[KU * 128 * 32];
  __shared__ unsigned short sB[KU * NB * 128 * 32];
  const int tid = threadIdx.x;
  const int w = tid >> 6, l = tid & 63;
  const int wm = w & 1, wn = w >> 1;
  const int bm = blockIdx.x, bn = blockIdx.y;

  floatx4_t acc[NB][4][4];
#pragma unroll
  for (int j = 0; j < NB; ++j)
#pragma unroll
    for (int m = 0; m < 4; ++m)
#pragma unroll
      for (int n = 0; n < 4; ++n) acc[j][m][n] = (floatx4_t)(0.f);

  const int rA = bm * 128 + 16 * w + (l >> 2);
  const int rB = bn * 128 + 16 * w + (l >> 2);
  const int kl = (l & 3) * 8;
  const unsigned short* gA = A + (long)rA * K + kl;
  const unsigned short* gB0 = B0 + (long)rB * K + kl;
  const unsigned short* gB1 = nullptr;
  if constexpr (NB > 1) gB1 = B1 + (long)rB * K + kl;
  unsigned short* lA = &sA[(16 * w) * 32];
  unsigned short* lB = &sB[(16 * w) * 32];

  for (int k0 = 0; k0 < K; k0 += 32 * KU) {
#pragma unroll
    for (int u = 0; u < KU; ++u) {
      gll16(gA + k0 + u * 32,             lA + u * 4096);
      gll16(gA + k0 + u * 32 + 64 * K,    lA + u * 4096 + 64 * 32);
      gll16(gB0 + k0 + u * 32,            lB + (u * NB) * 4096);
      gll16(gB0 + k0 + u * 32 + 64 * K,   lB + (u * NB) * 4096 + 64 * 32);
      if constexpr (NB > 1) {
        gll16(gB1 + k0 + u * 32,          lB + (u * NB + 1) * 4096);
        gll16(gB1 + k0 + u * 32 + 64 * K, lB + (u * NB + 1) * 4096 + 64 * 32);
      }
    }
    __syncthreads();
#pragma unroll
    for (int u = 0; u < KU; ++u) {
      short8 af[4];
#pragma unroll
      for (int m = 0; m < 4; ++m)
        af[m] = *(const short8*)&sA[u * 4096 +
                    (wm * 64 + m * 16 + (l & 15)) * 32 + (l >> 4) * 8];
#pragma unroll
      for (int j = 0; j < NB; ++j) {
#pragma unroll
        for (int n = 0; n < 4; ++n) {
          short8 bf = *(const short8*)&sB[(u * NB + j) * 4096 +
                          (wn * 64 + n * 16 + (l & 15)) * 32 + (l >> 4) * 8];
#pragma unroll
          for (int m = 0; m < 4; ++m)
            acc[j][m][n] = __builtin_amdgcn_mfma_f32_16x16x32_bf16(
                af[m], bf, acc[j][m][n], 0, 0, 0);
        }
      }
    }
    __syncthreads();
  }

  const int colBase = bn * 128 + wn * 64;
  const int rowBase = bm * 128 + wm * 64;
#pragma unroll
  for (int m = 0; m < 4; ++m) {
#pragma unroll
    for (int n = 0; n < 4; ++n) {
      const int col = colBase + n * 16 + (l & 15);
#pragma unroll
      for (int j = 0; j < 4; ++j) {
        const int row = rowBase + m * 16 + (l >> 4) * 4 + j;
        const long idx = (long)row * N + col;
        float v0 = acc[0][m][n][j];
        if constexpr (EPI == 1) {
          float gsum = acc[NB - 1][m][n][j] + aux1[col];
          float sg = 1.f / (1.f + __expf(-gsum));
          ((float*)outp)[idx] = aux0[idx] + v0 * sg;
        } else if constexpr (EPI == 2) {
          float sil = v0 / (1.f + __expf(-v0));
          ((unsigned short*)outp)[idx] = f2bf(sil * acc[NB - 1][m][n][j]);
        } else {  // EPI == 3
          ((float*)outp)[idx] = aux0[idx] + v0;
        }
      }
    }
  }
}

// ---------------------------------------------------------------------------

extern "C" void kernel_launch(void* const* d_in, const int* in_sizes, int n_in,
                              void* d_out, int out_size, void* d_ws, size_t ws_size,
                              hipStream_t stream) {
  (void)in_sizes; (void)n_in; (void)out_size; (void)ws_size;

  const float* x        = (const float*)d_in[0];
  const float* ln1_w    = (const float*)d_in[1];
  const float* liq_Wi   = (const float*)d_in[2];
  const float* liq_Wr   = (const float*)d_in[3];
  const float* liq_b    = (const float*)d_in[4];
  const float* liq_tau  = (const float*)d_in[5];
  const float* plif_tau = (const float*)d_in[6];
  const float* syn_w    = (const float*)d_in[7];
  const float* gate_w   = (const float*)d_in[8];
  const float* gate_b   = (const float*)d_in[9];
  const float* ln2_w    = (const float*)d_in[10];
  const float* ffn_wg   = (const float*)d_in[11];
  const float* ffn_wu   = (const float*)d_in[12];
  const float* ffn_wd   = (const float*)d_in[13];
  const void*  mask     = d_in[14];

  char* ws = (char*)d_ws;
  const size_t MB = 1024ull * 1024ull;
  unsigned short* wg_bf   = (unsigned short*)(ws + 0 * MB);    // 16 MB
  unsigned short* wu_bf   = (unsigned short*)(ws + 16 * MB);   // 16 MB
  unsigned short* wd_bf   = (unsigned short*)(ws + 32 * MB);   // 16 MB
  unsigned short* weff_bf = (unsigned short*)(ws + 48 * MB);   // 2 MB
  unsigned short* gw_bf   = (unsigned short*)(ws + 50 * MB);   // 2 MB
  float*          x2_f    = (float*)         (ws + 52 * MB);   // 16 MB
  unsigned short* s_bf    = (unsigned short*)(ws + 68 * MB);   // 8 MB
  unsigned short* y_bf    = (unsigned short*)(ws + 76 * MB);   // 8 MB
  unsigned short* ff_bf   = (unsigned short*)(ws + 84 * MB);   // 64 MB (84-148)
  unsigned long long* Utag= (unsigned long long*)(ws + 84 * MB); // 32 MB,
                                    // overlaps ff_bf: Utag dead before FFN
  unsigned long long* hex = (unsigned long long*)(ws + 148 * MB); // 64 KB
  float*          out_f   = (float*)d_out;

  const int M = Bsz * Tsz;  // 4096

  // Hex ring MUST be zeroed before the scan (poisoned tags would deadlock)
  zero_u64_k<<<32, 256, 0, stream>>>(hex, 2 * Bsz * Dsz);

  // fused: scan (blocks 0-127) + u-producers & weight converts (128-255)
  liquid_plif_k<<<256, 320, 0, stream>>>(
      x, ln1_w, liq_Wi, liq_b, liq_Wr, liq_tau, plif_tau, hex, Utag, s_bf,
      ffn_wg, wg_bf, ffn_wu, wu_bf, ffn_wd, wd_bf, gate_w, gw_bf,
      syn_w, mask, weff_bf);

  // x2 = x + (s@weff^T) * sigmoid(s@gate_w^T + gate_b)
  gemm_bt<2, 1, 1><<<dim3(M / 128, Dsz / 128), 256, 0, stream>>>(
      s_bf, weff_bf, gw_bf, x, gate_b, x2_f, M, Dsz, Dsz);

  // y = rmsnorm(x2, ln2_w) (bf16)
  rmsnorm_k<1><<<M, 256, 0, stream>>>(x2_f, ln2_w, y_bf);

  // ff = silu(y@wg^T) * (y@wu^T)  (bf16)
  gemm_bt<2, 2, 1><<<dim3(M / 128, Hsz / 128), 256, 0, stream>>>(
      y_bf, wg_bf, wu_bf, nullptr, nullptr, ff_bf, M, Hsz, Dsz);

  // out = x2 + ff @ wd^T  (f32; K=8192 -> KU=2 halves barrier drains)
  gemm_bt<1, 3, 2><<<dim3(M / 128, Dsz / 128), 256, 0, stream>>>(
      ff_bf, wd_bf, nullptr, x2_f, nullptr, out_f, M, Dsz, Hsz);
}

// Round 13
// 2152.663 us; speedup vs baseline: 1.0772x; 1.0206x over previous
//
#include <hip/hip_runtime.h>
#include <math.h>

// ---------------------------------------------------------------------------
// HybridBlock: rmsnorm -> LiquidCell scan -> PLIF scan -> sparse synapse +
// sigmoid gate (residual) -> rmsnorm -> SwiGLU-style FFN (residual).
// B=4, T=1024, D=1024, H=8192.
// ---------------------------------------------------------------------------

#define Bsz 4
#define Tsz 1024
#define Dsz 1024
#define Hsz 8192

typedef __attribute__((ext_vector_type(8))) short short8;
typedef __attribute__((ext_vector_type(4))) float floatx4_t;

// ---- helpers --------------------------------------------------------------

__device__ __forceinline__ unsigned short f2bf(float f) {
  union { float f; unsigned u; } c; c.f = f;
  unsigned x = c.u;
  unsigned r = (x + 0x7FFFu + ((x >> 16) & 1u)) >> 16;   // RNE
  return (unsigned short)r;
}

__device__ __forceinline__ void gll16(const void* gsrc, void* ldst) {
  // async global->LDS, 16B per lane; LDS dest = wave-uniform base + lane*16
  __builtin_amdgcn_global_load_lds(
      (const __attribute__((address_space(1))) unsigned int*)gsrc,
      (__attribute__((address_space(3))) unsigned int*)ldst,
      16, 0, 0);
}

// ---- tiny prep kernels ----------------------------------------------------

__global__ void zero_u64_k(unsigned long long* p, int n) {
  int i = blockIdx.x * 256 + threadIdx.x;
  if (i < n) p[i] = 0ull;
}

// ---- rmsnorm (one block per row of 1024) ----------------------------------

template<int BF16OUT>
__global__ __launch_bounds__(256)
void rmsnorm_k(const float* __restrict__ X, const float* __restrict__ w,
               void* __restrict__ out) {
  const long row = blockIdx.x;
  const float* x = X + row * Dsz;
  float4 v = ((const float4*)x)[threadIdx.x];
  float ss = v.x * v.x + v.y * v.y + v.z * v.z + v.w * v.w;
#pragma unroll
  for (int off = 32; off > 0; off >>= 1) ss += __shfl_down(ss, off);
  __shared__ float red[4];
  if ((threadIdx.x & 63) == 0) red[threadIdx.x >> 6] = ss;
  __syncthreads();
  float tot = red[0] + red[1] + red[2] + red[3];
  float scale = 1.0f / sqrtf(tot * (1.0f / Dsz) + 1e-6f);
  float4 wv = ((const float4*)w)[threadIdx.x];
  float o0 = v.x * scale * wv.x, o1 = v.y * scale * wv.y;
  float o2 = v.z * scale * wv.z, o3 = v.w * scale * wv.w;
  if (BF16OUT) {
    ushort4 o; o.x = f2bf(o0); o.y = f2bf(o1); o.z = f2bf(o2); o.w = f2bf(o3);
    ((ushort4*)out)[row * 256 + threadIdx.x] = o;
  } else {
    float4 o; o.x = o0; o.y = o1; o.z = o2; o.w = o3;
    ((float4*)out)[row * 256 + threadIdx.x] = o;
  }
}

// ---- fused persistent kernel (r7, frozen) ---------------------------------
// 256 blocks x 320 threads.
// Blocks 0..127  : the r3 scan (waves 0-3 matvec + LDS flags, wave 4 scalar
//                  combine/tanh/PLIF/publish); scalar wave's U read is a
//                  tagged-u64 poll on Utag. Exchange = tagged u64 agent-scope
//                  (LLC) stores/loads, depth-2 parity ring, single-round
//                  batched polls. FROZEN: six redesigns (L2-local, partials,
//                  redundant combine, fences, double-poll) all regressed.
// Blocks 128..255: producer blocks: stream u = rmsnorm(x)@Wi^T + b as tagged
//                  u64s into Utag (~4x faster than the scan consumes), then
//                  convert all FFN/gate/weff weights to bf16 under the scan.

__global__ __launch_bounds__(320)
void liquid_plif_k(const float* __restrict__ x,
                   const float* __restrict__ ln1_w,
                   const float* __restrict__ Wi,
                   const float* __restrict__ liq_b,
                   const float* __restrict__ Wr,
                   const float* __restrict__ liq_tau,
                   const float* __restrict__ plif_tau,
                   unsigned long long* __restrict__ Hex,   // [2][B][D]
                   unsigned long long* __restrict__ Utag,  // [B][T][D]
                   unsigned short* __restrict__ Sout,      // (B,T,D) bf16
                   const float* __restrict__ ffn_wg, unsigned short* wg_bf,
                   const float* __restrict__ ffn_wu, unsigned short* wu_bf,
                   const float* __restrict__ ffn_wd, unsigned short* wd_bf,
                   const float* __restrict__ gate_w, unsigned short* gw_bf,
                   const float* __restrict__ syn_w,  const void* mask,
                   unsigned short* weff_bf) {
  const int tid = threadIdx.x;

  __shared__ float h_lds[1024];
  __shared__ __align__(16) float red[2][4][8][4];
  __shared__ int flags[2][4];
  __shared__ float red4w[4];
  __shared__ int s_mode;

  if (tid < 8) ((int*)flags)[tid] = 0;
  __syncthreads();

  if (blockIdx.x < 128) {
    // ===================== SCAN PATH ======================================
    const int blk = blockIdx.x;
    const int b = blk >> 5;
    const int base = (blk & 31) * 32;

    if (tid < 256) {
      // ---- matvec waves ----
      const int l = tid & 63, w = tid >> 6;
      const int rg = tid & 7;
      const int ck = tid >> 3;
      const int win = 256 * w;

      float4 wr[4][8];
#pragma unroll
      for (int r = 0; r < 4; ++r) {
        const float* wrow = Wr + (long)(base + rg * 4 + r) * Dsz + ck * 32;
#pragma unroll
        for (int qq = 0; qq < 8; ++qq) {
          int q = (qq + ck) & 7;
          wr[r][qq] = *(const float4*)(wrow + q * 4);
        }
      }

      for (int t = 1; t <= Tsz; ++t) {
        const unsigned want = (unsigned)(t - 1);
        const unsigned long long* src =
            Hex + (((long)((t - 1) & 1) * Bsz + b) << 10) + win;
        unsigned long long a0, a1, a2, a3;
        for (;;) {  // 4 batched loads in flight, one wait, wave-wide check
          a0 = __hip_atomic_load(src + l,       __ATOMIC_RELAXED, __HIP_MEMORY_SCOPE_AGENT);
          a1 = __hip_atomic_load(src + l + 64,  __ATOMIC_RELAXED, __HIP_MEMORY_SCOPE_AGENT);
          a2 = __hip_atomic_load(src + l + 128, __ATOMIC_RELAXED, __HIP_MEMORY_SCOPE_AGENT);
          a3 = __hip_atomic_load(src + l + 192, __ATOMIC_RELAXED, __HIP_MEMORY_SCOPE_AGENT);
          int ok = ((unsigned)(a0 >> 32) == want) & ((unsigned)(a1 >> 32) == want) &
                   ((unsigned)(a2 >> 32) == want) & ((unsigned)(a3 >> 32) == want);
          if (__all(ok)) break;
        }
        // wave-local LDS stage (no barrier: same-wave ds ordering)
        h_lds[win + l]       = __uint_as_float((unsigned)a0);
        h_lds[win + l + 64]  = __uint_as_float((unsigned)a1);
        h_lds[win + l + 128] = __uint_as_float((unsigned)a2);
        h_lds[win + l + 192] = __uint_as_float((unsigned)a3);

        float acc0 = 0.f, acc1 = 0.f, acc2 = 0.f, acc3 = 0.f;
        const float* hch = &h_lds[ck * 32];
#pragma unroll
        for (int qq = 0; qq < 8; ++qq) {
          const int q = (qq + ck) & 7;
          float4 hv = *(const float4*)(hch + q * 4);
          acc0 += wr[0][qq].x * hv.x + wr[0][qq].y * hv.y + wr[0][qq].z * hv.z + wr[0][qq].w * hv.w;
          acc1 += wr[1][qq].x * hv.x + wr[1][qq].y * hv.y + wr[1][qq].z * hv.z + wr[1][qq].w * hv.w;
          acc2 += wr[2][qq].x * hv.x + wr[2][qq].y * hv.y + wr[2][qq].z * hv.z + wr[2][qq].w * hv.w;
          acc3 += wr[3][qq].x * hv.x + wr[3][qq].y * hv.y + wr[3][qq].z * hv.z + wr[3][qq].w * hv.w;
        }
        acc0 += __shfl_xor(acc0, 8); acc0 += __shfl_xor(acc0, 16); acc0 += __shfl_xor(acc0, 32);
        acc1 += __shfl_xor(acc1, 8); acc1 += __shfl_xor(acc1, 16); acc1 += __shfl_xor(acc1, 32);
        acc2 += __shfl_xor(acc2, 8); acc2 += __shfl_xor(acc2, 16); acc2 += __shfl_xor(acc2, 32);
        acc3 += __shfl_xor(acc3, 8); acc3 += __shfl_xor(acc3, 16); acc3 += __shfl_xor(acc3, 32);
        if ((l & 56) == 0) {
          float4 rv; rv.x = acc0; rv.y = acc1; rv.z = acc2; rv.w = acc3;
          *(float4*)&red[t & 1][w][rg][0] = rv;
        }
        asm volatile("s_waitcnt lgkmcnt(0)" ::: "memory");
        if (l == 0)
          __hip_atomic_store(&flags[t & 1][w], t, __ATOMIC_RELEASE,
                             __HIP_MEMORY_SCOPE_WORKGROUP);
      }
    } else {
      // ---- scalar wave ----
      const int r = tid - 256;  // active lanes r<32
      float hstate = 0.f, vstate = 0.f, dec = 0.f, omdec = 0.f, itau = 0.f;
      if (r < 32) {
        float tau = liq_tau[base + r];
        dec = expf(-1.0f / tau);
        omdec = 1.0f - dec;
        itau = 1.0f / plif_tau[0];
      }
      for (int t = 1; t <= Tsz; ++t) {
        float uval = 0.f;
        if (r < 32) {   // tagged poll on producer output (usually ready)
          const unsigned long long* up =
              Utag + ((long)b * Tsz + (t - 1)) * Dsz + base + r;
          unsigned long long uv;
          do {
            uv = __hip_atomic_load(up, __ATOMIC_RELAXED, __HIP_MEMORY_SCOPE_AGENT);
          } while ((unsigned)(uv >> 32) != (unsigned)t);
          uval = __uint_as_float((unsigned)uv);
        }
        const int p = t & 1;
        for (;;) {
          int f0 = __hip_atomic_load(&flags[p][0], __ATOMIC_ACQUIRE, __HIP_MEMORY_SCOPE_WORKGROUP);
          int f1 = __hip_atomic_load(&flags[p][1], __ATOMIC_ACQUIRE, __HIP_MEMORY_SCOPE_WORKGROUP);
          int f2 = __hip_atomic_load(&flags[p][2], __ATOMIC_ACQUIRE, __HIP_MEMORY_SCOPE_WORKGROUP);
          int f3 = __hip_atomic_load(&flags[p][3], __ATOMIC_ACQUIRE, __HIP_MEMORY_SCOPE_WORKGROUP);
          if ((f0 == t) & (f1 == t) & (f2 == t) & (f3 == t)) break;
        }
        if (r < 32) {
          const int r2 = r >> 2, jj = r & 3;
          float sum = red[p][0][r2][jj] + red[p][1][r2][jj] +
                      red[p][2][r2][jj] + red[p][3][r2][jj];
          float z = sum + uval;
          float ex = __expf(2.0f * z);
          float f = 1.0f - 2.0f * __builtin_amdgcn_rcpf(ex + 1.0f);
          hstate = hstate * dec + omdec * f;
          vstate += (hstate - vstate) * itau;
          float sp = ((vstate - 0.05f) > 0.f) ? 1.f : 0.f;
          vstate -= sp * 0.05f;
          const long pidx = (((long)p * Bsz + b) << 10) + base + r;
          unsigned long long pv =
              (((unsigned long long)(unsigned)t) << 32) |
              (unsigned long long)__float_as_uint(hstate);
          __hip_atomic_store(&Hex[pidx], pv, __ATOMIC_RELAXED,
                             __HIP_MEMORY_SCOPE_AGENT);
          Sout[((long)b * Tsz + (t - 1)) * Dsz + base + r] =
              (sp > 0.f) ? (unsigned short)0x3F80 : (unsigned short)0;
        }
      }
    }
  } else {
    // ===================== PRODUCER PATH ==================================
    const int blk2 = blockIdx.x - 128;   // 0..127
    const int b = blk2 >> 5;
    const int base = (blk2 & 31) * 32;

    // Wi slice -> registers (same rotated layout as scan's Wr)
    const int l = tid & 63, w = tid >> 6;
    const int rg = tid & 7;
    const int ck = tid >> 3;
    float4 wi[4][8];
    if (tid < 256) {
#pragma unroll
      for (int r = 0; r < 4; ++r) {
        const float* wrow = Wi + (long)(base + rg * 4 + r) * Dsz + ck * 32;
#pragma unroll
        for (int qq = 0; qq < 8; ++qq) {
          int q = (qq + ck) & 7;
          wi[r][qq] = *(const float4*)(wrow + q * 4);
        }
      }
    }
    float4 w4 = (tid < 256) ? ((const float4*)ln1_w)[tid] : float4{0, 0, 0, 0};
    float lb = 0.f;
    if (tid >= 256 && (tid - 256) < 32) lb = liq_b[base + (tid - 256)];

    for (int t = 1; t <= Tsz; ++t) {
      // rmsnorm of x[b,t-1] in-block
      float4 xv = {0, 0, 0, 0};
      if (tid < 256) {
        xv = ((const float4*)(x + ((long)b * Tsz + (t - 1)) * Dsz))[tid];
        float ss = xv.x * xv.x + xv.y * xv.y + xv.z * xv.z + xv.w * xv.w;
#pragma unroll
        for (int off = 32; off > 0; off >>= 1) ss += __shfl_down(ss, off);
        if (l == 0) red4w[w] = ss;
      }
      __syncthreads();
      if (tid < 256) {
        float tot = red4w[0] + red4w[1] + red4w[2] + red4w[3];
        float scale = 1.0f / sqrtf(tot * (1.0f / Dsz) + 1e-6f);
        float4 av;
        av.x = xv.x * scale * w4.x; av.y = xv.y * scale * w4.y;
        av.z = xv.z * scale * w4.z; av.w = xv.w * scale * w4.w;
        ((float4*)h_lds)[tid] = av;
      }
      __syncthreads();
      if (tid < 256) {
        float acc0 = 0.f, acc1 = 0.f, acc2 = 0.f, acc3 = 0.f;
        const float* hch = &h_lds[ck * 32];
#pragma unroll
        for (int qq = 0; qq < 8; ++qq) {
          const int q = (qq + ck) & 7;
          float4 hv = *(const float4*)(hch + q * 4);
          acc0 += wi[0][qq].x * hv.x + wi[0][qq].y * hv.y + wi[0][qq].z * hv.z + wi[0][qq].w * hv.w;
          acc1 += wi[1][qq].x * hv.x + wi[1][qq].y * hv.y + wi[1][qq].z * hv.z + wi[1][qq].w * hv.w;
          acc2 += wi[2][qq].x * hv.x + wi[2][qq].y * hv.y + wi[2][qq].z * hv.z + wi[2][qq].w * hv.w;
          acc3 += wi[3][qq].x * hv.x + wi[3][qq].y * hv.y + wi[3][qq].z * hv.z + wi[3][qq].w * hv.w;
        }
        acc0 += __shfl_xor(acc0, 8); acc0 += __shfl_xor(acc0, 16); acc0 += __shfl_xor(acc0, 32);
        acc1 += __shfl_xor(acc1, 8); acc1 += __shfl_xor(acc1, 16); acc1 += __shfl_xor(acc1, 32);
        acc2 += __shfl_xor(acc2, 8); acc2 += __shfl_xor(acc2, 16); acc2 += __shfl_xor(acc2, 32);
        acc3 += __shfl_xor(acc3, 8); acc3 += __shfl_xor(acc3, 16); acc3 += __shfl_xor(acc3, 32);
        if ((l & 56) == 0) {
          float4 rv; rv.x = acc0; rv.y = acc1; rv.z = acc2; rv.w = acc3;
          *(float4*)&red[0][w][rg][0] = rv;
        }
      }
      __syncthreads();
      if (tid >= 256) {
        const int r = tid - 256;
        if (r < 32) {
          const int r2 = r >> 2, jj = r & 3;
          float sum = red[0][0][r2][jj] + red[0][1][r2][jj] +
                      red[0][2][r2][jj] + red[0][3][r2][jj] + lb;
          unsigned long long pv =
              (((unsigned long long)(unsigned)t) << 32) |
              (unsigned long long)__float_as_uint(sum);
          __hip_atomic_store(&Utag[((long)b * Tsz + (t - 1)) * Dsz + base + r],
                             pv, __ATOMIC_RELAXED, __HIP_MEMORY_SCOPE_AGENT);
        }
      }
      __syncthreads();
    }

    // ---- tail: weight conversions (hidden under the scan) ----------------
    if (tid == 0) {
      int md = 0;
      const unsigned* m = (const unsigned*)mask;
      for (int i = 0; i < 256; ++i) {
        unsigned wd = m[i];
        if (wd == 0x3F800000u) { md = 2; break; }
        if (wd > 1u) md = 1;
      }
      s_mode = md;
    }
    __syncthreads();
    const int md = s_mode;
    const long gtid = (long)blk2 * 320 + tid;
    const long gstr = 128 * 320;
    const int n4big = Hsz * Dsz / 4;      // 2,097,152 float4s
    for (long i = gtid; i < n4big; i += gstr) {
      float4 v = ((const float4*)ffn_wg)[i];
      ushort4 o; o.x = f2bf(v.x); o.y = f2bf(v.y); o.z = f2bf(v.z); o.w = f2bf(v.w);
      ((ushort4*)wg_bf)[i] = o;
      v = ((const float4*)ffn_wu)[i];
      o.x = f2bf(v.x); o.y = f2bf(v.y); o.z = f2bf(v.z); o.w = f2bf(v.w);
      ((ushort4*)wu_bf)[i] = o;
      v = ((const float4*)ffn_wd)[i];
      o.x = f2bf(v.x); o.y = f2bf(v.y); o.z = f2bf(v.z); o.w = f2bf(v.w);
      ((ushort4*)wd_bf)[i] = o;
    }
    const int n4g = Dsz * Dsz / 4;
    for (long i = gtid; i < n4g; i += gstr) {
      float4 v = ((const float4*)gate_w)[i];
      ushort4 o; o.x = f2bf(v.x); o.y = f2bf(v.y); o.z = f2bf(v.z); o.w = f2bf(v.w);
      ((ushort4*)gw_bf)[i] = o;
    }
    const int nw = Dsz * Dsz;
    for (long i = gtid; i < nw; i += gstr) {
      bool on;
      if (md == 1)      on = ((const unsigned char*)mask)[i] != 0;
      else if (md == 2) on = ((const float*)mask)[i] != 0.f;
      else              on = ((const int*)mask)[i] != 0;
      weff_bf[i] = on ? f2bf(syn_w[i]) : (unsigned short)0;
    }
  }
}

// ---- bf16 MFMA GEMM, C = A @ B^T, m97-style 128x128 tile ------------------
// A:[M,K] bf16 rm, B:[N,K] bf16 rm. NB: 1 or 2 B-matrices.
// KU: K-tiles (of 32) staged per barrier pair. Halves barrier-drain count
// (the documented ~20% m97-structure stall). LDS: NB=1 KU=2 -> 32KB;
// NB=2 KU=2 -> 48KB (3 blocks/CU = the VGPR-imposed bound anyway, so no
// occupancy loss). Accumulation order (u=0 then u=1) is bitwise identical
// to KU=1's sequential k0, k0+32 steps.
// EPI 1: out f32 = aux0 + acc0 * sigmoid(acc1 + aux1[col])
// EPI 2: out bf16 = silu(acc0) * acc1
// EPI 3: out f32 = aux0 + acc0

template<int NB, int EPI, int KU>
__global__ __launch_bounds__(256)
void gemm_bt(const unsigned short* __restrict__ A,
             const unsigned short* __restrict__ B0,
             const unsigned short* __restrict__ B1,
             const float* __restrict__ aux0, const float* __restrict__ aux1,
             void* __restrict__ outp, int M, int N, int K) {
  __shared__ unsigned short sA[KU * 128 * 32];
  __shared__ unsigned short sB[KU * NB * 128 * 32];
  const int tid = threadIdx.x;
  const int w = tid >> 6, l = tid & 63;
  const int wm = w & 1, wn = w >> 1;
  const int bm = blockIdx.x, bn = blockIdx.y;

  floatx4_t acc[NB][4][4];
#pragma unroll
  for (int j = 0; j < NB; ++j)
#pragma unroll
    for (int m = 0; m < 4; ++m)
#pragma unroll
      for (int n = 0; n < 4; ++n) acc[j][m][n] = (floatx4_t)(0.f);

  const int rA = bm * 128 + 16 * w + (l >> 2);
  const int rB = bn * 128 + 16 * w + (l >> 2);
  const int kl = (l & 3) * 8;
  const unsigned short* gA = A + (long)rA * K + kl;
  const unsigned short* gB0 = B0 + (long)rB * K + kl;
  const unsigned short* gB1 = nullptr;
  if constexpr (NB > 1) gB1 = B1 + (long)rB * K + kl;
  unsigned short* lA = &sA[(16 * w) * 32];
  unsigned short* lB = &sB[(16 * w) * 32];

  for (int k0 = 0; k0 < K; k0 += 32 * KU) {
#pragma unroll
    for (int u = 0; u < KU; ++u) {
      gll16(gA + k0 + u * 32,             lA + u * 4096);
      gll16(gA + k0 + u * 32 + 64 * K,    lA + u * 4096 + 64 * 32);
      gll16(gB0 + k0 + u * 32,            lB + (u * NB) * 4096);
      gll16(gB0 + k0 + u * 32 + 64 * K,   lB + (u * NB) * 4096 + 64 * 32);
      if constexpr (NB > 1) {
        gll16(gB1 + k0 + u * 32,          lB + (u * NB + 1) * 4096);
        gll16(gB1 + k0 + u * 32 + 64 * K, lB + (u * NB + 1) * 4096 + 64 * 32);
      }
    }
    __syncthreads();
#pragma unroll
    for (int u = 0; u < KU; ++u) {
      short8 af[4];
#pragma unroll
      for (int m = 0; m < 4; ++m)
        af[m] = *(const short8*)&sA[u * 4096 +
                    (wm * 64 + m * 16 + (l & 15)) * 32 + (l >> 4) * 8];
#pragma unroll
      for (int j = 0; j < NB; ++j) {
#pragma unroll
        for (int n = 0; n < 4; ++n) {
          short8 bf = *(const short8*)&sB[(u * NB + j) * 4096 +
                          (wn * 64 + n * 16 + (l & 15)) * 32 + (l >> 4) * 8];
#pragma unroll
          for (int m = 0; m < 4; ++m)
            acc[j][m][n] = __builtin_amdgcn_mfma_f32_16x16x32_bf16(
                af[m], bf, acc[j][m][n], 0, 0, 0);
        }
      }
    }
    __syncthreads();
  }

  const int colBase = bn * 128 + wn * 64;
  const int rowBase = bm * 128 + wm * 64;
#pragma unroll
  for (int m = 0; m < 4; ++m) {
#pragma unroll
    for (int n = 0; n < 4; ++n) {
      const int col = colBase + n * 16 + (l & 15);
#pragma unroll
      for (int j = 0; j < 4; ++j) {
        const int row = rowBase + m * 16 + (l >> 4) * 4 + j;
        const long idx = (long)row * N + col;
        float v0 = acc[0][m][n][j];
        if constexpr (EPI == 1) {
          float gsum = acc[NB - 1][m][n][j] + aux1[col];
          float sg = 1.f / (1.f + __expf(-gsum));
          ((float*)outp)[idx] = aux0[idx] + v0 * sg;
        } else if constexpr (EPI == 2) {
          float sil = v0 / (1.f + __expf(-v0));
          ((unsigned short*)outp)[idx] = f2bf(sil * acc[NB - 1][m][n][j]);
        } else {  // EPI == 3
          ((float*)outp)[idx] = aux0[idx] + v0;
        }
      }
    }
  }
}

// ---------------------------------------------------------------------------

extern "C" void kernel_launch(void* const* d_in, const int* in_sizes, int n_in,
                              void* d_out, int out_size, void* d_ws, size_t ws_size,
                              hipStream_t stream) {
  (void)in_sizes; (void)n_in; (void)out_size; (void)ws_size;

  const float* x        = (const float*)d_in[0];
  const float* ln1_w    = (const float*)d_in[1];
  const float* liq_Wi   = (const float*)d_in[2];
  const float* liq_Wr   = (const float*)d_in[3];
  const float* liq_b    = (const float*)d_in[4];
  const float* liq_tau  = (const float*)d_in[5];
  const float* plif_tau = (const float*)d_in[6];
  const float* syn_w    = (const float*)d_in[7];
  const float* gate_w   = (const float*)d_in[8];
  const float* gate_b   = (const float*)d_in[9];
  const float* ln2_w    = (const float*)d_in[10];
  const float* ffn_wg   = (const float*)d_in[11];
  const float* ffn_wu   = (const float*)d_in[12];
  const float* ffn_wd   = (const float*)d_in[13];
  const void*  mask     = d_in[14];

  char* ws = (char*)d_ws;
  const size_t MB = 1024ull * 1024ull;
  unsigned short* wg_bf   = (unsigned short*)(ws + 0 * MB);    // 16 MB
  unsigned short* wu_bf   = (unsigned short*)(ws + 16 * MB);   // 16 MB
  unsigned short* wd_bf   = (unsigned short*)(ws + 32 * MB);   // 16 MB
  unsigned short* weff_bf = (unsigned short*)(ws + 48 * MB);   // 2 MB
  unsigned short* gw_bf   = (unsigned short*)(ws + 50 * MB);   // 2 MB
  float*          x2_f    = (float*)         (ws + 52 * MB);   // 16 MB
  unsigned short* s_bf    = (unsigned short*)(ws + 68 * MB);   // 8 MB
  unsigned short* y_bf    = (unsigned short*)(ws + 76 * MB);   // 8 MB
  unsigned short* ff_bf   = (unsigned short*)(ws + 84 * MB);   // 64 MB (84-148)
  unsigned long long* Utag= (unsigned long long*)(ws + 84 * MB); // 32 MB,
                                    // overlaps ff_bf: Utag dead before FFN
  unsigned long long* hex = (unsigned long long*)(ws + 148 * MB); // 64 KB
  float*          out_f   = (float*)d_out;

  const int M = Bsz * Tsz;  // 4096

  // Hex ring MUST be zeroed before the scan (poisoned tags would deadlock)
  zero_u64_k<<<32, 256, 0, stream>>>(hex, 2 * Bsz * Dsz);

  // fused: scan (blocks 0-127) + u-producers & weight converts (128-255)
  liquid_plif_k<<<256, 320, 0, stream>>>(
      x, ln1_w, liq_Wi, liq_b, liq_Wr, liq_tau, plif_tau, hex, Utag, s_bf,
      ffn_wg, wg_bf, ffn_wu, wu_bf, ffn_wd, wd_bf, gate_w, gw_bf,
      syn_w, mask, weff_bf);

  // x2 = x + (s@weff^T) * sigmoid(s@gate_w^T + gate_b)
  gemm_bt<2, 1, 2><<<dim3(M / 128, Dsz / 128), 256, 0, stream>>>(
      s_bf, weff_bf, gw_bf, x, gate_b, x2_f, M, Dsz, Dsz);

  // y = rmsnorm(x2, ln2_w) (bf16)
  rmsnorm_k<1><<<M, 256, 0, stream>>>(x2_f, ln2_w, y_bf);

  // ff = silu(y@wg^T) * (y@wu^T)  (bf16; KU=2 halves barrier drains)
  gemm_bt<2, 2, 2><<<dim3(M / 128, Hsz / 128), 256, 0, stream>>>(
      y_bf, wg_bf, wu_bf, nullptr, nullptr, ff_bf, M, Hsz, Dsz);

  // out = x2 + ff @ wd^T  (f32; K=8192 -> KU=2 halves barrier drains)
  gemm_bt<1, 3, 2><<<dim3(M / 128, Dsz / 128), 256, 0, stream>>>(
      ff_bf, wd_bf, nullptr, x2_f, nullptr, out_f, M, Dsz, Hsz);
}

// Round 14
// 2102.347 us; speedup vs baseline: 1.1030x; 1.0239x over previous
//
#include <hip/hip_runtime.h>
#include <math.h>

// ---------------------------------------------------------------------------
// HybridBlock: rmsnorm -> LiquidCell scan -> PLIF scan -> sparse synapse +
// sigmoid gate (residual) -> rmsnorm -> SwiGLU-style FFN (residual).
// B=4, T=1024, D=1024, H=8192.
// ---------------------------------------------------------------------------

#define Bsz 4
#define Tsz 1024
#define Dsz 1024
#define Hsz 8192

typedef __attribute__((ext_vector_type(8))) short short8;
typedef __attribute__((ext_vector_type(4))) float floatx4_t;

// ---- helpers --------------------------------------------------------------

__device__ __forceinline__ unsigned short f2bf(float f) {
  union { float f; unsigned u; } c; c.f = f;
  unsigned x = c.u;
  unsigned r = (x + 0x7FFFu + ((x >> 16) & 1u)) >> 16;   // RNE
  return (unsigned short)r;
}

__device__ __forceinline__ void gll16(const void* gsrc, void* ldst) {
  // async global->LDS, 16B per lane; LDS dest = wave-uniform base + lane*16
  __builtin_amdgcn_global_load_lds(
      (const __attribute__((address_space(1))) unsigned int*)gsrc,
      (__attribute__((address_space(3))) unsigned int*)ldst,
      16, 0, 0);
}

// ---- tiny prep kernels ----------------------------------------------------

__global__ void zero_u64_k(unsigned long long* p, int n) {
  int i = blockIdx.x * 256 + threadIdx.x;
  if (i < n) p[i] = 0ull;
}

// combine split-K partials + residual: out = x2 + p0 + p1 (f32, float4)
__global__ __launch_bounds__(256)
void combine_k(const float* __restrict__ x2, const float* __restrict__ p0,
               const float* __restrict__ p1, float* __restrict__ out) {
  const long i = (long)blockIdx.x * 256 + threadIdx.x;
  float4 a = ((const float4*)x2)[i];
  float4 b = ((const float4*)p0)[i];
  float4 c = ((const float4*)p1)[i];
  float4 o;
  o.x = a.x + (b.x + c.x); o.y = a.y + (b.y + c.y);
  o.z = a.z + (b.z + c.z); o.w = a.w + (b.w + c.w);
  ((float4*)out)[i] = o;
}

// ---- rmsnorm (one block per row of 1024) ----------------------------------

template<int BF16OUT>
__global__ __launch_bounds__(256)
void rmsnorm_k(const float* __restrict__ X, const float* __restrict__ w,
               void* __restrict__ out) {
  const long row = blockIdx.x;
  const float* x = X + row * Dsz;
  float4 v = ((const float4*)x)[threadIdx.x];
  float ss = v.x * v.x + v.y * v.y + v.z * v.z + v.w * v.w;
#pragma unroll
  for (int off = 32; off > 0; off >>= 1) ss += __shfl_down(ss, off);
  __shared__ float red[4];
  if ((threadIdx.x & 63) == 0) red[threadIdx.x >> 6] = ss;
  __syncthreads();
  float tot = red[0] + red[1] + red[2] + red[3];
  float scale = 1.0f / sqrtf(tot * (1.0f / Dsz) + 1e-6f);
  float4 wv = ((const float4*)w)[threadIdx.x];
  float o0 = v.x * scale * wv.x, o1 = v.y * scale * wv.y;
  float o2 = v.z * scale * wv.z, o3 = v.w * scale * wv.w;
  if (BF16OUT) {
    ushort4 o; o.x = f2bf(o0); o.y = f2bf(o1); o.z = f2bf(o2); o.w = f2bf(o3);
    ((ushort4*)out)[row * 256 + threadIdx.x] = o;
  } else {
    float4 o; o.x = o0; o.y = o1; o.z = o2; o.w = o3;
    ((float4*)out)[row * 256 + threadIdx.x] = o;
  }
}

// ---- fused persistent kernel (r7, frozen) ---------------------------------
// 256 blocks x 320 threads.
// Blocks 0..127  : the r3 scan (waves 0-3 matvec + LDS flags, wave 4 scalar
//                  combine/tanh/PLIF/publish); scalar wave's U read is a
//                  tagged-u64 poll on Utag. Exchange = tagged u64 agent-scope
//                  (LLC) stores/loads, depth-2 parity ring, single-round
//                  batched polls. FROZEN: six redesigns (L2-local, partials,
//                  redundant combine, fences, double-poll) all regressed.
// Blocks 128..255: producer blocks: stream u = rmsnorm(x)@Wi^T + b as tagged
//                  u64s into Utag (~4x faster than the scan consumes), then
//                  convert all FFN/gate/weff weights to bf16 under the scan.

__global__ __launch_bounds__(320)
void liquid_plif_k(const float* __restrict__ x,
                   const float* __restrict__ ln1_w,
                   const float* __restrict__ Wi,
                   const float* __restrict__ liq_b,
                   const float* __restrict__ Wr,
                   const float* __restrict__ liq_tau,
                   const float* __restrict__ plif_tau,
                   unsigned long long* __restrict__ Hex,   // [2][B][D]
                   unsigned long long* __restrict__ Utag,  // [B][T][D]
                   unsigned short* __restrict__ Sout,      // (B,T,D) bf16
                   const float* __restrict__ ffn_wg, unsigned short* wg_bf,
                   const float* __restrict__ ffn_wu, unsigned short* wu_bf,
                   const float* __restrict__ ffn_wd, unsigned short* wd_bf,
                   const float* __restrict__ gate_w, unsigned short* gw_bf,
                   const float* __restrict__ syn_w,  const void* mask,
                   unsigned short* weff_bf) {
  const int tid = threadIdx.x;

  __shared__ float h_lds[1024];
  __shared__ __align__(16) float red[2][4][8][4];
  __shared__ int flags[2][4];
  __shared__ float red4w[4];
  __shared__ int s_mode;

  if (tid < 8) ((int*)flags)[tid] = 0;
  __syncthreads();

  if (blockIdx.x < 128) {
    // ===================== SCAN PATH ======================================
    const int blk = blockIdx.x;
    const int b = blk >> 5;
    const int base = (blk & 31) * 32;

    if (tid < 256) {
      // ---- matvec waves ----
      const int l = tid & 63, w = tid >> 6;
      const int rg = tid & 7;
      const int ck = tid >> 3;
      const int win = 256 * w;

      float4 wr[4][8];
#pragma unroll
      for (int r = 0; r < 4; ++r) {
        const float* wrow = Wr + (long)(base + rg * 4 + r) * Dsz + ck * 32;
#pragma unroll
        for (int qq = 0; qq < 8; ++qq) {
          int q = (qq + ck) & 7;
          wr[r][qq] = *(const float4*)(wrow + q * 4);
        }
      }

      for (int t = 1; t <= Tsz; ++t) {
        const unsigned want = (unsigned)(t - 1);
        const unsigned long long* src =
            Hex + (((long)((t - 1) & 1) * Bsz + b) << 10) + win;
        unsigned long long a0, a1, a2, a3;
        for (;;) {  // 4 batched loads in flight, one wait, wave-wide check
          a0 = __hip_atomic_load(src + l,       __ATOMIC_RELAXED, __HIP_MEMORY_SCOPE_AGENT);
          a1 = __hip_atomic_load(src + l + 64,  __ATOMIC_RELAXED, __HIP_MEMORY_SCOPE_AGENT);
          a2 = __hip_atomic_load(src + l + 128, __ATOMIC_RELAXED, __HIP_MEMORY_SCOPE_AGENT);
          a3 = __hip_atomic_load(src + l + 192, __ATOMIC_RELAXED, __HIP_MEMORY_SCOPE_AGENT);
          int ok = ((unsigned)(a0 >> 32) == want) & ((unsigned)(a1 >> 32) == want) &
                   ((unsigned)(a2 >> 32) == want) & ((unsigned)(a3 >> 32) == want);
          if (__all(ok)) break;
        }
        // wave-local LDS stage (no barrier: same-wave ds ordering)
        h_lds[win + l]       = __uint_as_float((unsigned)a0);
        h_lds[win + l + 64]  = __uint_as_float((unsigned)a1);
        h_lds[win + l + 128] = __uint_as_float((unsigned)a2);
        h_lds[win + l + 192] = __uint_as_float((unsigned)a3);

        float acc0 = 0.f, acc1 = 0.f, acc2 = 0.f, acc3 = 0.f;
        const float* hch = &h_lds[ck * 32];
#pragma unroll
        for (int qq = 0; qq < 8; ++qq) {
          const int q = (qq + ck) & 7;
          float4 hv = *(const float4*)(hch + q * 4);
          acc0 += wr[0][qq].x * hv.x + wr[0][qq].y * hv.y + wr[0][qq].z * hv.z + wr[0][qq].w * hv.w;
          acc1 += wr[1][qq].x * hv.x + wr[1][qq].y * hv.y + wr[1][qq].z * hv.z + wr[1][qq].w * hv.w;
          acc2 += wr[2][qq].x * hv.x + wr[2][qq].y * hv.y + wr[2][qq].z * hv.z + wr[2][qq].w * hv.w;
          acc3 += wr[3][qq].x * hv.x + wr[3][qq].y * hv.y + wr[3][qq].z * hv.z + wr[3][qq].w * hv.w;
        }
        acc0 += __shfl_xor(acc0, 8); acc0 += __shfl_xor(acc0, 16); acc0 += __shfl_xor(acc0, 32);
        acc1 += __shfl_xor(acc1, 8); acc1 += __shfl_xor(acc1, 16); acc1 += __shfl_xor(acc1, 32);
        acc2 += __shfl_xor(acc2, 8); acc2 += __shfl_xor(acc2, 16); acc2 += __shfl_xor(acc2, 32);
        acc3 += __shfl_xor(acc3, 8); acc3 += __shfl_xor(acc3, 16); acc3 += __shfl_xor(acc3, 32);
        if ((l & 56) == 0) {
          float4 rv; rv.x = acc0; rv.y = acc1; rv.z = acc2; rv.w = acc3;
          *(float4*)&red[t & 1][w][rg][0] = rv;
        }
        asm volatile("s_waitcnt lgkmcnt(0)" ::: "memory");
        if (l == 0)
          __hip_atomic_store(&flags[t & 1][w], t, __ATOMIC_RELEASE,
                             __HIP_MEMORY_SCOPE_WORKGROUP);
      }
    } else {
      // ---- scalar wave ----
      const int r = tid - 256;  // active lanes r<32
      float hstate = 0.f, vstate = 0.f, dec = 0.f, omdec = 0.f, itau = 0.f;
      if (r < 32) {
        float tau = liq_tau[base + r];
        dec = expf(-1.0f / tau);
        omdec = 1.0f - dec;
        itau = 1.0f / plif_tau[0];
      }
      for (int t = 1; t <= Tsz; ++t) {
        float uval = 0.f;
        if (r < 32) {   // tagged poll on producer output (usually ready)
          const unsigned long long* up =
              Utag + ((long)b * Tsz + (t - 1)) * Dsz + base + r;
          unsigned long long uv;
          do {
            uv = __hip_atomic_load(up, __ATOMIC_RELAXED, __HIP_MEMORY_SCOPE_AGENT);
          } while ((unsigned)(uv >> 32) != (unsigned)t);
          uval = __uint_as_float((unsigned)uv);
        }
        const int p = t & 1;
        for (;;) {
          int f0 = __hip_atomic_load(&flags[p][0], __ATOMIC_ACQUIRE, __HIP_MEMORY_SCOPE_WORKGROUP);
          int f1 = __hip_atomic_load(&flags[p][1], __ATOMIC_ACQUIRE, __HIP_MEMORY_SCOPE_WORKGROUP);
          int f2 = __hip_atomic_load(&flags[p][2], __ATOMIC_ACQUIRE, __HIP_MEMORY_SCOPE_WORKGROUP);
          int f3 = __hip_atomic_load(&flags[p][3], __ATOMIC_ACQUIRE, __HIP_MEMORY_SCOPE_WORKGROUP);
          if ((f0 == t) & (f1 == t) & (f2 == t) & (f3 == t)) break;
        }
        if (r < 32) {
          const int r2 = r >> 2, jj = r & 3;
          float sum = red[p][0][r2][jj] + red[p][1][r2][jj] +
                      red[p][2][r2][jj] + red[p][3][r2][jj];
          float z = sum + uval;
          float ex = __expf(2.0f * z);
          float f = 1.0f - 2.0f * __builtin_amdgcn_rcpf(ex + 1.0f);
          hstate = hstate * dec + omdec * f;
          vstate += (hstate - vstate) * itau;
          float sp = ((vstate - 0.05f) > 0.f) ? 1.f : 0.f;
          vstate -= sp * 0.05f;
          const long pidx = (((long)p * Bsz + b) << 10) + base + r;
          unsigned long long pv =
              (((unsigned long long)(unsigned)t) << 32) |
              (unsigned long long)__float_as_uint(hstate);
          __hip_atomic_store(&Hex[pidx], pv, __ATOMIC_RELAXED,
                             __HIP_MEMORY_SCOPE_AGENT);
          Sout[((long)b * Tsz + (t - 1)) * Dsz + base + r] =
              (sp > 0.f) ? (unsigned short)0x3F80 : (unsigned short)0;
        }
      }
    }
  } else {
    // ===================== PRODUCER PATH ==================================
    const int blk2 = blockIdx.x - 128;   // 0..127
    const int b = blk2 >> 5;
    const int base = (blk2 & 31) * 32;

    // Wi slice -> registers (same rotated layout as scan's Wr)
    const int l = tid & 63, w = tid >> 6;
    const int rg = tid & 7;
    const int ck = tid >> 3;
    float4 wi[4][8];
    if (tid < 256) {
#pragma unroll
      for (int r = 0; r < 4; ++r) {
        const float* wrow = Wi + (long)(base + rg * 4 + r) * Dsz + ck * 32;
#pragma unroll
        for (int qq = 0; qq < 8; ++qq) {
          int q = (qq + ck) & 7;
          wi[r][qq] = *(const float4*)(wrow + q * 4);
        }
      }
    }
    float4 w4 = (tid < 256) ? ((const float4*)ln1_w)[tid] : float4{0, 0, 0, 0};
    float lb = 0.f;
    if (tid >= 256 && (tid - 256) < 32) lb = liq_b[base + (tid - 256)];

    for (int t = 1; t <= Tsz; ++t) {
      // rmsnorm of x[b,t-1] in-block
      float4 xv = {0, 0, 0, 0};
      if (tid < 256) {
        xv = ((const float4*)(x + ((long)b * Tsz + (t - 1)) * Dsz))[tid];
        float ss = xv.x * xv.x + xv.y * xv.y + xv.z * xv.z + xv.w * xv.w;
#pragma unroll
        for (int off = 32; off > 0; off >>= 1) ss += __shfl_down(ss, off);
        if (l == 0) red4w[w] = ss;
      }
      __syncthreads();
      if (tid < 256) {
        float tot = red4w[0] + red4w[1] + red4w[2] + red4w[3];
        float scale = 1.0f / sqrtf(tot * (1.0f / Dsz) + 1e-6f);
        float4 av;
        av.x = xv.x * scale * w4.x; av.y = xv.y * scale * w4.y;
        av.z = xv.z * scale * w4.z; av.w = xv.w * scale * w4.w;
        ((float4*)h_lds)[tid] = av;
      }
      __syncthreads();
      if (tid < 256) {
        float acc0 = 0.f, acc1 = 0.f, acc2 = 0.f, acc3 = 0.f;
        const float* hch = &h_lds[ck * 32];
#pragma unroll
        for (int qq = 0; qq < 8; ++qq) {
          const int q = (qq + ck) & 7;
          float4 hv = *(const float4*)(hch + q * 4);
          acc0 += wi[0][qq].x * hv.x + wi[0][qq].y * hv.y + wi[0][qq].z * hv.z + wi[0][qq].w * hv.w;
          acc1 += wi[1][qq].x * hv.x + wi[1][qq].y * hv.y + wi[1][qq].z * hv.z + wi[1][qq].w * hv.w;
          acc2 += wi[2][qq].x * hv.x + wi[2][qq].y * hv.y + wi[2][qq].z * hv.z + wi[2][qq].w * hv.w;
          acc3 += wi[3][qq].x * hv.x + wi[3][qq].y * hv.y + wi[3][qq].z * hv.z + wi[3][qq].w * hv.w;
        }
        acc0 += __shfl_xor(acc0, 8); acc0 += __shfl_xor(acc0, 16); acc0 += __shfl_xor(acc0, 32);
        acc1 += __shfl_xor(acc1, 8); acc1 += __shfl_xor(acc1, 16); acc1 += __shfl_xor(acc1, 32);
        acc2 += __shfl_xor(acc2, 8); acc2 += __shfl_xor(acc2, 16); acc2 += __shfl_xor(acc2, 32);
        acc3 += __shfl_xor(acc3, 8); acc3 += __shfl_xor(acc3, 16); acc3 += __shfl_xor(acc3, 32);
        if ((l & 56) == 0) {
          float4 rv; rv.x = acc0; rv.y = acc1; rv.z = acc2; rv.w = acc3;
          *(float4*)&red[0][w][rg][0] = rv;
        }
      }
      __syncthreads();
      if (tid >= 256) {
        const int r = tid - 256;
        if (r < 32) {
          const int r2 = r >> 2, jj = r & 3;
          float sum = red[0][0][r2][jj] + red[0][1][r2][jj] +
                      red[0][2][r2][jj] + red[0][3][r2][jj] + lb;
          unsigned long long pv =
              (((unsigned long long)(unsigned)t) << 32) |
              (unsigned long long)__float_as_uint(sum);
          __hip_atomic_store(&Utag[((long)b * Tsz + (t - 1)) * Dsz + base + r],
                             pv, __ATOMIC_RELAXED, __HIP_MEMORY_SCOPE_AGENT);
        }
      }
      __syncthreads();
    }

    // ---- tail: weight conversions (hidden under the scan) ----------------
    if (tid == 0) {
      int md = 0;
      const unsigned* m = (const unsigned*)mask;
      for (int i = 0; i < 256; ++i) {
        unsigned wd = m[i];
        if (wd == 0x3F800000u) { md = 2; break; }
        if (wd > 1u) md = 1;
      }
      s_mode = md;
    }
    __syncthreads();
    const int md = s_mode;
    const long gtid = (long)blk2 * 320 + tid;
    const long gstr = 128 * 320;
    const int n4big = Hsz * Dsz / 4;      // 2,097,152 float4s
    for (long i = gtid; i < n4big; i += gstr) {
      float4 v = ((const float4*)ffn_wg)[i];
      ushort4 o; o.x = f2bf(v.x); o.y = f2bf(v.y); o.z = f2bf(v.z); o.w = f2bf(v.w);
      ((ushort4*)wg_bf)[i] = o;
      v = ((const float4*)ffn_wu)[i];
      o.x = f2bf(v.x); o.y = f2bf(v.y); o.z = f2bf(v.z); o.w = f2bf(v.w);
      ((ushort4*)wu_bf)[i] = o;
      v = ((const float4*)ffn_wd)[i];
      o.x = f2bf(v.x); o.y = f2bf(v.y); o.z = f2bf(v.z); o.w = f2bf(v.w);
      ((ushort4*)wd_bf)[i] = o;
    }
    const int n4g = Dsz * Dsz / 4;
    for (long i = gtid; i < n4g; i += gstr) {
      float4 v = ((const float4*)gate_w)[i];
      ushort4 o; o.x = f2bf(v.x); o.y = f2bf(v.y); o.z = f2bf(v.z); o.w = f2bf(v.w);
      ((ushort4*)gw_bf)[i] = o;
    }
    const int nw = Dsz * Dsz;
    for (long i = gtid; i < nw; i += gstr) {
      bool on;
      if (md == 1)      on = ((const unsigned char*)mask)[i] != 0;
      else if (md == 2) on = ((const float*)mask)[i] != 0.f;
      else              on = ((const int*)mask)[i] != 0;
      weff_bf[i] = on ? f2bf(syn_w[i]) : (unsigned short)0;
    }
  }
}

// ---- bf16 MFMA GEMM, C = A @ B^T, m97-style 128x128 tile ------------------
// A:[M,Ks] bf16 rm, B:[N,Ks] bf16 rm. NB: 1 or 2 B-matrices.
// KU: K-tiles (of 32) staged per barrier pair (halves barrier drains).
// K = per-block K length; Ks = row stride; blockIdx.z selects the K-slice
// (offset z*K) for split-K. EPI:
//  1: out f32 = aux0 + acc0 * sigmoid(acc1 + aux1[col])
//  2: out bf16 = silu(acc0) * acc1
//  3: out f32 = aux0 + acc0
//  4: split-K partial: f32 acc0 -> (z==0 ? outp : outp2)

template<int NB, int EPI, int KU>
__global__ __launch_bounds__(256)
void gemm_bt(const unsigned short* __restrict__ A,
             const unsigned short* __restrict__ B0,
             const unsigned short* __restrict__ B1,
             const float* __restrict__ aux0, const float* __restrict__ aux1,
             void* __restrict__ outp, float* __restrict__ outp2,
             int M, int N, int K, int Ks) {
  __shared__ unsigned short sA[KU * 128 * 32];
  __shared__ unsigned short sB[KU * NB * 128 * 32];
  const int tid = threadIdx.x;
  const int w = tid >> 6, l = tid & 63;
  const int wm = w & 1, wn = w >> 1;
  const int bm = blockIdx.x, bn = blockIdx.y;
  const int koff = blockIdx.z * K;

  floatx4_t acc[NB][4][4];
#pragma unroll
  for (int j = 0; j < NB; ++j)
#pragma unroll
    for (int m = 0; m < 4; ++m)
#pragma unroll
      for (int n = 0; n < 4; ++n) acc[j][m][n] = (floatx4_t)(0.f);

  const int rA = bm * 128 + 16 * w + (l >> 2);
  const int rB = bn * 128 + 16 * w + (l >> 2);
  const int kl = (l & 3) * 8;
  const unsigned short* gA = A + (long)rA * Ks + kl + koff;
  const unsigned short* gB0 = B0 + (long)rB * Ks + kl + koff;
  const unsigned short* gB1 = nullptr;
  if constexpr (NB > 1) gB1 = B1 + (long)rB * Ks + kl + koff;
  unsigned short* lA = &sA[(16 * w) * 32];
  unsigned short* lB = &sB[(16 * w) * 32];

  for (int k0 = 0; k0 < K; k0 += 32 * KU) {
#pragma unroll
    for (int u = 0; u < KU; ++u) {
      gll16(gA + k0 + u * 32,              lA + u * 4096);
      gll16(gA + k0 + u * 32 + 64 * Ks,    lA + u * 4096 + 64 * 32);
      gll16(gB0 + k0 + u * 32,             lB + (u * NB) * 4096);
      gll16(gB0 + k0 + u * 32 + 64 * Ks,   lB + (u * NB) * 4096 + 64 * 32);
      if constexpr (NB > 1) {
        gll16(gB1 + k0 + u * 32,           lB + (u * NB + 1) * 4096);
        gll16(gB1 + k0 + u * 32 + 64 * Ks, lB + (u * NB + 1) * 4096 + 64 * 32);
      }
    }
    __syncthreads();
#pragma unroll
    for (int u = 0; u < KU; ++u) {
      short8 af[4];
#pragma unroll
      for (int m = 0; m < 4; ++m)
        af[m] = *(const short8*)&sA[u * 4096 +
                    (wm * 64 + m * 16 + (l & 15)) * 32 + (l >> 4) * 8];
#pragma unroll
      for (int j = 0; j < NB; ++j) {
#pragma unroll
        for (int n = 0; n < 4; ++n) {
          short8 bf = *(const short8*)&sB[(u * NB + j) * 4096 +
                          (wn * 64 + n * 16 + (l & 15)) * 32 + (l >> 4) * 8];
#pragma unroll
          for (int m = 0; m < 4; ++m)
            acc[j][m][n] = __builtin_amdgcn_mfma_f32_16x16x32_bf16(
                af[m], bf, acc[j][m][n], 0, 0, 0);
        }
      }
    }
    __syncthreads();
  }

  const int colBase = bn * 128 + wn * 64;
  const int rowBase = bm * 128 + wm * 64;
  float* pout = nullptr;
  if constexpr (EPI == 4)
    pout = (blockIdx.z == 0) ? (float*)outp : outp2;
#pragma unroll
  for (int m = 0; m < 4; ++m) {
#pragma unroll
    for (int n = 0; n < 4; ++n) {
      const int col = colBase + n * 16 + (l & 15);
#pragma unroll
      for (int j = 0; j < 4; ++j) {
        const int row = rowBase + m * 16 + (l >> 4) * 4 + j;
        const long idx = (long)row * N + col;
        float v0 = acc[0][m][n][j];
        if constexpr (EPI == 1) {
          float gsum = acc[NB - 1][m][n][j] + aux1[col];
          float sg = 1.f / (1.f + __expf(-gsum));
          ((float*)outp)[idx] = aux0[idx] + v0 * sg;
        } else if constexpr (EPI == 2) {
          float sil = v0 / (1.f + __expf(-v0));
          ((unsigned short*)outp)[idx] = f2bf(sil * acc[NB - 1][m][n][j]);
        } else if constexpr (EPI == 3) {
          ((float*)outp)[idx] = aux0[idx] + v0;
        } else {  // EPI == 4: split-K partial
          pout[idx] = v0;
        }
      }
    }
  }
}

// ---------------------------------------------------------------------------

extern "C" void kernel_launch(void* const* d_in, const int* in_sizes, int n_in,
                              void* d_out, int out_size, void* d_ws, size_t ws_size,
                              hipStream_t stream) {
  (void)in_sizes; (void)n_in; (void)out_size; (void)ws_size;

  const float* x        = (const float*)d_in[0];
  const float* ln1_w    = (const float*)d_in[1];
  const float* liq_Wi   = (const float*)d_in[2];
  const float* liq_Wr   = (const float*)d_in[3];
  const float* liq_b    = (const float*)d_in[4];
  const float* liq_tau  = (const float*)d_in[5];
  const float* plif_tau = (const float*)d_in[6];
  const float* syn_w    = (const float*)d_in[7];
  const float* gate_w   = (const float*)d_in[8];
  const float* gate_b   = (const float*)d_in[9];
  const float* ln2_w    = (const float*)d_in[10];
  const float* ffn_wg   = (const float*)d_in[11];
  const float* ffn_wu   = (const float*)d_in[12];
  const float* ffn_wd   = (const float*)d_in[13];
  const void*  mask     = d_in[14];

  char* ws = (char*)d_ws;
  const size_t MB = 1024ull * 1024ull;
  unsigned short* wg_bf   = (unsigned short*)(ws + 0 * MB);    // 16 MB
  unsigned short* wu_bf   = (unsigned short*)(ws + 16 * MB);   // 16 MB
  unsigned short* wd_bf   = (unsigned short*)(ws + 32 * MB);   // 16 MB
  unsigned short* weff_bf = (unsigned short*)(ws + 48 * MB);   // 2 MB
  unsigned short* gw_bf   = (unsigned short*)(ws + 50 * MB);   // 2 MB
  float*          x2_f    = (float*)         (ws + 52 * MB);   // 16 MB
  unsigned short* s_bf    = (unsigned short*)(ws + 68 * MB);   // 8 MB
  unsigned short* y_bf    = (unsigned short*)(ws + 76 * MB);   // 8 MB
  unsigned short* ff_bf   = (unsigned short*)(ws + 84 * MB);   // 64 MB (84-148)
  unsigned long long* Utag= (unsigned long long*)(ws + 84 * MB); // 32 MB,
                                    // overlaps ff_bf: Utag dead before FFN
  unsigned long long* hex = (unsigned long long*)(ws + 148 * MB); // 64 KB
  // split-K partials (16 MB each), in regions dead by down-proj time:
  float*          p0_f    = (float*)(ws + 0 * MB);   // was wg_bf (dead after FFN)
  float*          p1_f    = (float*)(ws + 68 * MB);  // was s_bf+y_bf (dead after FFN)
  float*          out_f   = (float*)d_out;

  const int M = Bsz * Tsz;  // 4096

  // Hex ring MUST be zeroed before the scan (poisoned tags would deadlock)
  zero_u64_k<<<32, 256, 0, stream>>>(hex, 2 * Bsz * Dsz);

  // fused: scan (blocks 0-127) + u-producers & weight converts (128-255)
  liquid_plif_k<<<256, 320, 0, stream>>>(
      x, ln1_w, liq_Wi, liq_b, liq_Wr, liq_tau, plif_tau, hex, Utag, s_bf,
      ffn_wg, wg_bf, ffn_wu, wu_bf, ffn_wd, wd_bf, gate_w, gw_bf,
      syn_w, mask, weff_bf);

  // x2 = x + (s@weff^T) * sigmoid(s@gate_w^T + gate_b)
  gemm_bt<2, 1, 2><<<dim3(M / 128, Dsz / 128), 256, 0, stream>>>(
      s_bf, weff_bf, gw_bf, x, gate_b, x2_f, nullptr, M, Dsz, Dsz, Dsz);

  // y = rmsnorm(x2, ln2_w) (bf16)
  rmsnorm_k<1><<<M, 256, 0, stream>>>(x2_f, ln2_w, y_bf);

  // ff = silu(y@wg^T) * (y@wu^T)  (bf16; KU=2 halves barrier drains)
  gemm_bt<2, 2, 2><<<dim3(M / 128, Hsz / 128), 256, 0, stream>>>(
      y_bf, wg_bf, wu_bf, nullptr, nullptr, ff_bf, nullptr, M, Hsz, Dsz, Dsz);

  // down-proj split-K=2: partials p0/p1 (512 blocks -> 2 blocks/CU)
  gemm_bt<1, 4, 2><<<dim3(M / 128, Dsz / 128, 2), 256, 0, stream>>>(
      ff_bf, wd_bf, nullptr, nullptr, nullptr, p0_f, p1_f,
      M, Dsz, Hsz / 2, Hsz);

  // out = x2 + p0 + p1
  combine_k<<<(M * Dsz / 4) / 256, 256, 0, stream>>>(x2_f, p0_f, p1_f, out_f);
}

// Round 15
// 2089.669 us; speedup vs baseline: 1.1097x; 1.0061x over previous
//
#include <hip/hip_runtime.h>
#include <math.h>

// ---------------------------------------------------------------------------
// HybridBlock: rmsnorm -> LiquidCell scan -> PLIF scan -> sparse synapse +
// sigmoid gate (residual) -> rmsnorm -> SwiGLU-style FFN (residual).
// B=4, T=1024, D=1024, H=8192.
// ---------------------------------------------------------------------------

#define Bsz 4
#define Tsz 1024
#define Dsz 1024
#define Hsz 8192

typedef __attribute__((ext_vector_type(8))) short short8;
typedef __attribute__((ext_vector_type(4))) float floatx4_t;

// ---- helpers --------------------------------------------------------------

__device__ __forceinline__ unsigned short f2bf(float f) {
  union { float f; unsigned u; } c; c.f = f;
  unsigned x = c.u;
  unsigned r = (x + 0x7FFFu + ((x >> 16) & 1u)) >> 16;   // RNE
  return (unsigned short)r;
}

__device__ __forceinline__ void gll16(const void* gsrc, void* ldst) {
  // async global->LDS, 16B per lane; LDS dest = wave-uniform base + lane*16
  __builtin_amdgcn_global_load_lds(
      (const __attribute__((address_space(1))) unsigned int*)gsrc,
      (__attribute__((address_space(3))) unsigned int*)ldst,
      16, 0, 0);
}

// ---- tiny prep kernels ----------------------------------------------------

__global__ void zero_u64_k(unsigned long long* p, int n) {
  int i = blockIdx.x * 256 + threadIdx.x;
  if (i < n) p[i] = 0ull;
}

// combine split-K partials + residual: out = x2 + p0 + p1 (f32, float4)
__global__ __launch_bounds__(256)
void combine_k(const float* __restrict__ x2, const float* __restrict__ p0,
               const float* __restrict__ p1, float* __restrict__ out) {
  const long i = (long)blockIdx.x * 256 + threadIdx.x;
  float4 a = ((const float4*)x2)[i];
  float4 b = ((const float4*)p0)[i];
  float4 c = ((const float4*)p1)[i];
  float4 o;
  o.x = a.x + (b.x + c.x); o.y = a.y + (b.y + c.y);
  o.z = a.z + (b.z + c.z); o.w = a.w + (b.w + c.w);
  ((float4*)out)[i] = o;
}

// ---- rmsnorm (one block per row of 1024) ----------------------------------

template<int BF16OUT>
__global__ __launch_bounds__(256)
void rmsnorm_k(const float* __restrict__ X, const float* __restrict__ w,
               void* __restrict__ out) {
  const long row = blockIdx.x;
  const float* x = X + row * Dsz;
  float4 v = ((const float4*)x)[threadIdx.x];
  float ss = v.x * v.x + v.y * v.y + v.z * v.z + v.w * v.w;
#pragma unroll
  for (int off = 32; off > 0; off >>= 1) ss += __shfl_down(ss, off);
  __shared__ float red[4];
  if ((threadIdx.x & 63) == 0) red[threadIdx.x >> 6] = ss;
  __syncthreads();
  float tot = red[0] + red[1] + red[2] + red[3];
  float scale = 1.0f / sqrtf(tot * (1.0f / Dsz) + 1e-6f);
  float4 wv = ((const float4*)w)[threadIdx.x];
  float o0 = v.x * scale * wv.x, o1 = v.y * scale * wv.y;
  float o2 = v.z * scale * wv.z, o3 = v.w * scale * wv.w;
  if (BF16OUT) {
    ushort4 o; o.x = f2bf(o0); o.y = f2bf(o1); o.z = f2bf(o2); o.w = f2bf(o3);
    ((ushort4*)out)[row * 256 + threadIdx.x] = o;
  } else {
    float4 o; o.x = o0; o.y = o1; o.z = o2; o.w = o3;
    ((float4*)out)[row * 256 + threadIdx.x] = o;
  }
}

// ---- fused persistent kernel (r7, frozen) ---------------------------------
// 256 blocks x 320 threads.
// Blocks 0..127  : the r3 scan (waves 0-3 matvec + LDS flags, wave 4 scalar
//                  combine/tanh/PLIF/publish); scalar wave's U read is a
//                  tagged-u64 poll on Utag. Exchange = tagged u64 agent-scope
//                  (LLC) stores/loads, depth-2 parity ring, single-round
//                  batched polls. FROZEN: six redesigns (L2-local, partials,
//                  redundant combine, fences, double-poll) all regressed.
// Blocks 128..255: producer blocks: stream u = rmsnorm(x)@Wi^T + b as tagged
//                  u64s into Utag (~4x faster than the scan consumes), then
//                  convert all FFN/gate/weff weights to bf16 under the scan.

__global__ __launch_bounds__(320)
void liquid_plif_k(const float* __restrict__ x,
                   const float* __restrict__ ln1_w,
                   const float* __restrict__ Wi,
                   const float* __restrict__ liq_b,
                   const float* __restrict__ Wr,
                   const float* __restrict__ liq_tau,
                   const float* __restrict__ plif_tau,
                   unsigned long long* __restrict__ Hex,   // [2][B][D]
                   unsigned long long* __restrict__ Utag,  // [B][T][D]
                   unsigned short* __restrict__ Sout,      // (B,T,D) bf16
                   const float* __restrict__ ffn_wg, unsigned short* wg_bf,
                   const float* __restrict__ ffn_wu, unsigned short* wu_bf,
                   const float* __restrict__ ffn_wd, unsigned short* wd_bf,
                   const float* __restrict__ gate_w, unsigned short* gw_bf,
                   const float* __restrict__ syn_w,  const void* mask,
                   unsigned short* weff_bf) {
  const int tid = threadIdx.x;

  __shared__ float h_lds[1024];
  __shared__ __align__(16) float red[2][4][8][4];
  __shared__ int flags[2][4];
  __shared__ float red4w[4];
  __shared__ int s_mode;

  if (tid < 8) ((int*)flags)[tid] = 0;
  __syncthreads();

  if (blockIdx.x < 128) {
    // ===================== SCAN PATH ======================================
    const int blk = blockIdx.x;
    const int b = blk >> 5;
    const int base = (blk & 31) * 32;

    if (tid < 256) {
      // ---- matvec waves ----
      const int l = tid & 63, w = tid >> 6;
      const int rg = tid & 7;
      const int ck = tid >> 3;
      const int win = 256 * w;

      float4 wr[4][8];
#pragma unroll
      for (int r = 0; r < 4; ++r) {
        const float* wrow = Wr + (long)(base + rg * 4 + r) * Dsz + ck * 32;
#pragma unroll
        for (int qq = 0; qq < 8; ++qq) {
          int q = (qq + ck) & 7;
          wr[r][qq] = *(const float4*)(wrow + q * 4);
        }
      }

      for (int t = 1; t <= Tsz; ++t) {
        const unsigned want = (unsigned)(t - 1);
        const unsigned long long* src =
            Hex + (((long)((t - 1) & 1) * Bsz + b) << 10) + win;
        unsigned long long a0, a1, a2, a3;
        for (;;) {  // 4 batched loads in flight, one wait, wave-wide check
          a0 = __hip_atomic_load(src + l,       __ATOMIC_RELAXED, __HIP_MEMORY_SCOPE_AGENT);
          a1 = __hip_atomic_load(src + l + 64,  __ATOMIC_RELAXED, __HIP_MEMORY_SCOPE_AGENT);
          a2 = __hip_atomic_load(src + l + 128, __ATOMIC_RELAXED, __HIP_MEMORY_SCOPE_AGENT);
          a3 = __hip_atomic_load(src + l + 192, __ATOMIC_RELAXED, __HIP_MEMORY_SCOPE_AGENT);
          int ok = ((unsigned)(a0 >> 32) == want) & ((unsigned)(a1 >> 32) == want) &
                   ((unsigned)(a2 >> 32) == want) & ((unsigned)(a3 >> 32) == want);
          if (__all(ok)) break;
        }
        // wave-local LDS stage (no barrier: same-wave ds ordering)
        h_lds[win + l]       = __uint_as_float((unsigned)a0);
        h_lds[win + l + 64]  = __uint_as_float((unsigned)a1);
        h_lds[win + l + 128] = __uint_as_float((unsigned)a2);
        h_lds[win + l + 192] = __uint_as_float((unsigned)a3);

        float acc0 = 0.f, acc1 = 0.f, acc2 = 0.f, acc3 = 0.f;
        const float* hch = &h_lds[ck * 32];
#pragma unroll
        for (int qq = 0; qq < 8; ++qq) {
          const int q = (qq + ck) & 7;
          float4 hv = *(const float4*)(hch + q * 4);
          acc0 += wr[0][qq].x * hv.x + wr[0][qq].y * hv.y + wr[0][qq].z * hv.z + wr[0][qq].w * hv.w;
          acc1 += wr[1][qq].x * hv.x + wr[1][qq].y * hv.y + wr[1][qq].z * hv.z + wr[1][qq].w * hv.w;
          acc2 += wr[2][qq].x * hv.x + wr[2][qq].y * hv.y + wr[2][qq].z * hv.z + wr[2][qq].w * hv.w;
          acc3 += wr[3][qq].x * hv.x + wr[3][qq].y * hv.y + wr[3][qq].z * hv.z + wr[3][qq].w * hv.w;
        }
        acc0 += __shfl_xor(acc0, 8); acc0 += __shfl_xor(acc0, 16); acc0 += __shfl_xor(acc0, 32);
        acc1 += __shfl_xor(acc1, 8); acc1 += __shfl_xor(acc1, 16); acc1 += __shfl_xor(acc1, 32);
        acc2 += __shfl_xor(acc2, 8); acc2 += __shfl_xor(acc2, 16); acc2 += __shfl_xor(acc2, 32);
        acc3 += __shfl_xor(acc3, 8); acc3 += __shfl_xor(acc3, 16); acc3 += __shfl_xor(acc3, 32);
        if ((l & 56) == 0) {
          float4 rv; rv.x = acc0; rv.y = acc1; rv.z = acc2; rv.w = acc3;
          *(float4*)&red[t & 1][w][rg][0] = rv;
        }
        asm volatile("s_waitcnt lgkmcnt(0)" ::: "memory");
        if (l == 0)
          __hip_atomic_store(&flags[t & 1][w], t, __ATOMIC_RELEASE,
                             __HIP_MEMORY_SCOPE_WORKGROUP);
      }
    } else {
      // ---- scalar wave ----
      const int r = tid - 256;  // active lanes r<32
      float hstate = 0.f, vstate = 0.f, dec = 0.f, omdec = 0.f, itau = 0.f;
      if (r < 32) {
        float tau = liq_tau[base + r];
        dec = expf(-1.0f / tau);
        omdec = 1.0f - dec;
        itau = 1.0f / plif_tau[0];
      }
      for (int t = 1; t <= Tsz; ++t) {
        float uval = 0.f;
        if (r < 32) {   // tagged poll on producer output (usually ready)
          const unsigned long long* up =
              Utag + ((long)b * Tsz + (t - 1)) * Dsz + base + r;
          unsigned long long uv;
          do {
            uv = __hip_atomic_load(up, __ATOMIC_RELAXED, __HIP_MEMORY_SCOPE_AGENT);
          } while ((unsigned)(uv >> 32) != (unsigned)t);
          uval = __uint_as_float((unsigned)uv);
        }
        const int p = t & 1;
        for (;;) {
          int f0 = __hip_atomic_load(&flags[p][0], __ATOMIC_ACQUIRE, __HIP_MEMORY_SCOPE_WORKGROUP);
          int f1 = __hip_atomic_load(&flags[p][1], __ATOMIC_ACQUIRE, __HIP_MEMORY_SCOPE_WORKGROUP);
          int f2 = __hip_atomic_load(&flags[p][2], __ATOMIC_ACQUIRE, __HIP_MEMORY_SCOPE_WORKGROUP);
          int f3 = __hip_atomic_load(&flags[p][3], __ATOMIC_ACQUIRE, __HIP_MEMORY_SCOPE_WORKGROUP);
          if ((f0 == t) & (f1 == t) & (f2 == t) & (f3 == t)) break;
        }
        if (r < 32) {
          const int r2 = r >> 2, jj = r & 3;
          float sum = red[p][0][r2][jj] + red[p][1][r2][jj] +
                      red[p][2][r2][jj] + red[p][3][r2][jj];
          float z = sum + uval;
          float ex = __expf(2.0f * z);
          float f = 1.0f - 2.0f * __builtin_amdgcn_rcpf(ex + 1.0f);
          hstate = hstate * dec + omdec * f;
          vstate += (hstate - vstate) * itau;
          float sp = ((vstate - 0.05f) > 0.f) ? 1.f : 0.f;
          vstate -= sp * 0.05f;
          const long pidx = (((long)p * Bsz + b) << 10) + base + r;
          unsigned long long pv =
              (((unsigned long long)(unsigned)t) << 32) |
              (unsigned long long)__float_as_uint(hstate);
          __hip_atomic_store(&Hex[pidx], pv, __ATOMIC_RELAXED,
                             __HIP_MEMORY_SCOPE_AGENT);
          Sout[((long)b * Tsz + (t - 1)) * Dsz + base + r] =
              (sp > 0.f) ? (unsigned short)0x3F80 : (unsigned short)0;
        }
      }
    }
  } else {
    // ===================== PRODUCER PATH ==================================
    const int blk2 = blockIdx.x - 128;   // 0..127
    const int b = blk2 >> 5;
    const int base = (blk2 & 31) * 32;

    // Wi slice -> registers (same rotated layout as scan's Wr)
    const int l = tid & 63, w = tid >> 6;
    const int rg = tid & 7;
    const int ck = tid >> 3;
    float4 wi[4][8];
    if (tid < 256) {
#pragma unroll
      for (int r = 0; r < 4; ++r) {
        const float* wrow = Wi + (long)(base + rg * 4 + r) * Dsz + ck * 32;
#pragma unroll
        for (int qq = 0; qq < 8; ++qq) {
          int q = (qq + ck) & 7;
          wi[r][qq] = *(const float4*)(wrow + q * 4);
        }
      }
    }
    float4 w4 = (tid < 256) ? ((const float4*)ln1_w)[tid] : float4{0, 0, 0, 0};
    float lb = 0.f;
    if (tid >= 256 && (tid - 256) < 32) lb = liq_b[base + (tid - 256)];

    for (int t = 1; t <= Tsz; ++t) {
      // rmsnorm of x[b,t-1] in-block
      float4 xv = {0, 0, 0, 0};
      if (tid < 256) {
        xv = ((const float4*)(x + ((long)b * Tsz + (t - 1)) * Dsz))[tid];
        float ss = xv.x * xv.x + xv.y * xv.y + xv.z * xv.z + xv.w * xv.w;
#pragma unroll
        for (int off = 32; off > 0; off >>= 1) ss += __shfl_down(ss, off);
        if (l == 0) red4w[w] = ss;
      }
      __syncthreads();
      if (tid < 256) {
        float tot = red4w[0] + red4w[1] + red4w[2] + red4w[3];
        float scale = 1.0f / sqrtf(tot * (1.0f / Dsz) + 1e-6f);
        float4 av;
        av.x = xv.x * scale * w4.x; av.y = xv.y * scale * w4.y;
        av.z = xv.z * scale * w4.z; av.w = xv.w * scale * w4.w;
        ((float4*)h_lds)[tid] = av;
      }
      __syncthreads();
      if (tid < 256) {
        float acc0 = 0.f, acc1 = 0.f, acc2 = 0.f, acc3 = 0.f;
        const float* hch = &h_lds[ck * 32];
#pragma unroll
        for (int qq = 0; qq < 8; ++qq) {
          const int q = (qq + ck) & 7;
          float4 hv = *(const float4*)(hch + q * 4);
          acc0 += wi[0][qq].x * hv.x + wi[0][qq].y * hv.y + wi[0][qq].z * hv.z + wi[0][qq].w * hv.w;
          acc1 += wi[1][qq].x * hv.x + wi[1][qq].y * hv.y + wi[1][qq].z * hv.z + wi[1][qq].w * hv.w;
          acc2 += wi[2][qq].x * hv.x + wi[2][qq].y * hv.y + wi[2][qq].z * hv.z + wi[2][qq].w * hv.w;
          acc3 += wi[3][qq].x * hv.x + wi[3][qq].y * hv.y + wi[3][qq].z * hv.z + wi[3][qq].w * hv.w;
        }
        acc0 += __shfl_xor(acc0, 8); acc0 += __shfl_xor(acc0, 16); acc0 += __shfl_xor(acc0, 32);
        acc1 += __shfl_xor(acc1, 8); acc1 += __shfl_xor(acc1, 16); acc1 += __shfl_xor(acc1, 32);
        acc2 += __shfl_xor(acc2, 8); acc2 += __shfl_xor(acc2, 16); acc2 += __shfl_xor(acc2, 32);
        acc3 += __shfl_xor(acc3, 8); acc3 += __shfl_xor(acc3, 16); acc3 += __shfl_xor(acc3, 32);
        if ((l & 56) == 0) {
          float4 rv; rv.x = acc0; rv.y = acc1; rv.z = acc2; rv.w = acc3;
          *(float4*)&red[0][w][rg][0] = rv;
        }
      }
      __syncthreads();
      if (tid >= 256) {
        const int r = tid - 256;
        if (r < 32) {
          const int r2 = r >> 2, jj = r & 3;
          float sum = red[0][0][r2][jj] + red[0][1][r2][jj] +
                      red[0][2][r2][jj] + red[0][3][r2][jj] + lb;
          unsigned long long pv =
              (((unsigned long long)(unsigned)t) << 32) |
              (unsigned long long)__float_as_uint(sum);
          __hip_atomic_store(&Utag[((long)b * Tsz + (t - 1)) * Dsz + base + r],
                             pv, __ATOMIC_RELAXED, __HIP_MEMORY_SCOPE_AGENT);
        }
      }
      __syncthreads();
    }

    // ---- tail: weight conversions (hidden under the scan) ----------------
    if (tid == 0) {
      int md = 0;
      const unsigned* m = (const unsigned*)mask;
      for (int i = 0; i < 256; ++i) {
        unsigned wd = m[i];
        if (wd == 0x3F800000u) { md = 2; break; }
        if (wd > 1u) md = 1;
      }
      s_mode = md;
    }
    __syncthreads();
    const int md = s_mode;
    const long gtid = (long)blk2 * 320 + tid;
    const long gstr = 128 * 320;
    const int n4big = Hsz * Dsz / 4;      // 2,097,152 float4s
    for (long i = gtid; i < n4big; i += gstr) {
      float4 v = ((const float4*)ffn_wg)[i];
      ushort4 o; o.x = f2bf(v.x); o.y = f2bf(v.y); o.z = f2bf(v.z); o.w = f2bf(v.w);
      ((ushort4*)wg_bf)[i] = o;
      v = ((const float4*)ffn_wu)[i];
      o.x = f2bf(v.x); o.y = f2bf(v.y); o.z = f2bf(v.z); o.w = f2bf(v.w);
      ((ushort4*)wu_bf)[i] = o;
      v = ((const float4*)ffn_wd)[i];
      o.x = f2bf(v.x); o.y = f2bf(v.y); o.z = f2bf(v.z); o.w = f2bf(v.w);
      ((ushort4*)wd_bf)[i] = o;
    }
    const int n4g = Dsz * Dsz / 4;
    for (long i = gtid; i < n4g; i += gstr) {
      float4 v = ((const float4*)gate_w)[i];
      ushort4 o; o.x = f2bf(v.x); o.y = f2bf(v.y); o.z = f2bf(v.z); o.w = f2bf(v.w);
      ((ushort4*)gw_bf)[i] = o;
    }
    const int nw = Dsz * Dsz;
    for (long i = gtid; i < nw; i += gstr) {
      bool on;
      if (md == 1)      on = ((const unsigned char*)mask)[i] != 0;
      else if (md == 2) on = ((const float*)mask)[i] != 0.f;
      else              on = ((const int*)mask)[i] != 0;
      weff_bf[i] = on ? f2bf(syn_w[i]) : (unsigned short)0;
    }
  }
}

// ---- bf16 MFMA GEMM, C = A @ B^T, m97-style 128x128 tile ------------------
// A:[M,Ks] bf16 rm, B:[N,Ks] bf16 rm. NB: 1 or 2 B-matrices.
// KU: K-tiles (of 32) staged per barrier pair (amortizes barrier drains).
// K = per-block K length; Ks = row stride; blockIdx.z selects the K-slice
// (offset z*K) for split-K. LDS: NB=1 KU=4 -> 64KB (2 blocks/CU, matches
// the split-K 2/CU residency); NB=2 KU=2 -> 48KB (3/CU = VGPR bound). EPI:
//  1: out f32 = aux0 + acc0 * sigmoid(acc1 + aux1[col])
//  2: out bf16 = silu(acc0) * acc1
//  3: out f32 = aux0 + acc0
//  4: split-K partial: f32 acc0 -> (z==0 ? outp : outp2)

template<int NB, int EPI, int KU>
__global__ __launch_bounds__(256)
void gemm_bt(const unsigned short* __restrict__ A,
             const unsigned short* __restrict__ B0,
             const unsigned short* __restrict__ B1,
             const float* __restrict__ aux0, const float* __restrict__ aux1,
             void* __restrict__ outp, float* __restrict__ outp2,
             int M, int N, int K, int Ks) {
  __shared__ unsigned short sA[KU * 128 * 32];
  __shared__ unsigned short sB[KU * NB * 128 * 32];
  const int tid = threadIdx.x;
  const int w = tid >> 6, l = tid & 63;
  const int wm = w & 1, wn = w >> 1;
  const int bm = blockIdx.x, bn = blockIdx.y;
  const int koff = blockIdx.z * K;

  floatx4_t acc[NB][4][4];
#pragma unroll
  for (int j = 0; j < NB; ++j)
#pragma unroll
    for (int m = 0; m < 4; ++m)
#pragma unroll
      for (int n = 0; n < 4; ++n) acc[j][m][n] = (floatx4_t)(0.f);

  const int rA = bm * 128 + 16 * w + (l >> 2);
  const int rB = bn * 128 + 16 * w + (l >> 2);
  const int kl = (l & 3) * 8;
  const unsigned short* gA = A + (long)rA * Ks + kl + koff;
  const unsigned short* gB0 = B0 + (long)rB * Ks + kl + koff;
  const unsigned short* gB1 = nullptr;
  if constexpr (NB > 1) gB1 = B1 + (long)rB * Ks + kl + koff;
  unsigned short* lA = &sA[(16 * w) * 32];
  unsigned short* lB = &sB[(16 * w) * 32];

  for (int k0 = 0; k0 < K; k0 += 32 * KU) {
#pragma unroll
    for (int u = 0; u < KU; ++u) {
      gll16(gA + k0 + u * 32,              lA + u * 4096);
      gll16(gA + k0 + u * 32 + 64 * Ks,    lA + u * 4096 + 64 * 32);
      gll16(gB0 + k0 + u * 32,             lB + (u * NB) * 4096);
      gll16(gB0 + k0 + u * 32 + 64 * Ks,   lB + (u * NB) * 4096 + 64 * 32);
      if constexpr (NB > 1) {
        gll16(gB1 + k0 + u * 32,           lB + (u * NB + 1) * 4096);
        gll16(gB1 + k0 + u * 32 + 64 * Ks, lB + (u * NB + 1) * 4096 + 64 * 32);
      }
    }
    __syncthreads();
#pragma unroll
    for (int u = 0; u < KU; ++u) {
      short8 af[4];
#pragma unroll
      for (int m = 0; m < 4; ++m)
        af[m] = *(const short8*)&sA[u * 4096 +
                    (wm * 64 + m * 16 + (l & 15)) * 32 + (l >> 4) * 8];
#pragma unroll
      for (int j = 0; j < NB; ++j) {
#pragma unroll
        for (int n = 0; n < 4; ++n) {
          short8 bf = *(const short8*)&sB[(u * NB + j) * 4096 +
                          (wn * 64 + n * 16 + (l & 15)) * 32 + (l >> 4) * 8];
#pragma unroll
          for (int m = 0; m < 4; ++m)
            acc[j][m][n] = __builtin_amdgcn_mfma_f32_16x16x32_bf16(
                af[m], bf, acc[j][m][n], 0, 0, 0);
        }
      }
    }
    __syncthreads();
  }

  const int colBase = bn * 128 + wn * 64;
  const int rowBase = bm * 128 + wm * 64;
  float* pout = nullptr;
  if constexpr (EPI == 4)
    pout = (blockIdx.z == 0) ? (float*)outp : outp2;
#pragma unroll
  for (int m = 0; m < 4; ++m) {
#pragma unroll
    for (int n = 0; n < 4; ++n) {
      const int col = colBase + n * 16 + (l & 15);
#pragma unroll
      for (int j = 0; j < 4; ++j) {
        const int row = rowBase + m * 16 + (l >> 4) * 4 + j;
        const long idx = (long)row * N + col;
        float v0 = acc[0][m][n][j];
        if constexpr (EPI == 1) {
          float gsum = acc[NB - 1][m][n][j] + aux1[col];
          float sg = 1.f / (1.f + __expf(-gsum));
          ((float*)outp)[idx] = aux0[idx] + v0 * sg;
        } else if constexpr (EPI == 2) {
          float sil = v0 / (1.f + __expf(-v0));
          ((unsigned short*)outp)[idx] = f2bf(sil * acc[NB - 1][m][n][j]);
        } else if constexpr (EPI == 3) {
          ((float*)outp)[idx] = aux0[idx] + v0;
        } else {  // EPI == 4: split-K partial
          pout[idx] = v0;
        }
      }
    }
  }
}

// ---------------------------------------------------------------------------

extern "C" void kernel_launch(void* const* d_in, const int* in_sizes, int n_in,
                              void* d_out, int out_size, void* d_ws, size_t ws_size,
                              hipStream_t stream) {
  (void)in_sizes; (void)n_in; (void)out_size; (void)ws_size;

  const float* x        = (const float*)d_in[0];
  const float* ln1_w    = (const float*)d_in[1];
  const float* liq_Wi   = (const float*)d_in[2];
  const float* liq_Wr   = (const float*)d_in[3];
  const float* liq_b    = (const float*)d_in[4];
  const float* liq_tau  = (const float*)d_in[5];
  const float* plif_tau = (const float*)d_in[6];
  const float* syn_w    = (const float*)d_in[7];
  const float* gate_w   = (const float*)d_in[8];
  const float* gate_b   = (const float*)d_in[9];
  const float* ln2_w    = (const float*)d_in[10];
  const float* ffn_wg   = (const float*)d_in[11];
  const float* ffn_wu   = (const float*)d_in[12];
  const float* ffn_wd   = (const float*)d_in[13];
  const void*  mask     = d_in[14];

  char* ws = (char*)d_ws;
  const size_t MB = 1024ull * 1024ull;
  unsigned short* wg_bf   = (unsigned short*)(ws + 0 * MB);    // 16 MB
  unsigned short* wu_bf   = (unsigned short*)(ws + 16 * MB);   // 16 MB
  unsigned short* wd_bf   = (unsigned short*)(ws + 32 * MB);   // 16 MB
  unsigned short* weff_bf = (unsigned short*)(ws + 48 * MB);   // 2 MB
  unsigned short* gw_bf   = (unsigned short*)(ws + 50 * MB);   // 2 MB
  float*          x2_f    = (float*)         (ws + 52 * MB);   // 16 MB
  unsigned short* s_bf    = (unsigned short*)(ws + 68 * MB);   // 8 MB
  unsigned short* y_bf    = (unsigned short*)(ws + 76 * MB);   // 8 MB
  unsigned short* ff_bf   = (unsigned short*)(ws + 84 * MB);   // 64 MB (84-148)
  unsigned long long* Utag= (unsigned long long*)(ws + 84 * MB); // 32 MB,
                                    // overlaps ff_bf: Utag dead before FFN
  unsigned long long* hex = (unsigned long long*)(ws + 148 * MB); // 64 KB
  // split-K partials (16 MB each), in regions dead by down-proj time:
  float*          p0_f    = (float*)(ws + 0 * MB);   // was wg_bf (dead after FFN)
  float*          p1_f    = (float*)(ws + 68 * MB);  // was s_bf+y_bf (dead after FFN)
  float*          out_f   = (float*)d_out;

  const int M = Bsz * Tsz;  // 4096

  // Hex ring MUST be zeroed before the scan (poisoned tags would deadlock)
  zero_u64_k<<<32, 256, 0, stream>>>(hex, 2 * Bsz * Dsz);

  // fused: scan (blocks 0-127) + u-producers & weight converts (128-255)
  liquid_plif_k<<<256, 320, 0, stream>>>(
      x, ln1_w, liq_Wi, liq_b, liq_Wr, liq_tau, plif_tau, hex, Utag, s_bf,
      ffn_wg, wg_bf, ffn_wu, wu_bf, ffn_wd, wd_bf, gate_w, gw_bf,
      syn_w, mask, weff_bf);

  // x2 = x + (s@weff^T) * sigmoid(s@gate_w^T + gate_b)
  gemm_bt<2, 1, 2><<<dim3(M / 128, Dsz / 128), 256, 0, stream>>>(
      s_bf, weff_bf, gw_bf, x, gate_b, x2_f, nullptr, M, Dsz, Dsz, Dsz);

  // y = rmsnorm(x2, ln2_w) (bf16)
  rmsnorm_k<1><<<M, 256, 0, stream>>>(x2_f, ln2_w, y_bf);

  // ff = silu(y@wg^T) * (y@wu^T)  (bf16; KU=2 halves barrier drains)
  gemm_bt<2, 2, 2><<<dim3(M / 128, Hsz / 128), 256, 0, stream>>>(
      y_bf, wg_bf, wu_bf, nullptr, nullptr, ff_bf, nullptr, M, Hsz, Dsz, Dsz);

  // down-proj split-K=2 (512 blocks -> 2 blocks/CU), KU=4 (32 barrier pairs)
  gemm_bt<1, 4, 4><<<dim3(M / 128, Dsz / 128, 2), 256, 0, stream>>>(
      ff_bf, wd_bf, nullptr, nullptr, nullptr, p0_f, p1_f,
      M, Dsz, Hsz / 2, Hsz);

  // out = x2 + p0 + p1
  combine_k<<<(M * Dsz / 4) / 256, 256, 0, stream>>>(x2_f, p0_f, p1_f, out_f);
}

// Round 16
// 2079.399 us; speedup vs baseline: 1.1152x; 1.0049x over previous
//
#include <hip/hip_runtime.h>
#include <math.h>

// ---------------------------------------------------------------------------
// HybridBlock: rmsnorm -> LiquidCell scan -> PLIF scan -> sparse synapse +
// sigmoid gate (residual) -> rmsnorm -> SwiGLU-style FFN (residual).
// B=4, T=1024, D=1024, H=8192.
// ---------------------------------------------------------------------------

#define Bsz 4
#define Tsz 1024
#define Dsz 1024
#define Hsz 8192

typedef __attribute__((ext_vector_type(8))) short short8;
typedef __attribute__((ext_vector_type(4))) float floatx4_t;

// ---- helpers --------------------------------------------------------------

__device__ __forceinline__ unsigned short f2bf(float f) {
  union { float f; unsigned u; } c; c.f = f;
  unsigned x = c.u;
  unsigned r = (x + 0x7FFFu + ((x >> 16) & 1u)) >> 16;   // RNE
  return (unsigned short)r;
}

__device__ __forceinline__ void gll16(const void* gsrc, void* ldst) {
  // async global->LDS, 16B per lane; LDS dest = wave-uniform base + lane*16
  __builtin_amdgcn_global_load_lds(
      (const __attribute__((address_space(1))) unsigned int*)gsrc,
      (__attribute__((address_space(3))) unsigned int*)ldst,
      16, 0, 0);
}

// ---- tiny kernels ----------------------------------------------------------

// combine split-K partials + residual: out = x2 + p0 + p1 (f32, float4)
__global__ __launch_bounds__(256)
void combine_k(const float* __restrict__ x2, const float* __restrict__ p0,
               const float* __restrict__ p1, float* __restrict__ out) {
  const long i = (long)blockIdx.x * 256 + threadIdx.x;
  float4 a = ((const float4*)x2)[i];
  float4 b = ((const float4*)p0)[i];
  float4 c = ((const float4*)p1)[i];
  float4 o;
  o.x = a.x + (b.x + c.x); o.y = a.y + (b.y + c.y);
  o.z = a.z + (b.z + c.z); o.w = a.w + (b.w + c.w);
  ((float4*)out)[i] = o;
}

// ---- rmsnorm (one block per row of 1024) ----------------------------------

template<int BF16OUT>
__global__ __launch_bounds__(256)
void rmsnorm_k(const float* __restrict__ X, const float* __restrict__ w,
               void* __restrict__ out) {
  const long row = blockIdx.x;
  const float* x = X + row * Dsz;
  float4 v = ((const float4*)x)[threadIdx.x];
  float ss = v.x * v.x + v.y * v.y + v.z * v.z + v.w * v.w;
#pragma unroll
  for (int off = 32; off > 0; off >>= 1) ss += __shfl_down(ss, off);
  __shared__ float red[4];
  if ((threadIdx.x & 63) == 0) red[threadIdx.x >> 6] = ss;
  __syncthreads();
  float tot = red[0] + red[1] + red[2] + red[3];
  float scale = 1.0f / sqrtf(tot * (1.0f / Dsz) + 1e-6f);
  float4 wv = ((const float4*)w)[threadIdx.x];
  float o0 = v.x * scale * wv.x, o1 = v.y * scale * wv.y;
  float o2 = v.z * scale * wv.z, o3 = v.w * scale * wv.w;
  if (BF16OUT) {
    ushort4 o; o.x = f2bf(o0); o.y = f2bf(o1); o.z = f2bf(o2); o.w = f2bf(o3);
    ((ushort4*)out)[row * 256 + threadIdx.x] = o;
  } else {
    float4 o; o.x = o0; o.y = o1; o.z = o2; o.w = o3;
    ((float4*)out)[row * 256 + threadIdx.x] = o;
  }
}

// ---- fused persistent kernel (r7, frozen; + in-kernel Hex self-zero) ------
// 256 blocks x 320 threads.
// Blocks 0..127  : the r3 scan (waves 0-3 matvec + LDS flags, wave 4 scalar
//                  combine/tanh/PLIF/publish); scalar wave's U read is a
//                  tagged-u64 poll on Utag. Exchange = tagged u64 agent-scope
//                  (LLC) stores/loads, depth-2 parity ring, single-round
//                  batched polls. FROZEN: six redesigns (L2-local, partials,
//                  redundant combine, fences, double-poll) all regressed.
//                  NEW (r8-proven): each scan block self-zeroes its own 64
//                  Hex slots before the init barrier (barrier's vmcnt(0)
//                  drain orders zero-before-publish; depth-2 ring induction
//                  makes tag-0 the t=0 publish, so stale cross-replay tags
//                  spin until the zero lands -> deadlock-free). This removes
//                  the standalone zero kernel + launch gap.
// Blocks 128..255: producer blocks: stream u = rmsnorm(x)@Wi^T + b as tagged
//                  u64s into Utag (~4x faster than the scan consumes), then
//                  convert all FFN/gate/weff weights to bf16 under the scan.

__global__ __launch_bounds__(320)
void liquid_plif_k(const float* __restrict__ x,
                   const float* __restrict__ ln1_w,
                   const float* __restrict__ Wi,
                   const float* __restrict__ liq_b,
                   const float* __restrict__ Wr,
                   const float* __restrict__ liq_tau,
                   const float* __restrict__ plif_tau,
                   unsigned long long* __restrict__ Hex,   // [2][B][D]
                   unsigned long long* __restrict__ Utag,  // [B][T][D]
                   unsigned short* __restrict__ Sout,      // (B,T,D) bf16
                   const float* __restrict__ ffn_wg, unsigned short* wg_bf,
                   const float* __restrict__ ffn_wu, unsigned short* wu_bf,
                   const float* __restrict__ ffn_wd, unsigned short* wd_bf,
                   const float* __restrict__ gate_w, unsigned short* gw_bf,
                   const float* __restrict__ syn_w,  const void* mask,
                   unsigned short* weff_bf) {
  const int tid = threadIdx.x;

  __shared__ float h_lds[1024];
  __shared__ __align__(16) float red[2][4][8][4];
  __shared__ int flags[2][4];
  __shared__ float red4w[4];
  __shared__ int s_mode;

  if (tid < 8) ((int*)flags)[tid] = 0;

  if (blockIdx.x < 128) {
    // ===================== SCAN PATH ======================================
    const int blk = blockIdx.x;
    const int b = blk >> 5;
    const int base = (blk & 31) * 32;

    // self-zero own Hex slots (both parities); the __syncthreads below emits
    // s_waitcnt vmcnt(0) before s_barrier -> zeros retire before any publish
    if (tid < 64) {
      const long zp = (((long)(tid >> 5) * Bsz + b) << 10) + base + (tid & 31);
      __hip_atomic_store(&Hex[zp], 0ull, __ATOMIC_RELAXED, __HIP_MEMORY_SCOPE_AGENT);
    }
    __syncthreads();

    if (tid < 256) {
      // ---- matvec waves ----
      const int l = tid & 63, w = tid >> 6;
      const int rg = tid & 7;
      const int ck = tid >> 3;
      const int win = 256 * w;

      float4 wr[4][8];
#pragma unroll
      for (int r = 0; r < 4; ++r) {
        const float* wrow = Wr + (long)(base + rg * 4 + r) * Dsz + ck * 32;
#pragma unroll
        for (int qq = 0; qq < 8; ++qq) {
          int q = (qq + ck) & 7;
          wr[r][qq] = *(const float4*)(wrow + q * 4);
        }
      }

      for (int t = 1; t <= Tsz; ++t) {
        const unsigned want = (unsigned)(t - 1);
        const unsigned long long* src =
            Hex + (((long)((t - 1) & 1) * Bsz + b) << 10) + win;
        unsigned long long a0, a1, a2, a3;
        for (;;) {  // 4 batched loads in flight, one wait, wave-wide check
          a0 = __hip_atomic_load(src + l,       __ATOMIC_RELAXED, __HIP_MEMORY_SCOPE_AGENT);
          a1 = __hip_atomic_load(src + l + 64,  __ATOMIC_RELAXED, __HIP_MEMORY_SCOPE_AGENT);
          a2 = __hip_atomic_load(src + l + 128, __ATOMIC_RELAXED, __HIP_MEMORY_SCOPE_AGENT);
          a3 = __hip_atomic_load(src + l + 192, __ATOMIC_RELAXED, __HIP_MEMORY_SCOPE_AGENT);
          int ok = ((unsigned)(a0 >> 32) == want) & ((unsigned)(a1 >> 32) == want) &
                   ((unsigned)(a2 >> 32) == want) & ((unsigned)(a3 >> 32) == want);
          if (__all(ok)) break;
        }
        // wave-local LDS stage (no barrier: same-wave ds ordering)
        h_lds[win + l]       = __uint_as_float((unsigned)a0);
        h_lds[win + l + 64]  = __uint_as_float((unsigned)a1);
        h_lds[win + l + 128] = __uint_as_float((unsigned)a2);
        h_lds[win + l + 192] = __uint_as_float((unsigned)a3);

        float acc0 = 0.f, acc1 = 0.f, acc2 = 0.f, acc3 = 0.f;
        const float* hch = &h_lds[ck * 32];
#pragma unroll
        for (int qq = 0; qq < 8; ++qq) {
          const int q = (qq + ck) & 7;
          float4 hv = *(const float4*)(hch + q * 4);
          acc0 += wr[0][qq].x * hv.x + wr[0][qq].y * hv.y + wr[0][qq].z * hv.z + wr[0][qq].w * hv.w;
          acc1 += wr[1][qq].x * hv.x + wr[1][qq].y * hv.y + wr[1][qq].z * hv.z + wr[1][qq].w * hv.w;
          acc2 += wr[2][qq].x * hv.x + wr[2][qq].y * hv.y + wr[2][qq].z * hv.z + wr[2][qq].w * hv.w;
          acc3 += wr[3][qq].x * hv.x + wr[3][qq].y * hv.y + wr[3][qq].z * hv.z + wr[3][qq].w * hv.w;
        }
        acc0 += __shfl_xor(acc0, 8); acc0 += __shfl_xor(acc0, 16); acc0 += __shfl_xor(acc0, 32);
        acc1 += __shfl_xor(acc1, 8); acc1 += __shfl_xor(acc1, 16); acc1 += __shfl_xor(acc1, 32);
        acc2 += __shfl_xor(acc2, 8); acc2 += __shfl_xor(acc2, 16); acc2 += __shfl_xor(acc2, 32);
        acc3 += __shfl_xor(acc3, 8); acc3 += __shfl_xor(acc3, 16); acc3 += __shfl_xor(acc3, 32);
        if ((l & 56) == 0) {
          float4 rv; rv.x = acc0; rv.y = acc1; rv.z = acc2; rv.w = acc3;
          *(float4*)&red[t & 1][w][rg][0] = rv;
        }
        asm volatile("s_waitcnt lgkmcnt(0)" ::: "memory");
        if (l == 0)
          __hip_atomic_store(&flags[t & 1][w], t, __ATOMIC_RELEASE,
                             __HIP_MEMORY_SCOPE_WORKGROUP);
      }
    } else {
      // ---- scalar wave ----
      const int r = tid - 256;  // active lanes r<32
      float hstate = 0.f, vstate = 0.f, dec = 0.f, omdec = 0.f, itau = 0.f;
      if (r < 32) {
        float tau = liq_tau[base + r];
        dec = expf(-1.0f / tau);
        omdec = 1.0f - dec;
        itau = 1.0f / plif_tau[0];
      }
      for (int t = 1; t <= Tsz; ++t) {
        float uval = 0.f;
        if (r < 32) {   // tagged poll on producer output (usually ready)
          const unsigned long long* up =
              Utag + ((long)b * Tsz + (t - 1)) * Dsz + base + r;
          unsigned long long uv;
          do {
            uv = __hip_atomic_load(up, __ATOMIC_RELAXED, __HIP_MEMORY_SCOPE_AGENT);
          } while ((unsigned)(uv >> 32) != (unsigned)t);
          uval = __uint_as_float((unsigned)uv);
        }
        const int p = t & 1;
        for (;;) {
          int f0 = __hip_atomic_load(&flags[p][0], __ATOMIC_ACQUIRE, __HIP_MEMORY_SCOPE_WORKGROUP);
          int f1 = __hip_atomic_load(&flags[p][1], __ATOMIC_ACQUIRE, __HIP_MEMORY_SCOPE_WORKGROUP);
          int f2 = __hip_atomic_load(&flags[p][2], __ATOMIC_ACQUIRE, __HIP_MEMORY_SCOPE_WORKGROUP);
          int f3 = __hip_atomic_load(&flags[p][3], __ATOMIC_ACQUIRE, __HIP_MEMORY_SCOPE_WORKGROUP);
          if ((f0 == t) & (f1 == t) & (f2 == t) & (f3 == t)) break;
        }
        if (r < 32) {
          const int r2 = r >> 2, jj = r & 3;
          float sum = red[p][0][r2][jj] + red[p][1][r2][jj] +
                      red[p][2][r2][jj] + red[p][3][r2][jj];
          float z = sum + uval;
          float ex = __expf(2.0f * z);
          float f = 1.0f - 2.0f * __builtin_amdgcn_rcpf(ex + 1.0f);
          hstate = hstate * dec + omdec * f;
          vstate += (hstate - vstate) * itau;
          float sp = ((vstate - 0.05f) > 0.f) ? 1.f : 0.f;
          vstate -= sp * 0.05f;
          const long pidx = (((long)p * Bsz + b) << 10) + base + r;
          unsigned long long pv =
              (((unsigned long long)(unsigned)t) << 32) |
              (unsigned long long)__float_as_uint(hstate);
          __hip_atomic_store(&Hex[pidx], pv, __ATOMIC_RELAXED,
                             __HIP_MEMORY_SCOPE_AGENT);
          Sout[((long)b * Tsz + (t - 1)) * Dsz + base + r] =
              (sp > 0.f) ? (unsigned short)0x3F80 : (unsigned short)0;
        }
      }
    }
  } else {
    // ===================== PRODUCER PATH ==================================
    __syncthreads();   // match scan-path barrier (uniform for whole grid? no
                       // -- barrier is per-block; this just pairs the init)
    const int blk2 = blockIdx.x - 128;   // 0..127
    const int b = blk2 >> 5;
    const int base = (blk2 & 31) * 32;

    // Wi slice -> registers (same rotated layout as scan's Wr)
    const int l = tid & 63, w = tid >> 6;
    const int rg = tid & 7;
    const int ck = tid >> 3;
    float4 wi[4][8];
    if (tid < 256) {
#pragma unroll
      for (int r = 0; r < 4; ++r) {
        const float* wrow = Wi + (long)(base + rg * 4 + r) * Dsz + ck * 32;
#pragma unroll
        for (int qq = 0; qq < 8; ++qq) {
          int q = (qq + ck) & 7;
          wi[r][qq] = *(const float4*)(wrow + q * 4);
        }
      }
    }
    float4 w4 = (tid < 256) ? ((const float4*)ln1_w)[tid] : float4{0, 0, 0, 0};
    float lb = 0.f;
    if (tid >= 256 && (tid - 256) < 32) lb = liq_b[base + (tid - 256)];

    for (int t = 1; t <= Tsz; ++t) {
      // rmsnorm of x[b,t-1] in-block
      float4 xv = {0, 0, 0, 0};
      if (tid < 256) {
        xv = ((const float4*)(x + ((long)b * Tsz + (t - 1)) * Dsz))[tid];
        float ss = xv.x * xv.x + xv.y * xv.y + xv.z * xv.z + xv.w * xv.w;
#pragma unroll
        for (int off = 32; off > 0; off >>= 1) ss += __shfl_down(ss, off);
        if (l == 0) red4w[w] = ss;
      }
      __syncthreads();
      if (tid < 256) {
        float tot = red4w[0] + red4w[1] + red4w[2] + red4w[3];
        float scale = 1.0f / sqrtf(tot * (1.0f / Dsz) + 1e-6f);
        float4 av;
        av.x = xv.x * scale * w4.x; av.y = xv.y * scale * w4.y;
        av.z = xv.z * scale * w4.z; av.w = xv.w * scale * w4.w;
        ((float4*)h_lds)[tid] = av;
      }
      __syncthreads();
      if (tid < 256) {
        float acc0 = 0.f, acc1 = 0.f, acc2 = 0.f, acc3 = 0.f;
        const float* hch = &h_lds[ck * 32];
#pragma unroll
        for (int qq = 0; qq < 8; ++qq) {
          const int q = (qq + ck) & 7;
          float4 hv = *(const float4*)(hch + q * 4);
          acc0 += wi[0][qq].x * hv.x + wi[0][qq].y * hv.y + wi[0][qq].z * hv.z + wi[0][qq].w * hv.w;
          acc1 += wi[1][qq].x * hv.x + wi[1][qq].y * hv.y + wi[1][qq].z * hv.z + wi[1][qq].w * hv.w;
          acc2 += wi[2][qq].x * hv.x + wi[2][qq].y * hv.y + wi[2][qq].z * hv.z + wi[2][qq].w * hv.w;
          acc3 += wi[3][qq].x * hv.x + wi[3][qq].y * hv.y + wi[3][qq].z * hv.z + wi[3][qq].w * hv.w;
        }
        acc0 += __shfl_xor(acc0, 8); acc0 += __shfl_xor(acc0, 16); acc0 += __shfl_xor(acc0, 32);
        acc1 += __shfl_xor(acc1, 8); acc1 += __shfl_xor(acc1, 16); acc1 += __shfl_xor(acc1, 32);
        acc2 += __shfl_xor(acc2, 8); acc2 += __shfl_xor(acc2, 16); acc2 += __shfl_xor(acc2, 32);
        acc3 += __shfl_xor(acc3, 8); acc3 += __shfl_xor(acc3, 16); acc3 += __shfl_xor(acc3, 32);
        if ((l & 56) == 0) {
          float4 rv; rv.x = acc0; rv.y = acc1; rv.z = acc2; rv.w = acc3;
          *(float4*)&red[0][w][rg][0] = rv;
        }
      }
      __syncthreads();
      if (tid >= 256) {
        const int r = tid - 256;
        if (r < 32) {
          const int r2 = r >> 2, jj = r & 3;
          float sum = red[0][0][r2][jj] + red[0][1][r2][jj] +
                      red[0][2][r2][jj] + red[0][3][r2][jj] + lb;
          unsigned long long pv =
              (((unsigned long long)(unsigned)t) << 32) |
              (unsigned long long)__float_as_uint(sum);
          __hip_atomic_store(&Utag[((long)b * Tsz + (t - 1)) * Dsz + base + r],
                             pv, __ATOMIC_RELAXED, __HIP_MEMORY_SCOPE_AGENT);
        }
      }
      __syncthreads();
    }

    // ---- tail: weight conversions (hidden under the scan) ----------------
    if (tid == 0) {
      int md = 0;
      const unsigned* m = (const unsigned*)mask;
      for (int i = 0; i < 256; ++i) {
        unsigned wd = m[i];
        if (wd == 0x3F800000u) { md = 2; break; }
        if (wd > 1u) md = 1;
      }
      s_mode = md;
    }
    __syncthreads();
    const int md = s_mode;
    const long gtid = (long)blk2 * 320 + tid;
    const long gstr = 128 * 320;
    const int n4big = Hsz * Dsz / 4;      // 2,097,152 float4s
    for (long i = gtid; i < n4big; i += gstr) {
      float4 v = ((const float4*)ffn_wg)[i];
      ushort4 o; o.x = f2bf(v.x); o.y = f2bf(v.y); o.z = f2bf(v.z); o.w = f2bf(v.w);
      ((ushort4*)wg_bf)[i] = o;
      v = ((const float4*)ffn_wu)[i];
      o.x = f2bf(v.x); o.y = f2bf(v.y); o.z = f2bf(v.z); o.w = f2bf(v.w);
      ((ushort4*)wu_bf)[i] = o;
      v = ((const float4*)ffn_wd)[i];
      o.x = f2bf(v.x); o.y = f2bf(v.y); o.z = f2bf(v.z); o.w = f2bf(v.w);
      ((ushort4*)wd_bf)[i] = o;
    }
    const int n4g = Dsz * Dsz / 4;
    for (long i = gtid; i < n4g; i += gstr) {
      float4 v = ((const float4*)gate_w)[i];
      ushort4 o; o.x = f2bf(v.x); o.y = f2bf(v.y); o.z = f2bf(v.z); o.w = f2bf(v.w);
      ((ushort4*)gw_bf)[i] = o;
    }
    const int nw = Dsz * Dsz;
    for (long i = gtid; i < nw; i += gstr) {
      bool on;
      if (md == 1)      on = ((const unsigned char*)mask)[i] != 0;
      else if (md == 2) on = ((const float*)mask)[i] != 0.f;
      else              on = ((const int*)mask)[i] != 0;
      weff_bf[i] = on ? f2bf(syn_w[i]) : (unsigned short)0;
    }
  }
}

// ---- bf16 MFMA GEMM, C = A @ B^T, m97-style 128x128 tile ------------------
// A:[M,Ks] bf16 rm, B:[N,Ks] bf16 rm. NB: 1 or 2 B-matrices.
// KU: K-tiles (of 32) staged per barrier pair (amortizes barrier drains).
// K = per-block K length; Ks = row stride; blockIdx.z selects the K-slice
// (offset z*K) for split-K. LDS: NB=1 KU=4 -> 64KB (2 blocks/CU, matches
// the split-K 2/CU residency); NB=2 KU=2 -> 48KB (3/CU = VGPR bound). EPI:
//  1: out f32 = aux0 + acc0 * sigmoid(acc1 + aux1[col])
//  2: out bf16 = silu(acc0) * acc1
//  3: out f32 = aux0 + acc0
//  4: split-K partial: f32 acc0 -> (z==0 ? outp : outp2)

template<int NB, int EPI, int KU>
__global__ __launch_bounds__(256)
void gemm_bt(const unsigned short* __restrict__ A,
             const unsigned short* __restrict__ B0,
             const unsigned short* __restrict__ B1,
             const float* __restrict__ aux0, const float* __restrict__ aux1,
             void* __restrict__ outp, float* __restrict__ outp2,
             int M, int N, int K, int Ks) {
  __shared__ unsigned short sA[KU * 128 * 32];
  __shared__ unsigned short sB[KU * NB * 128 * 32];
  const int tid = threadIdx.x;
  const int w = tid >> 6, l = tid & 63;
  const int wm = w & 1, wn = w >> 1;
  const int bm = blockIdx.x, bn = blockIdx.y;
  const int koff = blockIdx.z * K;

  floatx4_t acc[NB][4][4];
#pragma unroll
  for (int j = 0; j < NB; ++j)
#pragma unroll
    for (int m = 0; m < 4; ++m)
#pragma unroll
      for (int n = 0; n < 4; ++n) acc[j][m][n] = (floatx4_t)(0.f);

  const int rA = bm * 128 + 16 * w + (l >> 2);
  const int rB = bn * 128 + 16 * w + (l >> 2);
  const int kl = (l & 3) * 8;
  const unsigned short* gA = A + (long)rA * Ks + kl + koff;
  const unsigned short* gB0 = B0 + (long)rB * Ks + kl + koff;
  const unsigned short* gB1 = nullptr;
  if constexpr (NB > 1) gB1 = B1 + (long)rB * Ks + kl + koff;
  unsigned short* lA = &sA[(16 * w) * 32];
  unsigned short* lB = &sB[(16 * w) * 32];

  for (int k0 = 0; k0 < K; k0 += 32 * KU) {
#pragma unroll
    for (int u = 0; u < KU; ++u) {
      gll16(gA + k0 + u * 32,              lA + u * 4096);
      gll16(gA + k0 + u * 32 + 64 * Ks,    lA + u * 4096 + 64 * 32);
      gll16(gB0 + k0 + u * 32,             lB + (u * NB) * 4096);
      gll16(gB0 + k0 + u * 32 + 64 * Ks,   lB + (u * NB) * 4096 + 64 * 32);
      if constexpr (NB > 1) {
        gll16(gB1 + k0 + u * 32,           lB + (u * NB + 1) * 4096);
        gll16(gB1 + k0 + u * 32 + 64 * Ks, lB + (u * NB + 1) * 4096 + 64 * 32);
      }
    }
    __syncthreads();
#pragma unroll
    for (int u = 0; u < KU; ++u) {
      short8 af[4];
#pragma unroll
      for (int m = 0; m < 4; ++m)
        af[m] = *(const short8*)&sA[u * 4096 +
                    (wm * 64 + m * 16 + (l & 15)) * 32 + (l >> 4) * 8];
#pragma unroll
      for (int j = 0; j < NB; ++j) {
#pragma unroll
        for (int n = 0; n < 4; ++n) {
          short8 bf = *(const short8*)&sB[(u * NB + j) * 4096 +
                          (wn * 64 + n * 16 + (l & 15)) * 32 + (l >> 4) * 8];
#pragma unroll
          for (int m = 0; m < 4; ++m)
            acc[j][m][n] = __builtin_amdgcn_mfma_f32_16x16x32_bf16(
                af[m], bf, acc[j][m][n], 0, 0, 0);
        }
      }
    }
    __syncthreads();
  }

  const int colBase = bn * 128 + wn * 64;
  const int rowBase = bm * 128 + wm * 64;
  float* pout = nullptr;
  if constexpr (EPI == 4)
    pout = (blockIdx.z == 0) ? (float*)outp : outp2;
#pragma unroll
  for (int m = 0; m < 4; ++m) {
#pragma unroll
    for (int n = 0; n < 4; ++n) {
      const int col = colBase + n * 16 + (l & 15);
#pragma unroll
      for (int j = 0; j < 4; ++j) {
        const int row = rowBase + m * 16 + (l >> 4) * 4 + j;
        const long idx = (long)row * N + col;
        float v0 = acc[0][m][n][j];
        if constexpr (EPI == 1) {
          float gsum = acc[NB - 1][m][n][j] + aux1[col];
          float sg = 1.f / (1.f + __expf(-gsum));
          ((float*)outp)[idx] = aux0[idx] + v0 * sg;
        } else if constexpr (EPI == 2) {
          float sil = v0 / (1.f + __expf(-v0));
          ((unsigned short*)outp)[idx] = f2bf(sil * acc[NB - 1][m][n][j]);
        } else if constexpr (EPI == 3) {
          ((float*)outp)[idx] = aux0[idx] + v0;
        } else {  // EPI == 4: split-K partial
          pout[idx] = v0;
        }
      }
    }
  }
}

// ---------------------------------------------------------------------------

extern "C" void kernel_launch(void* const* d_in, const int* in_sizes, int n_in,
                              void* d_out, int out_size, void* d_ws, size_t ws_size,
                              hipStream_t stream) {
  (void)in_sizes; (void)n_in; (void)out_size; (void)ws_size;

  const float* x        = (const float*)d_in[0];
  const float* ln1_w    = (const float*)d_in[1];
  const float* liq_Wi   = (const float*)d_in[2];
  const float* liq_Wr   = (const float*)d_in[3];
  const float* liq_b    = (const float*)d_in[4];
  const float* liq_tau  = (const float*)d_in[5];
  const float* plif_tau = (const float*)d_in[6];
  const float* syn_w    = (const float*)d_in[7];
  const float* gate_w   = (const float*)d_in[8];
  const float* gate_b   = (const float*)d_in[9];
  const float* ln2_w    = (const float*)d_in[10];
  const float* ffn_wg   = (const float*)d_in[11];
  const float* ffn_wu   = (const float*)d_in[12];
  const float* ffn_wd   = (const float*)d_in[13];
  const void*  mask     = d_in[14];

  char* ws = (char*)d_ws;
  const size_t MB = 1024ull * 1024ull;
  unsigned short* wg_bf   = (unsigned short*)(ws + 0 * MB);    // 16 MB
  unsigned short* wu_bf   = (unsigned short*)(ws + 16 * MB);   // 16 MB
  unsigned short* wd_bf   = (unsigned short*)(ws + 32 * MB);   // 16 MB
  unsigned short* weff_bf = (unsigned short*)(ws + 48 * MB);   // 2 MB
  unsigned short* gw_bf   = (unsigned short*)(ws + 50 * MB);   // 2 MB
  float*          x2_f    = (float*)         (ws + 52 * MB);   // 16 MB
  unsigned short* s_bf    = (unsigned short*)(ws + 68 * MB);   // 8 MB
  unsigned short* y_bf    = (unsigned short*)(ws + 76 * MB);   // 8 MB
  unsigned short* ff_bf   = (unsigned short*)(ws + 84 * MB);   // 64 MB (84-148)
  unsigned long long* Utag= (unsigned long long*)(ws + 84 * MB); // 32 MB,
                                    // overlaps ff_bf: Utag dead before FFN
  unsigned long long* hex = (unsigned long long*)(ws + 148 * MB); // 64 KB
  // split-K partials (16 MB each), in regions dead by down-proj time:
  float*          p0_f    = (float*)(ws + 0 * MB);   // was wg_bf (dead after FFN)
  float*          p1_f    = (float*)(ws + 68 * MB);  // was s_bf+y_bf (dead after FFN)
  float*          out_f   = (float*)d_out;

  const int M = Bsz * Tsz;  // 4096

  // fused: scan (blocks 0-127; self-zeroes Hex) + producers/converts (128-255)
  liquid_plif_k<<<256, 320, 0, stream>>>(
      x, ln1_w, liq_Wi, liq_b, liq_Wr, liq_tau, plif_tau, hex, Utag, s_bf,
      ffn_wg, wg_bf, ffn_wu, wu_bf, ffn_wd, wd_bf, gate_w, gw_bf,
      syn_w, mask, weff_bf);

  // x2 = x + (s@weff^T) * sigmoid(s@gate_w^T + gate_b)
  gemm_bt<2, 1, 2><<<dim3(M / 128, Dsz / 128), 256, 0, stream>>>(
      s_bf, weff_bf, gw_bf, x, gate_b, x2_f, nullptr, M, Dsz, Dsz, Dsz);

  // y = rmsnorm(x2, ln2_w) (bf16)
  rmsnorm_k<1><<<M, 256, 0, stream>>>(x2_f, ln2_w, y_bf);

  // ff = silu(y@wg^T) * (y@wu^T)  (bf16; KU=2 halves barrier drains)
  gemm_bt<2, 2, 2><<<dim3(M / 128, Hsz / 128), 256, 0, stream>>>(
      y_bf, wg_bf, wu_bf, nullptr, nullptr, ff_bf, nullptr, M, Hsz, Dsz, Dsz);

  // down-proj split-K=2 (512 blocks -> 2 blocks/CU), KU=4 (32 barrier pairs)
  gemm_bt<1, 4, 4><<<dim3(M / 128, Dsz / 128, 2), 256, 0, stream>>>(
      ff_bf, wd_bf, nullptr, nullptr, nullptr, p0_f, p1_f,
      M, Dsz, Hsz / 2, Hsz);

  // out = x2 + p0 + p1
  combine_k<<<(M * Dsz / 4) / 256, 256, 0, stream>>>(x2_f, p0_f, p1_f, out_f);
}